// Round 10
// baseline (3691.395 us; speedup 1.0000x reference)
//
#include <hip/hip_runtime.h>
#include <hip/hip_bf16.h>
#include <math.h>

// Problem sizes
#define Bz   512
#define Tz   128
#define INz  64
#define Hz   512
#define TSz  32
#define PLz  32
#define BH   (Bz * Hz)          // 262144
#define NBLK 256
#define NTHR 512
#define PFB  6

typedef unsigned short u16;
typedef unsigned long long u64;
typedef __attribute__((ext_vector_type(8)))  short short8;
typedef __attribute__((ext_vector_type(4)))  float f32x4;
typedef __attribute__((ext_vector_type(16))) float floatx16;

static __device__ __forceinline__ void split_bf(float w, u16& hi, u16& lo) {
    __hip_bfloat16 h = __float2bfloat16(w);
    hi = *reinterpret_cast<u16*>(&h);
    float r = w - __bfloat162float(h);
    __hip_bfloat16 l = __float2bfloat16(r);
    lo = *reinterpret_cast<u16*>(&l);
}

// ---- sc1 (coherence-point / MALL) helpers: relaxed agent-scope atomics ----
union U64x2 { u64 q[2]; short8 v; };
union F2U { u64 q; float f[2]; };
union FU  { unsigned u; float f; };

static __device__ __forceinline__ short8 ald16(const u16* p) {
    U64x2 u;
    u.q[0] = __hip_atomic_load((const u64*)p,     __ATOMIC_RELAXED, __HIP_MEMORY_SCOPE_AGENT);
    u.q[1] = __hip_atomic_load((const u64*)p + 1, __ATOMIC_RELAXED, __HIP_MEMORY_SCOPE_AGENT);
    return u.v;
}
static __device__ __forceinline__ float aldf(const float* p) {
    FU c; c.u = __hip_atomic_load((const unsigned*)p, __ATOMIC_RELAXED, __HIP_MEMORY_SCOPE_AGENT);
    return c.f;
}
static __device__ __forceinline__ void ast64f(float* p, float a, float b) {
    F2U u; u.f[0] = a; u.f[1] = b;
    __hip_atomic_store((u64*)p, u.q, __ATOMIC_RELAXED, __HIP_MEMORY_SCOPE_AGENT);
}
static __device__ __forceinline__ void astf(float* p, float v) {
    FU c; c.f = v;
    __hip_atomic_store((unsigned*)p, c.u, __ATOMIC_RELAXED, __HIP_MEMORY_SCOPE_AGENT);
}
static __device__ __forceinline__ unsigned aldu(const unsigned* p) {
    return __hip_atomic_load(p, __ATOMIC_RELAXED, __HIP_MEMORY_SCOPE_AGENT);
}
static __device__ __forceinline__ void astu(unsigned* p, unsigned v) {
    __hip_atomic_store(p, v, __ATOMIC_RELAXED, __HIP_MEMORY_SCOPE_AGENT);
}
static __device__ __forceinline__ void astu16x2(u16* p, unsigned v) {
    __hip_atomic_store((unsigned*)p, v, __ATOMIC_RELAXED, __HIP_MEMORY_SCOPE_AGENT);
}

// ---- sc0 load: L1-bypass, L2-hit (same-XCD coherent reads of L2-dirty lines) ----
static __device__ __forceinline__ float4 ld_sc0(const u16* p) {
    float4 v;
    asm volatile("global_load_dwordx4 %0, %1, off sc0" : "=&v"(v) : "v"(p));
    return v;
}

// ---------------- init: zero initial h fragments + sync area ----------------
__global__ __launch_bounds__(256) void k_init(u16* __restrict__ hfa_hi,
                                              u16* __restrict__ hfa_lo,
                                              u16* __restrict__ hfb_hi,
                                              u16* __restrict__ hfb_lo,
                                              unsigned* __restrict__ sync) {
    const int i = blockIdx.x * 256 + threadIdx.x;
    if (i < BH) { hfa_hi[i] = 0; hfa_lo[i] = 0; hfb_hi[i] = 0; hfb_lo[i] = 0; }
    if (i < 8192) sync[i] = 0;
}

// ---------------- prep: encoder W frags, 16-col blocks, K=576 (18 granules of 32) ----------------
// B-frag (16x16x32): col = lane&15, k = g*32 + (lane>>4)*8 + e. Gate-permuted cols.
__global__ __launch_bounds__(256) void k_prep_wenc16(const float* __restrict__ W_ih,
                                                     const float* __restrict__ W_hh,
                                                     u16* __restrict__ wf_hi,
                                                     u16* __restrict__ wf_lo) {
    const int idx = blockIdx.x * 256 + threadIdx.x;   // 128 cb * 18 g * 64 lane = 147456
    if (idx >= 128 * 18 * 64) return;
    const int lane = idx & 63;
    const int g = (idx >> 6) % 18;
    const int cb = idx / (18 * 64);
    const int C = cb * 16 + (lane & 15);
    const int gate = ((C >> 4) & 3) * 512 + (C >> 6) * 16 + (C & 15);
    const int kh = lane >> 4;
    const size_t base = (size_t)idx * 8;
    #pragma unroll
    for (int e = 0; e < 8; ++e) {
        const int k = g * 32 + kh * 8 + e;   // [0,576)
        const float w = (k < 64) ? W_ih[(size_t)gate * 64 + k]
                                 : W_hh[(size_t)gate * 512 + (k - 64)];
        u16 hi, lo; split_bf(w, hi, lo);
        wf_hi[base + e] = hi; wf_lo[base + e] = lo;
    }
}

// ---------------- prep: decoder W frags (Wc = Wc_ih + Wc_hh), 16-col blocks, K=512 ----------------
__global__ __launch_bounds__(256) void k_prep_wc16(const float* __restrict__ Wc_ih,
                                                   const float* __restrict__ Wc_hh,
                                                   u16* __restrict__ wf_hi,
                                                   u16* __restrict__ wf_lo) {
    const int idx = blockIdx.x * 256 + threadIdx.x;   // 128 * 16 * 64 = 131072
    const int lane = idx & 63;
    const int g = (idx >> 6) % 16;
    const int cb = idx / (16 * 64);
    const int C = cb * 16 + (lane & 15);
    const int gate = ((C >> 4) & 3) * 512 + (C >> 6) * 16 + (C & 15);
    const int kh = lane >> 4;
    const size_t base = (size_t)idx * 8;
    #pragma unroll
    for (int e = 0; e < 8; ++e) {
        const int k = g * 32 + kh * 8 + e;   // [0,512)
        const float w = Wc_ih[(size_t)gate * 512 + k] + Wc_hh[(size_t)gate * 512 + k];
        u16 hi, lo; split_bf(w, hi, lo);
        wf_hi[base + e] = hi; wf_lo[base + e] = lo;
    }
}

// ---------------- prep: W1 frags (OLD 32-col layout for round-9 mlp) ----------------
__global__ __launch_bounds__(256) void k_prep_w1(const float* __restrict__ W1,
                                                 u16* __restrict__ wf_hi,
                                                 u16* __restrict__ wf_lo) {
    const int idx = blockIdx.x * 256 + threadIdx.x;
    const int lane = idx & 63;
    const int cb = idx / (64 * 64);
    const int g = (idx >> 6) % 64;
    const int n = cb * 32 + (lane & 31);
    const int kh = lane >> 5;
    const size_t base = (size_t)idx * 8;
    #pragma unroll
    for (int e = 0; e < 8; ++e) {
        const int k = g * 16 + kh * 8 + e;
        const float w = W1[(size_t)n * 1024 + k];
        u16 hi, lo; split_bf(w, hi, lo);
        wf_hi[base + e] = hi; wf_lo[base + e] = lo;
    }
}

// ---------------- prep: x frags, 16-row blocks: xf[t][rb16(32)][g(2)][lane][8] ----------------
__global__ __launch_bounds__(256) void k_prep_x16(const float* __restrict__ x,
                                                  u16* __restrict__ xf_hi,
                                                  u16* __restrict__ xf_lo) {
    const int idx = blockIdx.x * 256 + threadIdx.x;   // 128*32*2*64 = 524288
    const int lane = idx & 63;
    const int g = (idx >> 6) & 1;
    const int rb = (idx >> 7) & 31;
    const int t = idx >> 12;
    const int b = rb * 16 + (lane & 15);
    const int kh = lane >> 4;
    const size_t base = (size_t)idx * 8;
    #pragma unroll
    for (int e = 0; e < 8; ++e) {
        const int i = g * 32 + kh * 8 + e;   // [0,64)
        const float w = x[((size_t)b * Tz + t) * INz + i];
        u16 hi, lo; split_bf(w, hi, lo);
        xf_hi[base + e] = hi; xf_lo[base + e] = lo;
    }
}

// ---------------- grid barrier: slot-arrival + scan + group release; NO FENCE ----------------
static __device__ __forceinline__ void gsync(unsigned* sync, unsigned target, int bid) {
    __syncthreads();
    const int tid = threadIdx.x;
    unsigned* arr  = sync + 64;
    unsigned* grel = sync + 64 + 4096;
    if (bid == 0) {
        if (tid < 64) {
            if (tid == 0) astu(&arr[0], target);
            bool done = false;
            while (!done) {
                unsigned mn = 0xffffffffu;
                #pragma unroll
                for (int k = 0; k < 4; ++k) {
                    const unsigned v = aldu(&arr[(tid * 4 + k) * 16]);
                    mn = v < mn ? v : mn;
                }
                done = (bool)__all((int)(mn >= target));
                if (!done) __builtin_amdgcn_s_sleep(1);
            }
            if (tid < 16) astu(&grel[tid * 16], target);
        }
    } else {
        if (tid == 0) {
            astu(&arr[bid * 16], target);
            while (aldu(&grel[(bid >> 4) * 16]) < target)
                __builtin_amdgcn_s_sleep(1);
        }
    }
    __syncthreads();
}

// ---------------- gates + cell: grid bid = ji*32 + bi (XCD = bi%8, h XCD-local) ----------------
// Tile: 16 batches (bi) x 256 gate-cols (ji). 8 waves, each 2 col-blocks of 16, full K.
// A (x|h) staged in LDS; h via sc0 (L2-local); weights normal cached (L3 stream).
template<int NG, int GX, bool DEC>
__device__ __forceinline__ void gates16(
    const u16* __restrict__ xf_hi, const u16* __restrict__ xf_lo, int t,
    const u16* __restrict__ wf_hi, const u16* __restrict__ wf_lo,
    const u16* __restrict__ hin_hi, const u16* __restrict__ hin_lo,
    const float* __restrict__ bias,
    float (&c2)[2],
    u16* __restrict__ hout_hi, u16* __restrict__ hout_lo,   // new layout, NORMAL stores
    u16* __restrict__ hold_hi,                               // old layout sc1 (DEC, for mlp)
    float* __restrict__ h_f32,                               // sc1 (DEC, for attn)
    float* __restrict__ buf_enc, int slot,                   // sc1 (ENC, ring)
    u16* A_hi, u16* A_lo, float* Gt, int bid, int tid)
{
    const int ji = bid >> 5, bi = bid & 31;
    const int lane = tid & 63, w = tid >> 6;

    // ---- stage A (16 rows x K) into LDS; h granules via sc0 ----
    constexpr int NSLOT = NG * 64;
    #pragma unroll
    for (int it = 0; it < (NSLOT + NTHR - 1) / NTHR; ++it) {
        const int sl = it * NTHR + tid;
        if (sl < NSLOT) {
            const int g = sl >> 6, l2 = sl & 63;
            float4 vhi, vlo;
            if (GX > 0 && g < GX) {
                const size_t off = ((((size_t)t * 32 + bi) * GX + g) * 64 + l2) * 8;
                vhi = *(const float4*)(xf_hi + off);
                vlo = *(const float4*)(xf_lo + off);
            } else {
                const size_t off = (((size_t)bi * (NG - GX) + (g - GX)) * 64 + l2) * 8;
                vhi = ld_sc0(hin_hi + off);
                vlo = ld_sc0(hin_lo + off);
                asm volatile("s_waitcnt vmcnt(0)" ::: "memory");
                __builtin_amdgcn_sched_barrier(0);
            }
            *(float4*)(A_hi + (size_t)sl * 8) = vhi;
            *(float4*)(A_lo + (size_t)sl * 8) = vlo;
        }
    }
    __syncthreads();

    // ---- K-loop: 2 col-blocks per wave, 3 passes (hh, hl, lh), PFB-deep B prefetch ----
    const int cb0 = ji * 16 + w * 2;
    const u16* pb0h = wf_hi + ((size_t)cb0 * NG) * 512 + lane * 8;
    const u16* pb0l = wf_lo + ((size_t)cb0 * NG) * 512 + lane * 8;
    const u16* pb1h = pb0h + (size_t)NG * 512;
    const u16* pb1l = pb0l + (size_t)NG * 512;

    f32x4 a0h = {0.f,0.f,0.f,0.f}, a0l = a0h, a0x = a0h;
    f32x4 a1h = a0h, a1l = a0h, a1x = a0h;
    short8 b0h[PFB], b0l[PFB], b1h[PFB], b1l[PFB];

    #pragma unroll
    for (int i = 0; i < NG + PFB; ++i) {
        if (i >= PFB) {
            const int s = (i - PFB) % PFB;
            const int g = i - PFB;
            const short8 ahi = *(const short8*)(A_hi + (size_t)(g * 64 + lane) * 8);
            const short8 alo = *(const short8*)(A_lo + (size_t)(g * 64 + lane) * 8);
            a0h = __builtin_amdgcn_mfma_f32_16x16x32_bf16(ahi, b0h[s], a0h, 0, 0, 0);
            a0l = __builtin_amdgcn_mfma_f32_16x16x32_bf16(ahi, b0l[s], a0l, 0, 0, 0);
            a0x = __builtin_amdgcn_mfma_f32_16x16x32_bf16(alo, b0h[s], a0x, 0, 0, 0);
            a1h = __builtin_amdgcn_mfma_f32_16x16x32_bf16(ahi, b1h[s], a1h, 0, 0, 0);
            a1l = __builtin_amdgcn_mfma_f32_16x16x32_bf16(ahi, b1l[s], a1l, 0, 0, 0);
            a1x = __builtin_amdgcn_mfma_f32_16x16x32_bf16(alo, b1h[s], a1x, 0, 0, 0);
        }
        if (i < NG) {
            const int s = i % PFB;
            b0h[s] = *(const short8*)(pb0h + (size_t)i * 512);
            b0l[s] = *(const short8*)(pb0l + (size_t)i * 512);
            b1h[s] = *(const short8*)(pb1h + (size_t)i * 512);
            b1l[s] = *(const short8*)(pb1l + (size_t)i * 512);
        }
    }

    // ---- dump C frags (col=lane&15, row=(lane>>4)*4+r) to Gt[16][260] ----
    {
        const int colb = lane & 15;
        const int rsub = (lane >> 4) * 4;
        #pragma unroll
        for (int r = 0; r < 4; ++r) {
            Gt[(rsub + r) * 260 + (w * 2) * 16 + colb]     = a0h[r] + a0l[r] + a0x[r];
            Gt[(rsub + r) * 260 + (w * 2 + 1) * 16 + colb] = a1h[r] + a1l[r] + a1x[r];
        }
    }
    __syncthreads();

    // ---- cell update: thread -> (b = bi*16 + tid>>5, 2 consecutive j) ----
    {
        const int idx2 = tid * 2;
        const int bl = idx2 >> 6;
        const int jl = idx2 & 63;          // even
        const int b = bi * 16 + bl;
        const int j0 = ji * 64 + jl;
        float hn2[2];
        unsigned phi = 0, plo = 0;
        #pragma unroll
        for (int e = 0; e < 2; ++e) {
            const int jle = jl + e;
            const int Cl = ((jle >> 4) << 6) | (jle & 15);   // local col of gate q=0
            const float* gr = Gt + bl * 260 + Cl;
            const float gi = gr[0]  + bias[j0 + e];
            const float gf = gr[16] + bias[512 + j0 + e];
            const float gg = gr[32] + bias[1024 + j0 + e];
            const float go = gr[48] + bias[1536 + j0 + e];
            const float si = 1.f / (1.f + __expf(-gi));
            const float sf = 1.f / (1.f + __expf(-gf));
            const float so = 1.f / (1.f + __expf(-go));
            const float cn = sf * c2[e] + si * tanhf(gg);
            const float hn = so * tanhf(cn);
            c2[e] = cn; hn2[e] = hn;
            u16 hi, lo; split_bf(hn, hi, lo);
            phi |= (unsigned)hi << (16 * e);
            plo |= (unsigned)lo << (16 * e);
        }
        // new-layout h frag: NORMAL 4B stores (consumers are same-XCD, sc0 readers)
        const int gk = j0 >> 5;
        const int lane3 = (b & 15) | (((j0 >> 3) & 3) << 4);
        const size_t fo = (((size_t)bi * 16 + gk) * 64 + lane3) * 8 + (j0 & 7);
        *(unsigned*)(hout_hi + fo) = phi;
        *(unsigned*)(hout_lo + fo) = plo;
        if (!DEC) {
            if (slot >= 0)
                ast64f(buf_enc + ((size_t)b * TSz + slot) * Hz + j0, hn2[0], hn2[1]);
        } else {
            const int rb = b >> 5, gran = j0 >> 4;
            const int fl = ((j0 >> 3) & 1) * 32 + (b & 31);
            const size_t fo2 = (((size_t)rb * 32 + gran) * 64 + fl) * 8 + (j0 & 7);
            astu16x2(hold_hi + fo2, phi);                       // old layout for mlp
            ast64f(h_f32 + (size_t)b * Hz + j0, hn2[0], hn2[1]); // for attn
        }
    }
}

// ---------------- attention (round-9 verified): 2 batches/block ----------------
__device__ __forceinline__ void attn_phase(const float* __restrict__ h_f32,
                                           const float* __restrict__ buf_enc,
                                           float* __restrict__ buf_dec,
                                           u16* __restrict__ ctx_hi,
                                           int sd, float* lds, int bid, int tid) {
    const int grp = tid >> 8;
    const int t8 = tid & 255;
    const int b = bid * 2 + grp;
    float* sh = lds + grp * 544;
    float* sa = sh + 512;
    {
        const int i0 = t8 * 2;
        sh[i0]     = aldf(h_f32 + (size_t)b * Hz + i0);
        sh[i0 + 1] = aldf(h_f32 + (size_t)b * Hz + i0 + 1);
    }
    __syncthreads();
    {
        const int w = t8 >> 3, l8 = t8 & 7;
        const float* v = (w < TSz - sd)
            ? buf_enc + ((size_t)b * TSz + (sd + w)) * Hz
            : buf_dec + (size_t)(w - TSz + sd) * BH + (size_t)b * Hz;
        float p = 0.f;
        for (int j = l8; j < Hz; j += 8) p = fmaf(sh[j], v[j], p);
        p += __shfl_xor(p, 1); p += __shfl_xor(p, 2); p += __shfl_xor(p, 4);
        if (l8 == 0) sa[w] = p;
    }
    __syncthreads();
    if (t8 < TSz) {
        const float v = sa[t8];
        float m = v;
        #pragma unroll
        for (int d = 1; d < 32; d <<= 1) m = fmaxf(m, __shfl_xor(m, d));
        const float e = __expf(v - m);
        float ss = e;
        #pragma unroll
        for (int d = 1; d < 32; d <<= 1) ss += __shfl_xor(ss, d);
        sa[t8] = e / ss;
    }
    __syncthreads();
    {   // ctx (bf16 hi only) -> old-layout frag, sc1
        const int j0 = t8 * 2;
        float a0 = 0.f, a1 = 0.f;
        for (int w2 = 0; w2 < TSz; ++w2) {
            const float* vp = (w2 < TSz - sd)
                ? buf_enc + ((size_t)b * TSz + (sd + w2)) * Hz + j0
                : buf_dec + (size_t)(w2 - TSz + sd) * BH + (size_t)b * Hz + j0;
            const float2 vv = *(const float2*)vp;
            a0 = fmaf(sa[w2], vv.x, a0);
            a1 = fmaf(sa[w2], vv.y, a1);
        }
        u16 h0, l0, h1, l1;
        split_bf(a0, h0, l0); split_bf(a1, h1, l1);
        const int rb = b >> 5, gran = j0 >> 4;
        const int fl = ((j0 >> 3) & 1) * 32 + (b & 31);
        const size_t fo = (((size_t)rb * 32 + gran) * 64 + fl) * 8 + (j0 & 7);
        astu16x2(ctx_hi + fo, (unsigned)h0 | ((unsigned)h1 << 16));
    }
    {
        const int i0 = t8 * 2;
        ast64f(buf_dec + (size_t)sd * BH + (size_t)b * Hz + i0, sh[i0], sh[i0 + 1]);
    }
}

// ---------------- MLP (round-9 structure, A = bf16-only ctx/h): 8-wave K-split ----------------
__device__ __forceinline__ void mlp_phase(
    const u16* __restrict__ ctx_hi, const u16* __restrict__ hold_hi,
    const u16* __restrict__ w1_hi,  const u16* __restrict__ w1_lo,
    const float* __restrict__ b1, const float* __restrict__ W2,
    float* __restrict__ part_p, float* lds, int bid, int tid)
{
    const int lane = tid & 63, w = tid >> 6;
    const int ni = bid & 15, bi2 = bid >> 4;

    floatx16 acc0, acc1;
    #pragma unroll
    for (int i = 0; i < 16; ++i) { acc0[i] = 0.f; acc1[i] = 0.f; }

    short8 ah[4], bh[4], bl[4];

    #pragma unroll
    for (int i = 0; i < 8 + 4; ++i) {
        if (i >= 4) {
            const int s = (i - 4) & 3;
            acc0 = __builtin_amdgcn_mfma_f32_32x32x16_bf16(ah[s], bh[s], acc0, 0, 0, 0);
            acc1 = __builtin_amdgcn_mfma_f32_32x32x16_bf16(ah[s], bl[s], acc1, 0, 0, 0);
        }
        if (i < 8) {
            const int s = i & 3;
            const int g = w * 8 + i;
            if (g < 32) {
                const size_t off = (((size_t)bi2 * 32 + g) * 64 + lane) * 8;
                ah[s] = ald16(ctx_hi + off);
            } else {
                const size_t off = (((size_t)bi2 * 32 + (g - 32)) * 64 + lane) * 8;
                ah[s] = ald16(hold_hi + off);
            }
            const size_t boff = (((size_t)ni * 64 + g) * 64 + lane) * 8;
            bh[s] = *(const short8*)(w1_hi + boff);
            bl[s] = *(const short8*)(w1_lo + boff);
        }
    }
    #pragma unroll
    for (int i = 0; i < 16; ++i) acc0[i] += acc1[i];

    {
        const int col = lane & 31;
        const int rb4 = 4 * (lane >> 5);
        #pragma unroll
        for (int r = 0; r < 16; ++r)
            lds[w * 1024 + (rb4 + (r & 3) + 8 * (r >> 2)) * 32 + col] = acc0[r];
    }
    __syncthreads();

    const int row = tid >> 4, l16 = tid & 15;
    float a = 0.f;
    #pragma unroll
    for (int jj = 0; jj < 2; ++jj) {
        const int col = l16 * 2 + jj;
        const int ncol = ni * 32 + col;
        float pre = b1[ncol];
        #pragma unroll
        for (int ww = 0; ww < 8; ++ww) pre += lds[ww * 1024 + row * 32 + col];
        a = fmaf(tanhf(pre), W2[ncol], a);
    }
    a += __shfl_xor(a, 1); a += __shfl_xor(a, 2);
    a += __shfl_xor(a, 4); a += __shfl_xor(a, 8);
    if (l16 == 0) astf(&part_p[ni * 512 + bi2 * 32 + row], a);
}

__device__ __forceinline__ void y_reduce(const float* __restrict__ part_p,
                                         const float* __restrict__ b2,
                                         float* __restrict__ y, int s, int bid, int tid) {
    if (tid < 2) {
        const int b = bid * 2 + tid;
        float a = b2[0];
        #pragma unroll
        for (int ni = 0; ni < 16; ++ni) a += aldf(&part_p[ni * 512 + b]);
        astf(&y[(size_t)b * PLz + s], a);
    }
}

// ---------------- the persistent kernel ----------------
struct KParams {
    const u16 *xf_hi, *xf_lo, *wf_hi, *wf_lo, *wcf_hi, *wcf_lo, *w1f_hi, *w1f_lo;
    const float *b_l, *b_c, *b1, *W2, *b2;
    float *h_f32, *buf_enc, *buf_dec, *part_p, *y;
    u16 *hfa_hi, *hfa_lo, *hfb_hi, *hfb_lo, *hold_hi, *ctx_hi;
    unsigned *sync;
};

__global__ __launch_bounds__(NTHR, 1) void k_persist(KParams p) {
    __shared__ char smem[53504];
    u16* A_hi  = (u16*)smem;                  // 18*512 u16 = 18432 B
    u16* A_lo  = (u16*)(smem + 18432);
    float* Gt  = (float*)(smem + 36864);      // 16*260*4 = 16640 B
    float* scr = (float*)smem;                // attn (4.3 KB) / mlp (32 KB) reuse

    const int bid = blockIdx.x;
    const int tid = threadIdx.x;
    unsigned gen = 1;
    float c2[2] = {0.f, 0.f};

    // encoder: 128 steps; ring slots written for t >= 96 (write-once)
    for (int t = 0; t < Tz; ++t) {
        const u16* in_hi = (t & 1) ? p.hfb_hi : p.hfa_hi;
        const u16* in_lo = (t & 1) ? p.hfb_lo : p.hfa_lo;
        u16* out_hi = (t & 1) ? p.hfa_hi : p.hfb_hi;
        u16* out_lo = (t & 1) ? p.hfa_lo : p.hfb_lo;
        gates16<18, 2, false>(p.xf_hi, p.xf_lo, t, p.wf_hi, p.wf_lo, in_hi, in_lo,
                              p.b_l, c2, out_hi, out_lo, nullptr, nullptr,
                              p.buf_enc, t - 96, A_hi, A_lo, Gt, bid, tid);
        gsync(p.sync, gen++, bid);
    }
    // decoder: 32 iterations (gates | attn | mlp)
    for (int sd = 0; sd < PLz; ++sd) {
        if (sd > 0) y_reduce(p.part_p, p.b2, p.y, sd - 1, bid, tid);
        const u16* in_hi = (sd & 1) ? p.hfb_hi : p.hfa_hi;
        const u16* in_lo = (sd & 1) ? p.hfb_lo : p.hfa_lo;
        u16* out_hi = (sd & 1) ? p.hfa_hi : p.hfb_hi;
        u16* out_lo = (sd & 1) ? p.hfa_lo : p.hfb_lo;
        gates16<16, 0, true>(nullptr, nullptr, 0, p.wcf_hi, p.wcf_lo, in_hi, in_lo,
                             p.b_c, c2, out_hi, out_lo, p.hold_hi, p.h_f32,
                             nullptr, -1, A_hi, A_lo, Gt, bid, tid);
        gsync(p.sync, gen++, bid);
        attn_phase(p.h_f32, p.buf_enc, p.buf_dec, p.ctx_hi, sd, scr, bid, tid);
        gsync(p.sync, gen++, bid);
        mlp_phase(p.ctx_hi, p.hold_hi, p.w1f_hi, p.w1f_lo,
                  p.b1, p.W2, p.part_p, scr, bid, tid);
        gsync(p.sync, gen++, bid);
    }
    y_reduce(p.part_p, p.b2, p.y, PLz - 1, bid, tid);
}

extern "C" void kernel_launch(void* const* d_in, const int* in_sizes, int n_in,
                              void* d_out, int out_size, void* d_ws, size_t ws_size,
                              hipStream_t stream) {
    (void)in_sizes; (void)n_in; (void)out_size; (void)ws_size;
    const float* x     = (const float*)d_in[0];
    const float* W_ih  = (const float*)d_in[1];
    const float* W_hh  = (const float*)d_in[2];
    const float* b_l   = (const float*)d_in[3];
    const float* Wc_ih = (const float*)d_in[4];
    const float* Wc_hh = (const float*)d_in[5];
    const float* b_c   = (const float*)d_in[6];
    const float* W1    = (const float*)d_in[7];
    const float* b1    = (const float*)d_in[8];
    const float* W2    = (const float*)d_in[9];
    const float* b2    = (const float*)d_in[10];
    float* y = (float*)d_out;

    float* w = (float*)d_ws;
    float* h_f32   = w;                              // BH
    float* buf_enc = w + BH;                         // 32*BH
    float* buf_dec = w + 33 * (size_t)BH;            // 32*BH
    float* part_p  = w + 65 * (size_t)BH;            // 8192
    unsigned* sync = (unsigned*)(w + 65 * (size_t)BH + 8192);   // 8192 u32
    u16* us = (u16*)(w + 65 * (size_t)BH + 8192 + 8192);
    u16* hfa_hi = us;  us += BH;
    u16* hfa_lo = us;  us += BH;
    u16* hfb_hi = us;  us += BH;
    u16* hfb_lo = us;  us += BH;
    u16* hold_hi = us; us += BH;
    u16* ctx_hi = us;  us += BH;
    u16* xf_hi = us;   us += 4194304;   // 128*32*2*64*8
    u16* xf_lo = us;   us += 4194304;
    u16* wf_hi = us;   us += 1179648;   // 128*18*64*8
    u16* wf_lo = us;   us += 1179648;
    u16* wcf_hi = us;  us += 1048576;   // 128*16*64*8
    u16* wcf_lo = us;  us += 1048576;
    u16* w1f_hi = us;  us += 524288;
    u16* w1f_lo = us;  us += 524288;

    k_init       <<<1024, 256, 0, stream>>>(hfa_hi, hfa_lo, hfb_hi, hfb_lo, sync);
    k_prep_wenc16<<<576,  256, 0, stream>>>(W_ih, W_hh, wf_hi, wf_lo);
    k_prep_wc16  <<<512,  256, 0, stream>>>(Wc_ih, Wc_hh, wcf_hi, wcf_lo);
    k_prep_w1    <<<256,  256, 0, stream>>>(W1, w1f_hi, w1f_lo);
    k_prep_x16   <<<2048, 256, 0, stream>>>(x, xf_hi, xf_lo);

    KParams prm;
    prm.xf_hi = xf_hi;   prm.xf_lo = xf_lo;
    prm.wf_hi = wf_hi;   prm.wf_lo = wf_lo;
    prm.wcf_hi = wcf_hi; prm.wcf_lo = wcf_lo;
    prm.w1f_hi = w1f_hi; prm.w1f_lo = w1f_lo;
    prm.b_l = b_l; prm.b_c = b_c; prm.b1 = b1; prm.W2 = W2; prm.b2 = b2;
    prm.h_f32 = h_f32; prm.buf_enc = buf_enc; prm.buf_dec = buf_dec;
    prm.part_p = part_p; prm.y = y;
    prm.hfa_hi = hfa_hi; prm.hfa_lo = hfa_lo;
    prm.hfb_hi = hfb_hi; prm.hfb_lo = hfb_lo;
    prm.hold_hi = hold_hi; prm.ctx_hi = ctx_hi;
    prm.sync = sync;

    k_persist<<<dim3(NBLK), dim3(NTHR), 0, stream>>>(prm);
}

// Round 11
// 2976.073 us; speedup vs baseline: 1.2404x; 1.2404x over previous
//
#include <hip/hip_runtime.h>
#include <hip/hip_bf16.h>
#include <math.h>

// Problem sizes
#define Bz   512
#define Tz   128
#define INz  64
#define Hz   512
#define TSz  32
#define PLz  32
#define BH   (Bz * Hz)          // 262144
#define NBLK 256
#define NTHR 512
#define PF   6

typedef unsigned short u16;
typedef unsigned long long u64;
typedef __attribute__((ext_vector_type(8)))  short short8;
typedef __attribute__((ext_vector_type(16))) float floatx16;

static __device__ __forceinline__ void split_bf(float w, u16& hi, u16& lo) {
    __hip_bfloat16 h = __float2bfloat16(w);
    hi = *reinterpret_cast<u16*>(&h);
    float r = w - __bfloat162float(h);
    __hip_bfloat16 l = __float2bfloat16(r);
    lo = *reinterpret_cast<u16*>(&l);
}

// ---- sc1 (coherence-point / MALL) STORE helpers + sync atomics ----
union F2U { u64 q; float f[2]; };
union FU  { unsigned u; float f; };

static __device__ __forceinline__ float aldf(const float* p) {
    FU c; c.u = __hip_atomic_load((const unsigned*)p, __ATOMIC_RELAXED, __HIP_MEMORY_SCOPE_AGENT);
    return c.f;
}
static __device__ __forceinline__ void ast64f(float* p, float a, float b) {
    F2U u; u.f[0] = a; u.f[1] = b;
    __hip_atomic_store((u64*)p, u.q, __ATOMIC_RELAXED, __HIP_MEMORY_SCOPE_AGENT);
}
static __device__ __forceinline__ void astf(float* p, float v) {
    FU c; c.f = v;
    __hip_atomic_store((unsigned*)p, c.u, __ATOMIC_RELAXED, __HIP_MEMORY_SCOPE_AGENT);
}
static __device__ __forceinline__ unsigned aldu(const unsigned* p) {
    return __hip_atomic_load(p, __ATOMIC_RELAXED, __HIP_MEMORY_SCOPE_AGENT);
}
static __device__ __forceinline__ void astu(unsigned* p, unsigned v) {
    __hip_atomic_store(p, v, __ATOMIC_RELAXED, __HIP_MEMORY_SCOPE_AGENT);
}
static __device__ __forceinline__ void astu16x2(u16* p, unsigned v) {
    __hip_atomic_store((unsigned*)p, v, __ATOMIC_RELAXED, __HIP_MEMORY_SCOPE_AGENT);
}

// ---------------- init: zero hrot slot 15 + sync area ----------------
__global__ __launch_bounds__(256) void k_init(u16* __restrict__ h15_hi,
                                              u16* __restrict__ h15_lo,
                                              unsigned* __restrict__ sync) {
    const int i = blockIdx.x * 256 + threadIdx.x;
    if (i < BH) { h15_hi[i] = 0; h15_lo[i] = 0; }
    if (i < 8192) sync[i] = 0;
}

// ---------------- prep kernels (round-9 verified) ----------------
__global__ __launch_bounds__(256) void k_prep_wenc(const float* __restrict__ W_ih,
                                                   const float* __restrict__ W_hh,
                                                   u16* __restrict__ wf_hi,
                                                   u16* __restrict__ wf_lo) {
    const int idx = blockIdx.x * 256 + threadIdx.x;
    const int lane = idx & 63;
    const int g = (idx >> 6) % 36;
    const int cb = idx / (36 * 64);
    const int C = cb * 32 + (lane & 31);
    const int gate = ((C >> 4) & 3) * 512 + (C >> 6) * 16 + (C & 15);
    const int kh = lane >> 5;
    const size_t base = (size_t)idx * 8;
    #pragma unroll
    for (int e = 0; e < 8; ++e) {
        const int k = g * 16 + kh * 8 + e;
        const float w = (k < 64) ? W_ih[(size_t)gate * 64 + k]
                                 : W_hh[(size_t)gate * 512 + (k - 64)];
        u16 hi, lo; split_bf(w, hi, lo);
        wf_hi[base + e] = hi; wf_lo[base + e] = lo;
    }
}

__global__ __launch_bounds__(256) void k_prep_wc(const float* __restrict__ Wc_ih,
                                                 const float* __restrict__ Wc_hh,
                                                 u16* __restrict__ wf_hi,
                                                 u16* __restrict__ wf_lo) {
    const int idx = blockIdx.x * 256 + threadIdx.x;
    const int lane = idx & 63;
    const int cb = idx / (32 * 64);
    const int g = (idx >> 6) % 32;
    const int C = cb * 32 + (lane & 31);
    const int gate = ((C >> 4) & 3) * 512 + (C >> 6) * 16 + (C & 15);
    const int kh = lane >> 5;
    const size_t base = (size_t)idx * 8;
    #pragma unroll
    for (int e = 0; e < 8; ++e) {
        const int k = g * 16 + kh * 8 + e;
        const float w = Wc_ih[(size_t)gate * 512 + k] + Wc_hh[(size_t)gate * 512 + k];
        u16 hi, lo; split_bf(w, hi, lo);
        wf_hi[base + e] = hi; wf_lo[base + e] = lo;
    }
}

__global__ __launch_bounds__(256) void k_prep_w1(const float* __restrict__ W1,
                                                 u16* __restrict__ wf_hi,
                                                 u16* __restrict__ wf_lo) {
    const int idx = blockIdx.x * 256 + threadIdx.x;
    const int lane = idx & 63;
    const int cb = idx / (64 * 64);
    const int g = (idx >> 6) % 64;
    const int n = cb * 32 + (lane & 31);
    const int kh = lane >> 5;
    const size_t base = (size_t)idx * 8;
    #pragma unroll
    for (int e = 0; e < 8; ++e) {
        const int k = g * 16 + kh * 8 + e;
        const float w = W1[(size_t)n * 1024 + k];
        u16 hi, lo; split_bf(w, hi, lo);
        wf_hi[base + e] = hi; wf_lo[base + e] = lo;
    }
}

__global__ __launch_bounds__(256) void k_prep_x(const float* __restrict__ x,
                                                u16* __restrict__ xf_hi,
                                                u16* __restrict__ xf_lo) {
    const int idx = blockIdx.x * 256 + threadIdx.x;
    const int lane = idx & 63;
    const int g = (idx >> 6) & 3;
    const int rb = (idx >> 8) & 15;
    const int t = idx >> 12;
    const int b = rb * 32 + (lane & 31);
    const int kh = lane >> 5;
    const size_t base = (size_t)idx * 8;
    #pragma unroll
    for (int e = 0; e < 8; ++e) {
        const int i = g * 16 + kh * 8 + e;
        const float w = x[((size_t)b * Tz + t) * INz + i];
        u16 hi, lo; split_bf(w, hi, lo);
        xf_hi[base + e] = hi; xf_lo[base + e] = lo;
    }
}

// ---------------- grid barrier; acquire-fence (buffer_inv) every 8th generation ----------------
// Cross-block data: sc1 STORES (MALL always fresh) + NORMAL cached reads of rotated
// (reuse-distance >= 12 gens) or write-once addresses. A stale clean line can only be
// re-read after >= 12 gens; the inv every 8 gens drops it first. Weights/x stay L2-warm
// except at the 28 invs (~1.6 MB/XCD refill each).
static __device__ __forceinline__ void gsync(unsigned* sync, unsigned target, int bid) {
    __syncthreads();
    const int tid = threadIdx.x;
    unsigned* arr  = sync + 64;
    unsigned* grel = sync + 64 + 4096;
    if (bid == 0) {
        if (tid < 64) {
            if (tid == 0) astu(&arr[0], target);
            bool done = false;
            while (!done) {
                unsigned mn = 0xffffffffu;
                #pragma unroll
                for (int k = 0; k < 4; ++k) {
                    const unsigned v = aldu(&arr[(tid * 4 + k) * 16]);
                    mn = v < mn ? v : mn;
                }
                done = (bool)__all((int)(mn >= target));
                if (!done) __builtin_amdgcn_s_sleep(1);
            }
            if (tid < 16) astu(&grel[tid * 16], target);
        }
    } else {
        if (tid == 0) {
            astu(&arr[bid * 16], target);
            while (aldu(&grel[(bid >> 4) * 16]) < target)
                __builtin_amdgcn_s_sleep(1);
        }
    }
    if ((target & 7u) == 0u && tid == 0)
        __builtin_amdgcn_fence(__ATOMIC_ACQUIRE, "agent");   // periodic buffer_inv
    __syncthreads();
}

// ---------------- gates + cell phase: 8 waves, K-split; h reads CACHED ----------------
template<int NG, int GX>
__device__ __forceinline__ void gates_phase(
    const u16* __restrict__ xf_hi, const u16* __restrict__ xf_lo, int t,
    const u16* __restrict__ wf_hi, const u16* __restrict__ wf_lo,
    const u16* __restrict__ hin_hi, const u16* __restrict__ hin_lo,
    const float* __restrict__ bias,
    float (&c2)[2], float* __restrict__ h_f32,
    u16* __restrict__ hout_hi, u16* __restrict__ hout_lo,
    float* __restrict__ buf_enc, int slot,
    float* Gt, int bid, int tid)
{
    const int lane = tid & 63, wid = tid >> 6;
    const int wc = wid & 1, wr = (wid >> 1) & 1, kh = wid >> 2;
    const int ji = bid & 31, bi = bid >> 5;
    const int rbIdx = bi * 2 + wr;
    const int cbIdx = ji * 2 + wc;
    constexpr int NGH = NG / 2;
    const int g0 = kh * NGH;

    floatx16 acc0, acc1, acc2;
    #pragma unroll
    for (int i = 0; i < 16; ++i) { acc0[i] = 0.f; acc1[i] = 0.f; acc2[i] = 0.f; }

    const u16* pbh = wf_hi + ((size_t)cbIdx * NG) * 512 + lane * 8;
    const u16* pbl = wf_lo + ((size_t)cbIdx * NG) * 512 + lane * 8;

    short8 ah[PF], al[PF], bh[PF], bl[PF];

    #pragma unroll
    for (int i = 0; i < NGH + PF; ++i) {
        if (i >= PF) {   // consume granule i-PF
            const int s = (i - PF) % PF;
            acc0 = __builtin_amdgcn_mfma_f32_32x32x16_bf16(ah[s], bh[s], acc0, 0, 0, 0);
            acc1 = __builtin_amdgcn_mfma_f32_32x32x16_bf16(ah[s], bl[s], acc1, 0, 0, 0);
            acc2 = __builtin_amdgcn_mfma_f32_32x32x16_bf16(al[s], bh[s], acc2, 0, 0, 0);
        }
        if (i < NGH) {   // refill slot with granule g0+i (ALL cached loads)
            const int s = i % PF;
            const int g = g0 + i;
            if (g < GX) {
                const size_t off = ((((size_t)t * 16 + rbIdx) * 4 + g) * 64 + lane) * 8;
                ah[s] = *(const short8*)(xf_hi + off);
                al[s] = *(const short8*)(xf_lo + off);
            } else {
                const size_t off = (((size_t)rbIdx * 32 + (g - GX)) * 64 + lane) * 8;
                ah[s] = *(const short8*)(hin_hi + off);
                al[s] = *(const short8*)(hin_lo + off);
            }
            bh[s] = *(const short8*)(pbh + (size_t)g * 512);
            bl[s] = *(const short8*)(pbl + (size_t)g * 512);
        }
    }
    #pragma unroll
    for (int i = 0; i < 16; ++i) acc0[i] += acc1[i] + acc2[i];

    {   // dump 32x32 frags to Gt[kh][64][65]
        const int col = wc * 32 + (lane & 31);
        const int rbase = wr * 32 + 4 * (lane >> 5);
        float* G = Gt + kh * 4160;
        #pragma unroll
        for (int r = 0; r < 16; ++r)
            G[(rbase + (r & 3) + 8 * (r >> 2)) * 65 + col] = acc0[r];
    }
    __syncthreads();

    // cell update: thread -> (b = bi*64 + tid>>3, 2 consecutive j); c in VGPRs
    {
        const int bl2 = tid >> 3, jq = tid & 7;
        const int b = bi * 64 + bl2;
        const int j0 = ji * 16 + jq * 2;
        float hn2[2];
        unsigned phi = 0, plo = 0;
        #pragma unroll
        for (int e = 0; e < 2; ++e) {
            const int jj = jq * 2 + e;
            const float gi = Gt[bl2 * 65 + jj]      + Gt[4160 + bl2 * 65 + jj]      + bias[j0 + e];
            const float gf = Gt[bl2 * 65 + 16 + jj] + Gt[4160 + bl2 * 65 + 16 + jj] + bias[512 + j0 + e];
            const float gg = Gt[bl2 * 65 + 32 + jj] + Gt[4160 + bl2 * 65 + 32 + jj] + bias[1024 + j0 + e];
            const float go = Gt[bl2 * 65 + 48 + jj] + Gt[4160 + bl2 * 65 + 48 + jj] + bias[1536 + j0 + e];
            const float si = 1.f / (1.f + __expf(-gi));
            const float sf = 1.f / (1.f + __expf(-gf));
            const float so = 1.f / (1.f + __expf(-go));
            const float cn = sf * c2[e] + si * tanhf(gg);
            const float hn = so * tanhf(cn);
            c2[e] = cn; hn2[e] = hn;
            u16 hi, lo; split_bf(hn, hi, lo);
            phi |= (unsigned)hi << (16 * e);
            plo |= (unsigned)lo << (16 * e);
        }
        const int rb = b >> 5, gran = j0 >> 4;
        const int fl = ((j0 >> 3) & 1) * 32 + (b & 31);
        const size_t fo = (((size_t)rb * 32 + gran) * 64 + fl) * 8 + (j0 & 7);
        astu16x2(hout_hi + fo, phi);    // sc1: fresh at MALL for all XCDs
        astu16x2(hout_lo + fo, plo);
        if (slot >= 0)
            ast64f(buf_enc + ((size_t)b * TSz + slot) * Hz + j0, hn2[0], hn2[1]);
        if (h_f32 != nullptr)
            ast64f(h_f32 + (size_t)b * Hz + j0, hn2[0], hn2[1]);
    }
}

// ---------------- attention: 2 batches/block; all reads cached (rotated / write-once) ----------------
__device__ __forceinline__ void attn_phase(const float* __restrict__ h_f32,
                                           const float* __restrict__ buf_enc,
                                           float* __restrict__ buf_dec,
                                           u16* __restrict__ ctx_hi, u16* __restrict__ ctx_lo,
                                           int sd, float* lds, int bid, int tid) {
    const int grp = tid >> 8;
    const int t8 = tid & 255;
    const int b = bid * 2 + grp;
    float* sh = lds + grp * 544;
    float* sa = sh + 512;
    {   // stage h row (cached; h_f32 is 4-deep rotated)
        const int i0 = t8 * 2;
        const float2 hv = *(const float2*)(h_f32 + (size_t)b * Hz + i0);
        sh[i0] = hv.x; sh[i0 + 1] = hv.y;
    }
    __syncthreads();
    {   // 32 scores x 8 lanes; ring reads cached (write-once addresses)
        const int w = t8 >> 3, l8 = t8 & 7;
        const float* v = (w < TSz - sd)
            ? buf_enc + ((size_t)b * TSz + (sd + w)) * Hz
            : buf_dec + (size_t)(w - TSz + sd) * BH + (size_t)b * Hz;
        float p = 0.f;
        for (int j = l8; j < Hz; j += 8) p = fmaf(sh[j], v[j], p);
        p += __shfl_xor(p, 1); p += __shfl_xor(p, 2); p += __shfl_xor(p, 4);
        if (l8 == 0) sa[w] = p;
    }
    __syncthreads();
    if (t8 < TSz) {   // softmax over 32
        const float v = sa[t8];
        float m = v;
        #pragma unroll
        for (int d = 1; d < 32; d <<= 1) m = fmaxf(m, __shfl_xor(m, d));
        const float e = __expf(v - m);
        float ss = e;
        #pragma unroll
        for (int d = 1; d < 32; d <<= 1) ss += __shfl_xor(ss, d);
        sa[t8] = e / ss;
    }
    __syncthreads();
    {   // ctx: 2 consecutive j per thread; sc1 frag store to rotated ctx
        const int j0 = t8 * 2;
        float a0 = 0.f, a1 = 0.f;
        for (int w2 = 0; w2 < TSz; ++w2) {
            const float* vp = (w2 < TSz - sd)
                ? buf_enc + ((size_t)b * TSz + (sd + w2)) * Hz + j0
                : buf_dec + (size_t)(w2 - TSz + sd) * BH + (size_t)b * Hz + j0;
            const float2 vv = *(const float2*)vp;
            a0 = fmaf(sa[w2], vv.x, a0);
            a1 = fmaf(sa[w2], vv.y, a1);
        }
        u16 h0, l0, h1, l1;
        split_bf(a0, h0, l0); split_bf(a1, h1, l1);
        const int rb = b >> 5, gran = j0 >> 4;
        const int fl = ((j0 >> 3) & 1) * 32 + (b & 31);
        const size_t fo = (((size_t)rb * 32 + gran) * 64 + fl) * 8 + (j0 & 7);
        astu16x2(ctx_hi + fo, (unsigned)h0 | ((unsigned)h1 << 16));
        astu16x2(ctx_lo + fo, (unsigned)l0 | ((unsigned)l1 << 16));
    }
    {   // append h_sd to fresh buffer buf_dec[sd] (sc1, write-once)
        const int i0 = t8 * 2;
        ast64f(buf_dec + (size_t)sd * BH + (size_t)b * Hz + i0, sh[i0], sh[i0 + 1]);
    }
}

// ---------------- MLP + partial out: 8-wave K-split; A reads cached (rotated) ----------------
__device__ __forceinline__ void mlp_phase(
    const u16* __restrict__ ctx_hi, const u16* __restrict__ ctx_lo,
    const u16* __restrict__ h_hi,   const u16* __restrict__ h_lo,
    const u16* __restrict__ w1_hi,  const u16* __restrict__ w1_lo,
    const float* __restrict__ b1, const float* __restrict__ W2,
    float* __restrict__ part_p, float* lds, int bid, int tid)
{
    const int lane = tid & 63, w = tid >> 6;
    const int ni = bid & 15, bi2 = bid >> 4;

    floatx16 acc0, acc1, acc2;
    #pragma unroll
    for (int i = 0; i < 16; ++i) { acc0[i] = 0.f; acc1[i] = 0.f; acc2[i] = 0.f; }

    short8 ah[4], al[4], bh[4], bl[4];

    #pragma unroll
    for (int i = 0; i < 8 + 4; ++i) {
        if (i >= 4) {
            const int s = (i - 4) & 3;
            acc0 = __builtin_amdgcn_mfma_f32_32x32x16_bf16(ah[s], bh[s], acc0, 0, 0, 0);
            acc1 = __builtin_amdgcn_mfma_f32_32x32x16_bf16(ah[s], bl[s], acc1, 0, 0, 0);
            acc2 = __builtin_amdgcn_mfma_f32_32x32x16_bf16(al[s], bh[s], acc2, 0, 0, 0);
        }
        if (i < 8) {
            const int s = i & 3;
            const int g = w * 8 + i;   // wave-split K
            if (g < 32) {
                const size_t off = (((size_t)bi2 * 32 + g) * 64 + lane) * 8;
                ah[s] = *(const short8*)(ctx_hi + off);
                al[s] = *(const short8*)(ctx_lo + off);
            } else {
                const size_t off = (((size_t)bi2 * 32 + (g - 32)) * 64 + lane) * 8;
                ah[s] = *(const short8*)(h_hi + off);
                al[s] = *(const short8*)(h_lo + off);
            }
            const size_t boff = (((size_t)ni * 64 + g) * 64 + lane) * 8;
            bh[s] = *(const short8*)(w1_hi + boff);
            bl[s] = *(const short8*)(w1_lo + boff);
        }
    }
    #pragma unroll
    for (int i = 0; i < 16; ++i) acc0[i] += acc1[i] + acc2[i];

    {   // per-wave 32x32 partial -> lds[w][row][col]
        const int col = lane & 31;
        const int rb4 = 4 * (lane >> 5);
        #pragma unroll
        for (int r = 0; r < 16; ++r)
            lds[w * 1024 + (rb4 + (r & 3) + 8 * (r >> 2)) * 32 + col] = acc0[r];
    }
    __syncthreads();

    // reduce 8 wave-partials + bias, tanh, dot with W2 slice -> part_p (sc1)
    const int row = tid >> 4, l16 = tid & 15;
    float a = 0.f;
    #pragma unroll
    for (int jj = 0; jj < 2; ++jj) {
        const int col = l16 * 2 + jj;
        const int ncol = ni * 32 + col;
        float pre = b1[ncol];
        #pragma unroll
        for (int ww = 0; ww < 8; ++ww) pre += lds[ww * 1024 + row * 32 + col];
        a = fmaf(tanhf(pre), W2[ncol], a);
    }
    a += __shfl_xor(a, 1); a += __shfl_xor(a, 2);
    a += __shfl_xor(a, 4); a += __shfl_xor(a, 8);
    if (l16 == 0) astf(&part_p[ni * 512 + bi2 * 32 + row], a);
}

__device__ __forceinline__ void y_reduce(const float* __restrict__ part_p,
                                         const float* __restrict__ b2,
                                         float* __restrict__ y, int s, int bid, int tid) {
    if (tid < 2) {
        const int b = bid * 2 + tid;
        float a = b2[0];
        #pragma unroll
        for (int ni = 0; ni < 16; ++ni) a += aldf(&part_p[ni * 512 + b]);
        astf(&y[(size_t)b * PLz + s], a);
    }
}

// ---------------- the persistent kernel ----------------
struct KParams {
    const u16 *xf_hi, *xf_lo, *wf_hi, *wf_lo, *wcf_hi, *wcf_lo, *w1f_hi, *w1f_lo;
    const float *b_l, *b_c, *b1, *W2, *b2;
    float *h_f32rot, *buf_enc, *buf_dec, *part_p, *y;
    u16 *hrot_hi, *hrot_lo, *ctxrot_hi, *ctxrot_lo;
    unsigned *sync;
};

__global__ __launch_bounds__(NTHR, 1) void k_persist(KParams p) {
    __shared__ float s_gt[2 * 64 * 65];   // 33 KB; aliased by attn (2*544) and mlp (8*1024)
    const int bid = blockIdx.x;
    const int tid = threadIdx.x;
    unsigned gen = 1;
    float c2[2] = {0.f, 0.f};   // persistent cell state

    // encoder: 128 steps; h rotation depth 16 (slot u%16), ring slots write-once (t>=96)
    for (int t = 0; t < Tz; ++t) {
        const int si = (t + 15) & 15, so = t & 15;
        gates_phase<36, 4>(p.xf_hi, p.xf_lo, t, p.wf_hi, p.wf_lo,
                           p.hrot_hi + (size_t)si * BH, p.hrot_lo + (size_t)si * BH,
                           p.b_l, c2, nullptr,
                           p.hrot_hi + (size_t)so * BH, p.hrot_lo + (size_t)so * BH,
                           p.buf_enc, t - 96, s_gt, bid, tid);
        gsync(p.sync, gen++, bid);
    }
    // decoder: 32 iterations (gates | attn | mlp)
    for (int sd = 0; sd < PLz; ++sd) {
        if (sd > 0) y_reduce(p.part_p, p.b2, p.y, sd - 1, bid, tid);
        const int si = (sd + 15) & 15, so = sd & 15;   // u = 128+sd, 128%16==0
        float* hf = p.h_f32rot + (size_t)(sd & 3) * BH;
        u16* cx_hi = p.ctxrot_hi + (size_t)(sd & 3) * BH;
        u16* cx_lo = p.ctxrot_lo + (size_t)(sd & 3) * BH;
        gates_phase<32, 0>(nullptr, nullptr, 0, p.wcf_hi, p.wcf_lo,
                           p.hrot_hi + (size_t)si * BH, p.hrot_lo + (size_t)si * BH,
                           p.b_c, c2, hf,
                           p.hrot_hi + (size_t)so * BH, p.hrot_lo + (size_t)so * BH,
                           nullptr, -1, s_gt, bid, tid);
        gsync(p.sync, gen++, bid);
        attn_phase(hf, p.buf_enc, p.buf_dec, cx_hi, cx_lo, sd, s_gt, bid, tid);
        gsync(p.sync, gen++, bid);
        mlp_phase(cx_hi, cx_lo,
                  p.hrot_hi + (size_t)so * BH, p.hrot_lo + (size_t)so * BH,
                  p.w1f_hi, p.w1f_lo, p.b1, p.W2, p.part_p, s_gt, bid, tid);
        gsync(p.sync, gen++, bid);
    }
    y_reduce(p.part_p, p.b2, p.y, PLz - 1, bid, tid);
}

extern "C" void kernel_launch(void* const* d_in, const int* in_sizes, int n_in,
                              void* d_out, int out_size, void* d_ws, size_t ws_size,
                              hipStream_t stream) {
    (void)in_sizes; (void)n_in; (void)out_size; (void)ws_size;
    const float* x     = (const float*)d_in[0];
    const float* W_ih  = (const float*)d_in[1];
    const float* W_hh  = (const float*)d_in[2];
    const float* b_l   = (const float*)d_in[3];
    const float* Wc_ih = (const float*)d_in[4];
    const float* Wc_hh = (const float*)d_in[5];
    const float* b_c   = (const float*)d_in[6];
    const float* W1    = (const float*)d_in[7];
    const float* b1    = (const float*)d_in[8];
    const float* W2    = (const float*)d_in[9];
    const float* b2    = (const float*)d_in[10];
    float* y = (float*)d_out;

    float* w = (float*)d_ws;
    float* h_f32rot = w;                             // 4*BH
    float* buf_enc  = w + 4 * (size_t)BH;            // 32*BH
    float* buf_dec  = w + 36 * (size_t)BH;           // 32*BH
    float* part_p   = w + 68 * (size_t)BH;           // 8192
    unsigned* sync  = (unsigned*)(w + 68 * (size_t)BH + 8192);   // 8192 u32
    u16* us = (u16*)(w + 68 * (size_t)BH + 8192 + 8192);
    u16* hrot_hi = us;   us += 16 * (size_t)BH;
    u16* hrot_lo = us;   us += 16 * (size_t)BH;
    u16* ctxrot_hi = us; us += 4 * (size_t)BH;
    u16* ctxrot_lo = us; us += 4 * (size_t)BH;
    u16* xf_hi = us;   us += 4194304;
    u16* xf_lo = us;   us += 4194304;
    u16* wf_hi = us;   us += 1179648;
    u16* wf_lo = us;   us += 1179648;
    u16* wcf_hi = us;  us += 1048576;
    u16* wcf_lo = us;  us += 1048576;
    u16* w1f_hi = us;  us += 524288;
    u16* w1f_lo = us;  us += 524288;

    k_init     <<<1024, 256, 0, stream>>>(hrot_hi + 15 * (size_t)BH,
                                          hrot_lo + 15 * (size_t)BH, sync);
    k_prep_wenc<<<576,  256, 0, stream>>>(W_ih, W_hh, wf_hi, wf_lo);
    k_prep_wc  <<<512,  256, 0, stream>>>(Wc_ih, Wc_hh, wcf_hi, wcf_lo);
    k_prep_w1  <<<256,  256, 0, stream>>>(W1, w1f_hi, w1f_lo);
    k_prep_x   <<<2048, 256, 0, stream>>>(x, xf_hi, xf_lo);

    KParams prm;
    prm.xf_hi = xf_hi;   prm.xf_lo = xf_lo;
    prm.wf_hi = wf_hi;   prm.wf_lo = wf_lo;
    prm.wcf_hi = wcf_hi; prm.wcf_lo = wcf_lo;
    prm.w1f_hi = w1f_hi; prm.w1f_lo = w1f_lo;
    prm.b_l = b_l; prm.b_c = b_c; prm.b1 = b1; prm.W2 = W2; prm.b2 = b2;
    prm.h_f32rot = h_f32rot; prm.buf_enc = buf_enc; prm.buf_dec = buf_dec;
    prm.part_p = part_p; prm.y = y;
    prm.hrot_hi = hrot_hi; prm.hrot_lo = hrot_lo;
    prm.ctxrot_hi = ctxrot_hi; prm.ctxrot_lo = ctxrot_lo;
    prm.sync = sync;

    k_persist<<<dim3(NBLK), dim3(NTHR), 0, stream>>>(prm);
}

// Round 12
// 2745.350 us; speedup vs baseline: 1.3446x; 1.0840x over previous
//
#include <hip/hip_runtime.h>
#include <hip/hip_bf16.h>
#include <math.h>

// Problem sizes
#define Bz   512
#define Tz   128
#define INz  64
#define Hz   512
#define TSz  32
#define PLz  32
#define BH   (Bz * Hz)          // 262144
#define NBLK 256
#define NTHR 512
#define PF   6

typedef unsigned short u16;
typedef unsigned long long u64;
typedef __attribute__((ext_vector_type(8)))  short short8;
typedef __attribute__((ext_vector_type(16))) float floatx16;

static __device__ __forceinline__ void split_bf(float w, u16& hi, u16& lo) {
    __hip_bfloat16 h = __float2bfloat16(w);
    hi = *reinterpret_cast<u16*>(&h);
    float r = w - __bfloat162float(h);
    __hip_bfloat16 l = __float2bfloat16(r);
    lo = *reinterpret_cast<u16*>(&l);
}

// ---- sc1 (coherence-point / MALL) STORE helpers + sync atomics ----
union F2U { u64 q; float f[2]; };
union FU  { unsigned u; float f; };

static __device__ __forceinline__ float aldf(const float* p) {
    FU c; c.u = __hip_atomic_load((const unsigned*)p, __ATOMIC_RELAXED, __HIP_MEMORY_SCOPE_AGENT);
    return c.f;
}
static __device__ __forceinline__ void ast64f(float* p, float a, float b) {
    F2U u; u.f[0] = a; u.f[1] = b;
    __hip_atomic_store((u64*)p, u.q, __ATOMIC_RELAXED, __HIP_MEMORY_SCOPE_AGENT);
}
static __device__ __forceinline__ void astf(float* p, float v) {
    FU c; c.f = v;
    __hip_atomic_store((unsigned*)p, c.u, __ATOMIC_RELAXED, __HIP_MEMORY_SCOPE_AGENT);
}
static __device__ __forceinline__ unsigned aldu(const unsigned* p) {
    return __hip_atomic_load(p, __ATOMIC_RELAXED, __HIP_MEMORY_SCOPE_AGENT);
}
static __device__ __forceinline__ void astu(unsigned* p, unsigned v) {
    __hip_atomic_store(p, v, __ATOMIC_RELAXED, __HIP_MEMORY_SCOPE_AGENT);
}
static __device__ __forceinline__ void astu16x2(u16* p, unsigned v) {
    __hip_atomic_store((unsigned*)p, v, __ATOMIC_RELAXED, __HIP_MEMORY_SCOPE_AGENT);
}

// ---------------- init: zero hrot slot 15 + sync area ----------------
__global__ __launch_bounds__(256) void k_init(u16* __restrict__ h15_hi,
                                              u16* __restrict__ h15_lo,
                                              unsigned* __restrict__ sync) {
    const int i = blockIdx.x * 256 + threadIdx.x;
    if (i < BH) { h15_hi[i] = 0; h15_lo[i] = 0; }
    if (i < 8192) sync[i] = 0;
}

// ---------------- prep kernels (verified, unchanged) ----------------
__global__ __launch_bounds__(256) void k_prep_wenc(const float* __restrict__ W_ih,
                                                   const float* __restrict__ W_hh,
                                                   u16* __restrict__ wf_hi,
                                                   u16* __restrict__ wf_lo) {
    const int idx = blockIdx.x * 256 + threadIdx.x;
    const int lane = idx & 63;
    const int g = (idx >> 6) % 36;
    const int cb = idx / (36 * 64);
    const int C = cb * 32 + (lane & 31);
    const int gate = ((C >> 4) & 3) * 512 + (C >> 6) * 16 + (C & 15);
    const int kh = lane >> 5;
    const size_t base = (size_t)idx * 8;
    #pragma unroll
    for (int e = 0; e < 8; ++e) {
        const int k = g * 16 + kh * 8 + e;
        const float w = (k < 64) ? W_ih[(size_t)gate * 64 + k]
                                 : W_hh[(size_t)gate * 512 + (k - 64)];
        u16 hi, lo; split_bf(w, hi, lo);
        wf_hi[base + e] = hi; wf_lo[base + e] = lo;
    }
}

__global__ __launch_bounds__(256) void k_prep_wc(const float* __restrict__ Wc_ih,
                                                 const float* __restrict__ Wc_hh,
                                                 u16* __restrict__ wf_hi,
                                                 u16* __restrict__ wf_lo) {
    const int idx = blockIdx.x * 256 + threadIdx.x;
    const int lane = idx & 63;
    const int cb = idx / (32 * 64);
    const int g = (idx >> 6) % 32;
    const int C = cb * 32 + (lane & 31);
    const int gate = ((C >> 4) & 3) * 512 + (C >> 6) * 16 + (C & 15);
    const int kh = lane >> 5;
    const size_t base = (size_t)idx * 8;
    #pragma unroll
    for (int e = 0; e < 8; ++e) {
        const int k = g * 16 + kh * 8 + e;
        const float w = Wc_ih[(size_t)gate * 512 + k] + Wc_hh[(size_t)gate * 512 + k];
        u16 hi, lo; split_bf(w, hi, lo);
        wf_hi[base + e] = hi; wf_lo[base + e] = lo;
    }
}

__global__ __launch_bounds__(256) void k_prep_w1(const float* __restrict__ W1,
                                                 u16* __restrict__ wf_hi,
                                                 u16* __restrict__ wf_lo) {
    const int idx = blockIdx.x * 256 + threadIdx.x;
    const int lane = idx & 63;
    const int cb = idx / (64 * 64);
    const int g = (idx >> 6) % 64;
    const int n = cb * 32 + (lane & 31);
    const int kh = lane >> 5;
    const size_t base = (size_t)idx * 8;
    #pragma unroll
    for (int e = 0; e < 8; ++e) {
        const int k = g * 16 + kh * 8 + e;
        const float w = W1[(size_t)n * 1024 + k];
        u16 hi, lo; split_bf(w, hi, lo);
        wf_hi[base + e] = hi; wf_lo[base + e] = lo;
    }
}

__global__ __launch_bounds__(256) void k_prep_x(const float* __restrict__ x,
                                                u16* __restrict__ xf_hi,
                                                u16* __restrict__ xf_lo) {
    const int idx = blockIdx.x * 256 + threadIdx.x;
    const int lane = idx & 63;
    const int g = (idx >> 6) & 3;
    const int rb = (idx >> 8) & 15;
    const int t = idx >> 12;
    const int b = rb * 32 + (lane & 31);
    const int kh = lane >> 5;
    const size_t base = (size_t)idx * 8;
    #pragma unroll
    for (int e = 0; e < 8; ++e) {
        const int i = g * 16 + kh * 8 + e;
        const float w = x[((size_t)b * Tz + t) * INz + i];
        u16 hi, lo; split_bf(w, hi, lo);
        xf_hi[base + e] = hi; xf_lo[base + e] = lo;
    }
}

// ---------------- grid barrier; acquire-fence (buffer_inv) every 8th generation ----------------
static __device__ __forceinline__ void gsync(unsigned* sync, unsigned target, int bid) {
    __syncthreads();
    const int tid = threadIdx.x;
    unsigned* arr  = sync + 64;
    unsigned* grel = sync + 64 + 4096;
    if (bid == 0) {
        if (tid < 64) {
            if (tid == 0) astu(&arr[0], target);
            bool done = false;
            while (!done) {
                unsigned mn = 0xffffffffu;
                #pragma unroll
                for (int k = 0; k < 4; ++k) {
                    const unsigned v = aldu(&arr[(tid * 4 + k) * 16]);
                    mn = v < mn ? v : mn;
                }
                done = (bool)__all((int)(mn >= target));
                if (!done) __builtin_amdgcn_s_sleep(1);
            }
            if (tid < 16) astu(&grel[tid * 16], target);
        }
    } else {
        if (tid == 0) {
            astu(&arr[bid * 16], target);
            while (aldu(&grel[(bid >> 4) * 16]) < target)
                __builtin_amdgcn_s_sleep(1);
        }
    }
    if ((target & 7u) == 0u && tid == 0)
        __builtin_amdgcn_fence(__ATOMIC_ACQUIRE, "agent");   // periodic buffer_inv
    __syncthreads();
}

// ---------------- gates + cell: grid bid = bi*16 + ji (XCD = ji%8, weights L2-local) ----------------
// Tile: 32 batches (bi) x 128 gate-cols (ji). Burst-stage h (64 KB) into LDS for MLP;
// K-loop reads A via ds_read_b128, B via L2-warm global with PF-deep register pipeline.
// 8 waves = wc(4 col-blocks of 32) x kh(2 K-halves); Gt[2] halves summed in cell update.
template<int NG, int GX>
__device__ __forceinline__ void gates_phase(
    const u16* __restrict__ xf_hi, const u16* __restrict__ xf_lo, int t,
    const u16* __restrict__ wf_hi, const u16* __restrict__ wf_lo,
    const u16* __restrict__ hin_hi, const u16* __restrict__ hin_lo,
    const float* __restrict__ bias,
    float (&c2)[2], float* __restrict__ h_f32,
    u16* __restrict__ hout_hi, u16* __restrict__ hout_lo,
    float* __restrict__ buf_enc, int slot,
    u16* A_hi, u16* A_lo, float* Gt, int bid, int tid)
{
    const int lane = tid & 63, wid = tid >> 6;
    const int wc = wid & 3, kh = wid >> 2;
    const int ji = bid & 15, bi = bid >> 4;

    // ---- burst-stage h slice (32 granules, 64 KB hi+lo) into LDS ----
    {
        float4 vh[4], vl[4];
        #pragma unroll
        for (int it = 0; it < 4; ++it) {
            const int sl = it * 512 + tid;                 // [0,2048)
            const size_t off = ((size_t)bi * 32 + (sl >> 6)) * 512 + (size_t)(sl & 63) * 8;
            vh[it] = *(const float4*)(hin_hi + off);
            vl[it] = *(const float4*)(hin_lo + off);
        }
        #pragma unroll
        for (int it = 0; it < 4; ++it) {
            const int sl = it * 512 + tid;
            *(float4*)(A_hi + (size_t)sl * 8) = vh[it];
            *(float4*)(A_lo + (size_t)sl * 8) = vl[it];
        }
    }
    __syncthreads();

    // ---- K-loop: col-block cb = ji*4+wc, K-half kh; A from LDS/x-global, B global ----
    constexpr int NGH = NG / 2;
    const int g0 = kh * NGH;
    const int cb = ji * 4 + wc;
    const u16* pbh = wf_hi + ((size_t)cb * NG) * 512 + lane * 8;
    const u16* pbl = wf_lo + ((size_t)cb * NG) * 512 + lane * 8;

    floatx16 acc0, acc1, acc2;
    #pragma unroll
    for (int i = 0; i < 16; ++i) { acc0[i] = 0.f; acc1[i] = 0.f; acc2[i] = 0.f; }

    short8 ah[PF], al[PF], bh[PF], bl[PF];

    #pragma unroll
    for (int i = 0; i < NGH + PF; ++i) {
        if (i >= PF) {   // consume granule g0 + i - PF
            const int s = (i - PF) % PF;
            acc0 = __builtin_amdgcn_mfma_f32_32x32x16_bf16(ah[s], bh[s], acc0, 0, 0, 0);
            acc1 = __builtin_amdgcn_mfma_f32_32x32x16_bf16(ah[s], bl[s], acc1, 0, 0, 0);
            acc2 = __builtin_amdgcn_mfma_f32_32x32x16_bf16(al[s], bh[s], acc2, 0, 0, 0);
        }
        if (i < NGH) {   // refill slot with granule g0+i
            const int s = i % PF;
            const int g = g0 + i;
            if (GX > 0 && g < GX) {   // x: direct cached global
                const size_t off = (((size_t)t * 16 + bi) * GX + g) * 512 + (size_t)lane * 8;
                ah[s] = *(const short8*)(xf_hi + off);
                al[s] = *(const short8*)(xf_lo + off);
            } else {                   // h: from LDS (conflict-free ds_read_b128)
                const int gh = g - GX;
                ah[s] = *(const short8*)(A_hi + ((size_t)gh * 64 + lane) * 8);
                al[s] = *(const short8*)(A_lo + ((size_t)gh * 64 + lane) * 8);
            }
            bh[s] = *(const short8*)(pbh + (size_t)g * 512);
            bl[s] = *(const short8*)(pbl + (size_t)g * 512);
        }
    }
    #pragma unroll
    for (int i = 0; i < 16; ++i) acc0[i] += acc1[i] + acc2[i];

    // ---- Gt overlays A region: sync (all A-reads done), dump, sync ----
    __syncthreads();
    {
        const int col = wc * 32 + (lane & 31);
        const int rb4 = 4 * (lane >> 5);
        float* G = Gt + (size_t)kh * 4224;   // [2][32][132]
        #pragma unroll
        for (int r = 0; r < 16; ++r)
            G[(rb4 + (r & 3) + 8 * (r >> 2)) * 132 + col] = acc0[r];
    }
    __syncthreads();

    // ---- cell update: thread -> (b = bi*32 + tid>>4, 2 consecutive j); c in VGPRs ----
    {
        const int bl2 = tid >> 4, jq = tid & 15;
        const int b = bi * 32 + bl2;
        const int j0 = ji * 32 + jq * 2;
        float hn2[2];
        unsigned phi = 0, plo = 0;
        #pragma unroll
        for (int e = 0; e < 2; ++e) {
            const int jl = jq * 2 + e;
            const int Cl = ((jl >> 4) << 6) | (jl & 15);
            const float* gp = Gt + (size_t)bl2 * 132 + Cl;
            const float* gq = gp + 4224;
            const float gi = gp[0]  + gq[0]  + bias[j0 + e];
            const float gf = gp[16] + gq[16] + bias[512 + j0 + e];
            const float gg = gp[32] + gq[32] + bias[1024 + j0 + e];
            const float go = gp[48] + gq[48] + bias[1536 + j0 + e];
            const float si = 1.f / (1.f + __expf(-gi));
            const float sf = 1.f / (1.f + __expf(-gf));
            const float so = 1.f / (1.f + __expf(-go));
            const float cn = sf * c2[e] + si * tanhf(gg);
            const float hn = so * tanhf(cn);
            c2[e] = cn; hn2[e] = hn;
            u16 hi, lo; split_bf(hn, hi, lo);
            phi |= (unsigned)hi << (16 * e);
            plo |= (unsigned)lo << (16 * e);
        }
        const int rb = bi, gran = j0 >> 4;
        const int fl = ((j0 >> 3) & 1) * 32 + (b & 31);
        const size_t fo = (((size_t)rb * 32 + gran) * 64 + fl) * 8 + (j0 & 7);
        astu16x2(hout_hi + fo, phi);    // sc1: fresh at MALL for all XCDs
        astu16x2(hout_lo + fo, plo);
        if (slot >= 0)
            ast64f(buf_enc + ((size_t)b * TSz + slot) * Hz + j0, hn2[0], hn2[1]);
        if (h_f32 != nullptr)
            ast64f(h_f32 + (size_t)b * Hz + j0, hn2[0], hn2[1]);
    }
}

// ---------------- attention: 2 batches/block; reads cached (rotated / write-once) ----------------
__device__ __forceinline__ void attn_phase(const float* __restrict__ h_f32,
                                           const float* __restrict__ buf_enc,
                                           float* __restrict__ buf_dec,
                                           u16* __restrict__ ctx_hi, u16* __restrict__ ctx_lo,
                                           int sd, float* lds, int bid, int tid) {
    const int grp = tid >> 8;
    const int t8 = tid & 255;
    const int b = bid * 2 + grp;
    float* sh = lds + grp * 544;
    float* sa = sh + 512;
    {
        const int i0 = t8 * 2;
        const float2 hv = *(const float2*)(h_f32 + (size_t)b * Hz + i0);
        sh[i0] = hv.x; sh[i0 + 1] = hv.y;
    }
    __syncthreads();
    {
        const int w = t8 >> 3, l8 = t8 & 7;
        const float* v = (w < TSz - sd)
            ? buf_enc + ((size_t)b * TSz + (sd + w)) * Hz
            : buf_dec + (size_t)(w - TSz + sd) * BH + (size_t)b * Hz;
        float p = 0.f;
        for (int j = l8; j < Hz; j += 8) p = fmaf(sh[j], v[j], p);
        p += __shfl_xor(p, 1); p += __shfl_xor(p, 2); p += __shfl_xor(p, 4);
        if (l8 == 0) sa[w] = p;
    }
    __syncthreads();
    if (t8 < TSz) {
        const float v = sa[t8];
        float m = v;
        #pragma unroll
        for (int d = 1; d < 32; d <<= 1) m = fmaxf(m, __shfl_xor(m, d));
        const float e = __expf(v - m);
        float ss = e;
        #pragma unroll
        for (int d = 1; d < 32; d <<= 1) ss += __shfl_xor(ss, d);
        sa[t8] = e / ss;
    }
    __syncthreads();
    {
        const int j0 = t8 * 2;
        float a0 = 0.f, a1 = 0.f;
        for (int w2 = 0; w2 < TSz; ++w2) {
            const float* vp = (w2 < TSz - sd)
                ? buf_enc + ((size_t)b * TSz + (sd + w2)) * Hz + j0
                : buf_dec + (size_t)(w2 - TSz + sd) * BH + (size_t)b * Hz + j0;
            const float2 vv = *(const float2*)vp;
            a0 = fmaf(sa[w2], vv.x, a0);
            a1 = fmaf(sa[w2], vv.y, a1);
        }
        u16 h0, l0, h1, l1;
        split_bf(a0, h0, l0); split_bf(a1, h1, l1);
        const int rb = b >> 5, gran = j0 >> 4;
        const int fl = ((j0 >> 3) & 1) * 32 + (b & 31);
        const size_t fo = (((size_t)rb * 32 + gran) * 64 + fl) * 8 + (j0 & 7);
        astu16x2(ctx_hi + fo, (unsigned)h0 | ((unsigned)h1 << 16));
        astu16x2(ctx_lo + fo, (unsigned)l0 | ((unsigned)l1 << 16));
    }
    {
        const int i0 = t8 * 2;
        ast64f(buf_dec + (size_t)sd * BH + (size_t)b * Hz + i0, sh[i0], sh[i0 + 1]);
    }
}

// ---------------- MLP + partial out: 8-wave K-split; A reads cached (rotated) ----------------
__device__ __forceinline__ void mlp_phase(
    const u16* __restrict__ ctx_hi, const u16* __restrict__ ctx_lo,
    const u16* __restrict__ h_hi,   const u16* __restrict__ h_lo,
    const u16* __restrict__ w1_hi,  const u16* __restrict__ w1_lo,
    const float* __restrict__ b1, const float* __restrict__ W2,
    float* __restrict__ part_p, float* lds, int bid, int tid)
{
    const int lane = tid & 63, w = tid >> 6;
    const int ni = bid & 15, bi2 = bid >> 4;

    floatx16 acc0, acc1, acc2;
    #pragma unroll
    for (int i = 0; i < 16; ++i) { acc0[i] = 0.f; acc1[i] = 0.f; acc2[i] = 0.f; }

    short8 ah[4], al[4], bh[4], bl[4];

    #pragma unroll
    for (int i = 0; i < 8 + 4; ++i) {
        if (i >= 4) {
            const int s = (i - 4) & 3;
            acc0 = __builtin_amdgcn_mfma_f32_32x32x16_bf16(ah[s], bh[s], acc0, 0, 0, 0);
            acc1 = __builtin_amdgcn_mfma_f32_32x32x16_bf16(ah[s], bl[s], acc1, 0, 0, 0);
            acc2 = __builtin_amdgcn_mfma_f32_32x32x16_bf16(al[s], bh[s], acc2, 0, 0, 0);
        }
        if (i < 8) {
            const int s = i & 3;
            const int g = w * 8 + i;
            if (g < 32) {
                const size_t off = (((size_t)bi2 * 32 + g) * 64 + lane) * 8;
                ah[s] = *(const short8*)(ctx_hi + off);
                al[s] = *(const short8*)(ctx_lo + off);
            } else {
                const size_t off = (((size_t)bi2 * 32 + (g - 32)) * 64 + lane) * 8;
                ah[s] = *(const short8*)(h_hi + off);
                al[s] = *(const short8*)(h_lo + off);
            }
            const size_t boff = (((size_t)ni * 64 + g) * 64 + lane) * 8;
            bh[s] = *(const short8*)(w1_hi + boff);
            bl[s] = *(const short8*)(w1_lo + boff);
        }
    }
    #pragma unroll
    for (int i = 0; i < 16; ++i) acc0[i] += acc1[i] + acc2[i];

    {
        const int col = lane & 31;
        const int rb4 = 4 * (lane >> 5);
        #pragma unroll
        for (int r = 0; r < 16; ++r)
            lds[w * 1024 + (rb4 + (r & 3) + 8 * (r >> 2)) * 32 + col] = acc0[r];
    }
    __syncthreads();

    const int row = tid >> 4, l16 = tid & 15;
    float a = 0.f;
    #pragma unroll
    for (int jj = 0; jj < 2; ++jj) {
        const int col = l16 * 2 + jj;
        const int ncol = ni * 32 + col;
        float pre = b1[ncol];
        #pragma unroll
        for (int ww = 0; ww < 8; ++ww) pre += lds[ww * 1024 + row * 32 + col];
        a = fmaf(tanhf(pre), W2[ncol], a);
    }
    a += __shfl_xor(a, 1); a += __shfl_xor(a, 2);
    a += __shfl_xor(a, 4); a += __shfl_xor(a, 8);
    if (l16 == 0) astf(&part_p[ni * 512 + bi2 * 32 + row], a);
}

__device__ __forceinline__ void y_reduce(const float* __restrict__ part_p,
                                         const float* __restrict__ b2,
                                         float* __restrict__ y, int s, int bid, int tid) {
    if (tid < 2) {
        const int b = bid * 2 + tid;
        float a = b2[0];
        #pragma unroll
        for (int ni = 0; ni < 16; ++ni) a += aldf(&part_p[ni * 512 + b]);
        astf(&y[(size_t)b * PLz + s], a);
    }
}

// ---------------- the persistent kernel ----------------
struct KParams {
    const u16 *xf_hi, *xf_lo, *wf_hi, *wf_lo, *wcf_hi, *wcf_lo, *w1f_hi, *w1f_lo;
    const float *b_l, *b_c, *b1, *W2, *b2;
    float *h_f32rot, *buf_enc, *buf_dec, *part_p, *y;
    u16 *hrot_hi, *hrot_lo, *ctxrot_hi, *ctxrot_lo;
    unsigned *sync;
};

__global__ __launch_bounds__(NTHR, 1) void k_persist(KParams p) {
    __shared__ char smem[65536];
    u16* A_hi = (u16*)smem;                 // 32 KB (staged h hi)
    u16* A_lo = (u16*)(smem + 32768);       // 32 KB (staged h lo)
    float* Gt = (float*)smem;               // [2][32][132] = 33 KB, overlays A after sync
    float* scr = (float*)smem;              // attn/mlp scratch

    const int bid = blockIdx.x;
    const int tid = threadIdx.x;
    unsigned gen = 1;
    float c2[2] = {0.f, 0.f};   // persistent cell state

    // encoder: 128 steps; h rotation depth 16, ring slots write-once (t>=96)
    for (int t = 0; t < Tz; ++t) {
        const int si = (t + 15) & 15, so = t & 15;
        gates_phase<36, 4>(p.xf_hi, p.xf_lo, t, p.wf_hi, p.wf_lo,
                           p.hrot_hi + (size_t)si * BH, p.hrot_lo + (size_t)si * BH,
                           p.b_l, c2, nullptr,
                           p.hrot_hi + (size_t)so * BH, p.hrot_lo + (size_t)so * BH,
                           p.buf_enc, t - 96, A_hi, A_lo, Gt, bid, tid);
        gsync(p.sync, gen++, bid);
    }
    // decoder: 32 iterations (gates | attn | mlp)
    for (int sd = 0; sd < PLz; ++sd) {
        if (sd > 0) y_reduce(p.part_p, p.b2, p.y, sd - 1, bid, tid);
        const int si = (sd + 15) & 15, so = sd & 15;
        float* hf = p.h_f32rot + (size_t)(sd & 3) * BH;
        u16* cx_hi = p.ctxrot_hi + (size_t)(sd & 3) * BH;
        u16* cx_lo = p.ctxrot_lo + (size_t)(sd & 3) * BH;
        gates_phase<32, 0>(nullptr, nullptr, 0, p.wcf_hi, p.wcf_lo,
                           p.hrot_hi + (size_t)si * BH, p.hrot_lo + (size_t)si * BH,
                           p.b_c, c2, hf,
                           p.hrot_hi + (size_t)so * BH, p.hrot_lo + (size_t)so * BH,
                           nullptr, -1, A_hi, A_lo, Gt, bid, tid);
        gsync(p.sync, gen++, bid);
        attn_phase(hf, p.buf_enc, p.buf_dec, cx_hi, cx_lo, sd, scr, bid, tid);
        gsync(p.sync, gen++, bid);
        mlp_phase(cx_hi, cx_lo,
                  p.hrot_hi + (size_t)so * BH, p.hrot_lo + (size_t)so * BH,
                  p.w1f_hi, p.w1f_lo, p.b1, p.W2, p.part_p, scr, bid, tid);
        gsync(p.sync, gen++, bid);
    }
    y_reduce(p.part_p, p.b2, p.y, PLz - 1, bid, tid);
}

extern "C" void kernel_launch(void* const* d_in, const int* in_sizes, int n_in,
                              void* d_out, int out_size, void* d_ws, size_t ws_size,
                              hipStream_t stream) {
    (void)in_sizes; (void)n_in; (void)out_size; (void)ws_size;
    const float* x     = (const float*)d_in[0];
    const float* W_ih  = (const float*)d_in[1];
    const float* W_hh  = (const float*)d_in[2];
    const float* b_l   = (const float*)d_in[3];
    const float* Wc_ih = (const float*)d_in[4];
    const float* Wc_hh = (const float*)d_in[5];
    const float* b_c   = (const float*)d_in[6];
    const float* W1    = (const float*)d_in[7];
    const float* b1    = (const float*)d_in[8];
    const float* W2    = (const float*)d_in[9];
    const float* b2    = (const float*)d_in[10];
    float* y = (float*)d_out;

    float* w = (float*)d_ws;
    float* h_f32rot = w;                             // 4*BH
    float* buf_enc  = w + 4 * (size_t)BH;            // 32*BH
    float* buf_dec  = w + 36 * (size_t)BH;           // 32*BH
    float* part_p   = w + 68 * (size_t)BH;           // 8192
    unsigned* sync  = (unsigned*)(w + 68 * (size_t)BH + 8192);   // 8192 u32
    u16* us = (u16*)(w + 68 * (size_t)BH + 8192 + 8192);
    u16* hrot_hi = us;   us += 16 * (size_t)BH;
    u16* hrot_lo = us;   us += 16 * (size_t)BH;
    u16* ctxrot_hi = us; us += 4 * (size_t)BH;
    u16* ctxrot_lo = us; us += 4 * (size_t)BH;
    u16* xf_hi = us;   us += 4194304;
    u16* xf_lo = us;   us += 4194304;
    u16* wf_hi = us;   us += 1179648;
    u16* wf_lo = us;   us += 1179648;
    u16* wcf_hi = us;  us += 1048576;
    u16* wcf_lo = us;  us += 1048576;
    u16* w1f_hi = us;  us += 524288;
    u16* w1f_lo = us;  us += 524288;

    k_init     <<<1024, 256, 0, stream>>>(hrot_hi + 15 * (size_t)BH,
                                          hrot_lo + 15 * (size_t)BH, sync);
    k_prep_wenc<<<576,  256, 0, stream>>>(W_ih, W_hh, wf_hi, wf_lo);
    k_prep_wc  <<<512,  256, 0, stream>>>(Wc_ih, Wc_hh, wcf_hi, wcf_lo);
    k_prep_w1  <<<256,  256, 0, stream>>>(W1, w1f_hi, w1f_lo);
    k_prep_x   <<<2048, 256, 0, stream>>>(x, xf_hi, xf_lo);

    KParams prm;
    prm.xf_hi = xf_hi;   prm.xf_lo = xf_lo;
    prm.wf_hi = wf_hi;   prm.wf_lo = wf_lo;
    prm.wcf_hi = wcf_hi; prm.wcf_lo = wcf_lo;
    prm.w1f_hi = w1f_hi; prm.w1f_lo = w1f_lo;
    prm.b_l = b_l; prm.b_c = b_c; prm.b1 = b1; prm.W2 = W2; prm.b2 = b2;
    prm.h_f32rot = h_f32rot; prm.buf_enc = buf_enc; prm.buf_dec = buf_dec;
    prm.part_p = part_p; prm.y = y;
    prm.hrot_hi = hrot_hi; prm.hrot_lo = hrot_lo;
    prm.ctxrot_hi = ctxrot_hi; prm.ctxrot_lo = ctxrot_lo;
    prm.sync = sync;

    k_persist<<<dim3(NBLK), dim3(NTHR), 0, stream>>>(prm);
}

// Round 13
// 2200.824 us; speedup vs baseline: 1.6773x; 1.2474x over previous
//
#include <hip/hip_runtime.h>
#include <hip/hip_bf16.h>
#include <math.h>

// Problem sizes
#define Bz   512
#define Tz   128
#define INz  64
#define Hz   512
#define TSz  32
#define PLz  32
#define BH   (Bz * Hz)          // 262144
#define NBLK 256
#define NTHR 512
#define PF   6

typedef unsigned short u16;
typedef unsigned long long u64;
typedef __attribute__((ext_vector_type(8)))  short short8;
typedef __attribute__((ext_vector_type(16))) float floatx16;

static __device__ __forceinline__ void split_bf(float w, u16& hi, u16& lo) {
    __hip_bfloat16 h = __float2bfloat16(w);
    hi = *reinterpret_cast<u16*>(&h);
    float r = w - __bfloat162float(h);
    __hip_bfloat16 l = __float2bfloat16(r);
    lo = *reinterpret_cast<u16*>(&l);
}

union FU  { unsigned u; float f; };
union F2U { u64 q; float f[2]; };

static __device__ __forceinline__ float b2f(u16 v) {
    FU c; c.u = ((unsigned)v) << 16; return c.f;
}
static __device__ __forceinline__ u16 f2b(float f) {
    __hip_bfloat16 h = __float2bfloat16(f);
    return *reinterpret_cast<u16*>(&h);
}

// ---- sc1 (coherence-point / MALL) STORE helpers + sync atomics ----
static __device__ __forceinline__ float aldf(const float* p) {
    FU c; c.u = __hip_atomic_load((const unsigned*)p, __ATOMIC_RELAXED, __HIP_MEMORY_SCOPE_AGENT);
    return c.f;
}
static __device__ __forceinline__ void ast64f(float* p, float a, float b) {
    F2U u; u.f[0] = a; u.f[1] = b;
    __hip_atomic_store((u64*)p, u.q, __ATOMIC_RELAXED, __HIP_MEMORY_SCOPE_AGENT);
}
static __device__ __forceinline__ void astf(float* p, float v) {
    FU c; c.f = v;
    __hip_atomic_store((unsigned*)p, c.u, __ATOMIC_RELAXED, __HIP_MEMORY_SCOPE_AGENT);
}
static __device__ __forceinline__ unsigned aldu(const unsigned* p) {
    return __hip_atomic_load(p, __ATOMIC_RELAXED, __HIP_MEMORY_SCOPE_AGENT);
}
static __device__ __forceinline__ void astu(unsigned* p, unsigned v) {
    __hip_atomic_store(p, v, __ATOMIC_RELAXED, __HIP_MEMORY_SCOPE_AGENT);
}
static __device__ __forceinline__ void astu16x2(u16* p, unsigned v) {
    __hip_atomic_store((unsigned*)p, v, __ATOMIC_RELAXED, __HIP_MEMORY_SCOPE_AGENT);
}

// ---------------- init: zero hrot slot 15 + sync area ----------------
__global__ __launch_bounds__(256) void k_init(u16* __restrict__ h15_hi,
                                              u16* __restrict__ h15_lo,
                                              unsigned* __restrict__ sync) {
    const int i = blockIdx.x * 256 + threadIdx.x;
    if (i < BH) { h15_hi[i] = 0; h15_lo[i] = 0; }
    if (i < 8192) sync[i] = 0;
}

// ---------------- prep kernels (verified, unchanged) ----------------
__global__ __launch_bounds__(256) void k_prep_wenc(const float* __restrict__ W_ih,
                                                   const float* __restrict__ W_hh,
                                                   u16* __restrict__ wf_hi,
                                                   u16* __restrict__ wf_lo) {
    const int idx = blockIdx.x * 256 + threadIdx.x;
    const int lane = idx & 63;
    const int g = (idx >> 6) % 36;
    const int cb = idx / (36 * 64);
    const int C = cb * 32 + (lane & 31);
    const int gate = ((C >> 4) & 3) * 512 + (C >> 6) * 16 + (C & 15);
    const int kh = lane >> 5;
    const size_t base = (size_t)idx * 8;
    #pragma unroll
    for (int e = 0; e < 8; ++e) {
        const int k = g * 16 + kh * 8 + e;
        const float w = (k < 64) ? W_ih[(size_t)gate * 64 + k]
                                 : W_hh[(size_t)gate * 512 + (k - 64)];
        u16 hi, lo; split_bf(w, hi, lo);
        wf_hi[base + e] = hi; wf_lo[base + e] = lo;
    }
}

__global__ __launch_bounds__(256) void k_prep_wc(const float* __restrict__ Wc_ih,
                                                 const float* __restrict__ Wc_hh,
                                                 u16* __restrict__ wf_hi,
                                                 u16* __restrict__ wf_lo) {
    const int idx = blockIdx.x * 256 + threadIdx.x;
    const int lane = idx & 63;
    const int cb = idx / (32 * 64);
    const int g = (idx >> 6) % 32;
    const int C = cb * 32 + (lane & 31);
    const int gate = ((C >> 4) & 3) * 512 + (C >> 6) * 16 + (C & 15);
    const int kh = lane >> 5;
    const size_t base = (size_t)idx * 8;
    #pragma unroll
    for (int e = 0; e < 8; ++e) {
        const int k = g * 16 + kh * 8 + e;
        const float w = Wc_ih[(size_t)gate * 512 + k] + Wc_hh[(size_t)gate * 512 + k];
        u16 hi, lo; split_bf(w, hi, lo);
        wf_hi[base + e] = hi; wf_lo[base + e] = lo;
    }
}

__global__ __launch_bounds__(256) void k_prep_w1(const float* __restrict__ W1,
                                                 u16* __restrict__ wf_hi,
                                                 u16* __restrict__ wf_lo) {
    const int idx = blockIdx.x * 256 + threadIdx.x;
    const int lane = idx & 63;
    const int cb = idx / (64 * 64);
    const int g = (idx >> 6) % 64;
    const int n = cb * 32 + (lane & 31);
    const int kh = lane >> 5;
    const size_t base = (size_t)idx * 8;
    #pragma unroll
    for (int e = 0; e < 8; ++e) {
        const int k = g * 16 + kh * 8 + e;
        const float w = W1[(size_t)n * 1024 + k];
        u16 hi, lo; split_bf(w, hi, lo);
        wf_hi[base + e] = hi; wf_lo[base + e] = lo;
    }
}

__global__ __launch_bounds__(256) void k_prep_x(const float* __restrict__ x,
                                                u16* __restrict__ xf_hi,
                                                u16* __restrict__ xf_lo) {
    const int idx = blockIdx.x * 256 + threadIdx.x;
    const int lane = idx & 63;
    const int g = (idx >> 6) & 3;
    const int rb = (idx >> 8) & 15;
    const int t = idx >> 12;
    const int b = rb * 32 + (lane & 31);
    const int kh = lane >> 5;
    const size_t base = (size_t)idx * 8;
    #pragma unroll
    for (int e = 0; e < 8; ++e) {
        const int i = g * 16 + kh * 8 + e;
        const float w = x[((size_t)b * Tz + t) * INz + i];
        u16 hi, lo; split_bf(w, hi, lo);
        xf_hi[base + e] = hi; xf_lo[base + e] = lo;
    }
}

// ---------------- grid barrier; acquire-fence (buffer_inv) every 8th generation ----------------
static __device__ __forceinline__ void gsync(unsigned* sync, unsigned target, int bid) {
    __syncthreads();
    const int tid = threadIdx.x;
    unsigned* arr  = sync + 64;
    unsigned* grel = sync + 64 + 4096;
    if (bid == 0) {
        if (tid < 64) {
            if (tid == 0) astu(&arr[0], target);
            bool done = false;
            while (!done) {
                unsigned mn = 0xffffffffu;
                #pragma unroll
                for (int k = 0; k < 4; ++k) {
                    const unsigned v = aldu(&arr[(tid * 4 + k) * 16]);
                    mn = v < mn ? v : mn;
                }
                done = (bool)__all((int)(mn >= target));
                if (!done) __builtin_amdgcn_s_sleep(1);
            }
            if (tid < 16) astu(&grel[tid * 16], target);
        }
    } else {
        if (tid == 0) {
            astu(&arr[bid * 16], target);
            while (aldu(&grel[(bid >> 4) * 16]) < target)
                __builtin_amdgcn_s_sleep(1);
        }
    }
    if ((target & 7u) == 0u && tid == 0)
        __builtin_amdgcn_fence(__ATOMIC_ACQUIRE, "agent");   // periodic buffer_inv
    __syncthreads();
}

// ---------------- gates + cell: 2D-remapped (ji,bi); XCD = (ji&3)|((bi&1)<<2) ----------------
// Tile: 32 batches (bi) x 128 gate-cols (ji). Burst-stage h (64 KB) into LDS;
// K-loop reads A via ds_read_b128, B via L2-warm global with PF-deep register pipeline.
template<int NG, int GX>
__device__ __forceinline__ void gates_phase(
    const u16* __restrict__ xf_hi, const u16* __restrict__ xf_lo, int t,
    const u16* __restrict__ wf_hi, const u16* __restrict__ wf_lo,
    const u16* __restrict__ hin_hi, const u16* __restrict__ hin_lo,
    const float* __restrict__ bias,
    float (&c2)[2], float* __restrict__ h_f32,
    u16* __restrict__ hout_hi, u16* __restrict__ hout_lo,
    u16* __restrict__ buf_enc, int slot,
    u16* A_hi, u16* A_lo, float* Gt, int ji, int bi, int tid)
{
    const int lane = tid & 63, wid = tid >> 6;
    const int wc = wid & 3, kh = wid >> 2;

    // ---- burst-stage h slice (32 granules, 64 KB hi+lo) into LDS ----
    {
        float4 vh[4], vl[4];
        #pragma unroll
        for (int it = 0; it < 4; ++it) {
            const int sl = it * 512 + tid;                 // [0,2048)
            const size_t off = ((size_t)bi * 32 + (sl >> 6)) * 512 + (size_t)(sl & 63) * 8;
            vh[it] = *(const float4*)(hin_hi + off);
            vl[it] = *(const float4*)(hin_lo + off);
        }
        #pragma unroll
        for (int it = 0; it < 4; ++it) {
            const int sl = it * 512 + tid;
            *(float4*)(A_hi + (size_t)sl * 8) = vh[it];
            *(float4*)(A_lo + (size_t)sl * 8) = vl[it];
        }
    }
    __syncthreads();

    // ---- K-loop: col-block cb = ji*4+wc, K-half kh; A from LDS/x-global, B global ----
    constexpr int NGH = NG / 2;
    const int g0 = kh * NGH;
    const int cb = ji * 4 + wc;
    const u16* pbh = wf_hi + ((size_t)cb * NG) * 512 + lane * 8;
    const u16* pbl = wf_lo + ((size_t)cb * NG) * 512 + lane * 8;

    floatx16 acc0, acc1, acc2;
    #pragma unroll
    for (int i = 0; i < 16; ++i) { acc0[i] = 0.f; acc1[i] = 0.f; acc2[i] = 0.f; }

    short8 ah[PF], al[PF], bh[PF], bl[PF];

    #pragma unroll
    for (int i = 0; i < NGH + PF; ++i) {
        if (i >= PF) {   // consume granule g0 + i - PF
            const int s = (i - PF) % PF;
            acc0 = __builtin_amdgcn_mfma_f32_32x32x16_bf16(ah[s], bh[s], acc0, 0, 0, 0);
            acc1 = __builtin_amdgcn_mfma_f32_32x32x16_bf16(ah[s], bl[s], acc1, 0, 0, 0);
            acc2 = __builtin_amdgcn_mfma_f32_32x32x16_bf16(al[s], bh[s], acc2, 0, 0, 0);
        }
        if (i < NGH) {   // refill slot with granule g0+i
            const int s = i % PF;
            const int g = g0 + i;
            if (GX > 0 && g < GX) {   // x: direct cached global
                const size_t off = (((size_t)t * 16 + bi) * GX + g) * 512 + (size_t)lane * 8;
                ah[s] = *(const short8*)(xf_hi + off);
                al[s] = *(const short8*)(xf_lo + off);
            } else {                   // h: from LDS (conflict-free ds_read_b128)
                const int gh = g - GX;
                ah[s] = *(const short8*)(A_hi + ((size_t)gh * 64 + lane) * 8);
                al[s] = *(const short8*)(A_lo + ((size_t)gh * 64 + lane) * 8);
            }
            bh[s] = *(const short8*)(pbh + (size_t)g * 512);
            bl[s] = *(const short8*)(pbl + (size_t)g * 512);
        }
    }
    #pragma unroll
    for (int i = 0; i < 16; ++i) acc0[i] += acc1[i] + acc2[i];

    // ---- Gt overlays A region: sync (all A-reads done), dump, sync ----
    __syncthreads();
    {
        const int col = wc * 32 + (lane & 31);
        const int rb4 = 4 * (lane >> 5);
        float* G = Gt + (size_t)kh * 4224;   // [2][32][132]
        #pragma unroll
        for (int r = 0; r < 16; ++r)
            G[(rb4 + (r & 3) + 8 * (r >> 2)) * 132 + col] = acc0[r];
    }
    __syncthreads();

    // ---- cell update: thread -> (b = bi*32 + tid>>4, 2 consecutive j); c in VGPRs ----
    {
        const int bl2 = tid >> 4, jq = tid & 15;
        const int b = bi * 32 + bl2;
        const int j0 = ji * 32 + jq * 2;
        float hn2[2];
        unsigned phi = 0, plo = 0;
        #pragma unroll
        for (int e = 0; e < 2; ++e) {
            const int jl = jq * 2 + e;
            const int Cl = ((jl >> 4) << 6) | (jl & 15);
            const float* gp = Gt + (size_t)bl2 * 132 + Cl;
            const float* gq = gp + 4224;
            const float gi = gp[0]  + gq[0]  + bias[j0 + e];
            const float gf = gp[16] + gq[16] + bias[512 + j0 + e];
            const float gg = gp[32] + gq[32] + bias[1024 + j0 + e];
            const float go = gp[48] + gq[48] + bias[1536 + j0 + e];
            const float si = 1.f / (1.f + __expf(-gi));
            const float sf = 1.f / (1.f + __expf(-gf));
            const float so = 1.f / (1.f + __expf(-go));
            const float cn = sf * c2[e] + si * tanhf(gg);
            const float hn = so * tanhf(cn);
            c2[e] = cn; hn2[e] = hn;
            u16 hi, lo; split_bf(hn, hi, lo);
            phi |= (unsigned)hi << (16 * e);
            plo |= (unsigned)lo << (16 * e);
        }
        const int gran = j0 >> 4;
        const int fl = ((j0 >> 3) & 1) * 32 + (b & 31);
        const size_t fo = (((size_t)bi * 32 + gran) * 64 + fl) * 8 + (j0 & 7);
        astu16x2(hout_hi + fo, phi);    // sc1: fresh at MALL for all XCDs
        astu16x2(hout_lo + fo, plo);
        if (slot >= 0)
            astu16x2(buf_enc + ((size_t)b * TSz + slot) * Hz + j0, phi);  // bf16 ring
        if (h_f32 != nullptr)
            ast64f(h_f32 + (size_t)b * Hz + j0, hn2[0], hn2[1]);
    }
}

// ---------------- attention: 2 batches/block; bf16 ring, cached reads ----------------
__device__ __forceinline__ void attn_phase(const float* __restrict__ h_f32,
                                           const u16* __restrict__ buf_enc,
                                           u16* __restrict__ buf_dec,
                                           u16* __restrict__ ctx_hi, u16* __restrict__ ctx_lo,
                                           int sd, float* lds, int bid, int tid) {
    const int grp = tid >> 8;
    const int t8 = tid & 255;
    const int b = bid * 2 + grp;
    float* sh = lds + grp * 544;
    float* sa = sh + 512;
    {
        const int i0 = t8 * 2;
        const float2 hv = *(const float2*)(h_f32 + (size_t)b * Hz + i0);
        sh[i0] = hv.x; sh[i0 + 1] = hv.y;
    }
    __syncthreads();
    {   // 32 scores x 8 lanes; bf16 ring, ushort4 coalesced
        const int w = t8 >> 3, l8 = t8 & 7;
        const u16* v = (w < TSz - sd)
            ? buf_enc + ((size_t)b * TSz + (sd + w)) * Hz
            : buf_dec + (size_t)(w - TSz + sd) * BH + (size_t)b * Hz;
        float p = 0.f;
        #pragma unroll 4
        for (int k = 0; k < 16; ++k) {
            const int j = l8 * 4 + k * 32;
            const ushort4 q = *(const ushort4*)(v + j);
            p = fmaf(sh[j],     b2f(q.x), p);
            p = fmaf(sh[j + 1], b2f(q.y), p);
            p = fmaf(sh[j + 2], b2f(q.z), p);
            p = fmaf(sh[j + 3], b2f(q.w), p);
        }
        p += __shfl_xor(p, 1); p += __shfl_xor(p, 2); p += __shfl_xor(p, 4);
        if (l8 == 0) sa[w] = p;
    }
    __syncthreads();
    if (t8 < TSz) {
        const float v = sa[t8];
        float m = v;
        #pragma unroll
        for (int d = 1; d < 32; d <<= 1) m = fmaxf(m, __shfl_xor(m, d));
        const float e = __expf(v - m);
        float ss = e;
        #pragma unroll
        for (int d = 1; d < 32; d <<= 1) ss += __shfl_xor(ss, d);
        sa[t8] = e / ss;
    }
    __syncthreads();
    {   // ctx: 2 consecutive j per thread; bf16 ring reads; sc1 frag store
        const int j0 = t8 * 2;
        float a0 = 0.f, a1 = 0.f;
        for (int w2 = 0; w2 < TSz; ++w2) {
            const u16* vp = (w2 < TSz - sd)
                ? buf_enc + ((size_t)b * TSz + (sd + w2)) * Hz + j0
                : buf_dec + (size_t)(w2 - TSz + sd) * BH + (size_t)b * Hz + j0;
            const ushort2 vv = *(const ushort2*)vp;
            a0 = fmaf(sa[w2], b2f(vv.x), a0);
            a1 = fmaf(sa[w2], b2f(vv.y), a1);
        }
        u16 h0, l0, h1, l1;
        split_bf(a0, h0, l0); split_bf(a1, h1, l1);
        const int rb = b >> 5, gran = j0 >> 4;
        const int fl = ((j0 >> 3) & 1) * 32 + (b & 31);
        const size_t fo = (((size_t)rb * 32 + gran) * 64 + fl) * 8 + (j0 & 7);
        astu16x2(ctx_hi + fo, (unsigned)h0 | ((unsigned)h1 << 16));
        astu16x2(ctx_lo + fo, (unsigned)l0 | ((unsigned)l1 << 16));
    }
    {   // append h_sd to fresh buffer buf_dec[sd] (sc1, bf16, write-once)
        const int i0 = t8 * 2;
        const unsigned pk = (unsigned)f2b(sh[i0]) | ((unsigned)f2b(sh[i0 + 1]) << 16);
        astu16x2(buf_dec + (size_t)sd * BH + (size_t)b * Hz + i0, pk);
    }
}

// ---------------- MLP + partial out: 8-wave K-split; A reads cached (rotated) ----------------
__device__ __forceinline__ void mlp_phase(
    const u16* __restrict__ ctx_hi, const u16* __restrict__ ctx_lo,
    const u16* __restrict__ h_hi,   const u16* __restrict__ h_lo,
    const u16* __restrict__ w1_hi,  const u16* __restrict__ w1_lo,
    const float* __restrict__ b1, const float* __restrict__ W2,
    float* __restrict__ part_p, float* lds, int bid, int tid)
{
    const int lane = tid & 63, w = tid >> 6;
    const int ni = bid & 15, bi2 = bid >> 4;

    floatx16 acc0, acc1, acc2;
    #pragma unroll
    for (int i = 0; i < 16; ++i) { acc0[i] = 0.f; acc1[i] = 0.f; acc2[i] = 0.f; }

    short8 ah[4], al[4], bh[4], bl[4];

    #pragma unroll
    for (int i = 0; i < 8 + 4; ++i) {
        if (i >= 4) {
            const int s = (i - 4) & 3;
            acc0 = __builtin_amdgcn_mfma_f32_32x32x16_bf16(ah[s], bh[s], acc0, 0, 0, 0);
            acc1 = __builtin_amdgcn_mfma_f32_32x32x16_bf16(ah[s], bl[s], acc1, 0, 0, 0);
            acc2 = __builtin_amdgcn_mfma_f32_32x32x16_bf16(al[s], bh[s], acc2, 0, 0, 0);
        }
        if (i < 8) {
            const int s = i & 3;
            const int g = w * 8 + i;
            if (g < 32) {
                const size_t off = (((size_t)bi2 * 32 + g) * 64 + lane) * 8;
                ah[s] = *(const short8*)(ctx_hi + off);
                al[s] = *(const short8*)(ctx_lo + off);
            } else {
                const size_t off = (((size_t)bi2 * 32 + (g - 32)) * 64 + lane) * 8;
                ah[s] = *(const short8*)(h_hi + off);
                al[s] = *(const short8*)(h_lo + off);
            }
            const size_t boff = (((size_t)ni * 64 + g) * 64 + lane) * 8;
            bh[s] = *(const short8*)(w1_hi + boff);
            bl[s] = *(const short8*)(w1_lo + boff);
        }
    }
    #pragma unroll
    for (int i = 0; i < 16; ++i) acc0[i] += acc1[i] + acc2[i];

    {
        const int col = lane & 31;
        const int rb4 = 4 * (lane >> 5);
        #pragma unroll
        for (int r = 0; r < 16; ++r)
            lds[w * 1024 + (rb4 + (r & 3) + 8 * (r >> 2)) * 32 + col] = acc0[r];
    }
    __syncthreads();

    const int row = tid >> 4, l16 = tid & 15;
    float a = 0.f;
    #pragma unroll
    for (int jj = 0; jj < 2; ++jj) {
        const int col = l16 * 2 + jj;
        const int ncol = ni * 32 + col;
        float pre = b1[ncol];
        #pragma unroll
        for (int ww = 0; ww < 8; ++ww) pre += lds[ww * 1024 + row * 32 + col];
        a = fmaf(tanhf(pre), W2[ncol], a);
    }
    a += __shfl_xor(a, 1); a += __shfl_xor(a, 2);
    a += __shfl_xor(a, 4); a += __shfl_xor(a, 8);
    if (l16 == 0) astf(&part_p[ni * 512 + bi2 * 32 + row], a);
}

__device__ __forceinline__ void y_reduce(const float* __restrict__ part_p,
                                         const float* __restrict__ b2,
                                         float* __restrict__ y, int s, int bid, int tid) {
    if (tid < 2) {
        const int b = bid * 2 + tid;
        float a = b2[0];
        #pragma unroll
        for (int ni = 0; ni < 16; ++ni) a += aldf(&part_p[ni * 512 + b]);
        astf(&y[(size_t)b * PLz + s], a);
    }
}

// ---------------- the persistent kernel ----------------
struct KParams {
    const u16 *xf_hi, *xf_lo, *wf_hi, *wf_lo, *wcf_hi, *wcf_lo, *w1f_hi, *w1f_lo;
    const float *b_l, *b_c, *b1, *W2, *b2;
    float *h_f32rot, *part_p, *y;
    u16 *buf_enc, *buf_dec;
    u16 *hrot_hi, *hrot_lo, *ctxrot_hi, *ctxrot_lo;
    unsigned *sync;
};

__global__ __launch_bounds__(NTHR, 1) void k_persist(KParams p) {
    __shared__ char smem[65536];
    u16* A_hi = (u16*)smem;                 // 32 KB (staged h hi)
    u16* A_lo = (u16*)(smem + 32768);       // 32 KB (staged h lo)
    float* Gt = (float*)smem;               // [2][32][132] = 33 KB, overlays A after sync
    float* scr = (float*)smem;              // attn/mlp scratch

    const int bid = blockIdx.x;
    const int tid = threadIdx.x;
    // 2D XCD remap: xcd = bid&7 hosts ji ≡ xcd&3 (mod 4), bi ≡ xcd>>2 (mod 2)
    const int xcd = bid & 7, idx = bid >> 3;
    const int g_ji = (xcd & 3) | ((idx & 3) << 2);
    const int g_bi = ((xcd >> 2) & 1) | ((idx >> 2) << 1);
    unsigned gen = 1;
    float c2[2] = {0.f, 0.f};   // persistent cell state

    // encoder: 128 steps; h rotation depth 16, ring slots write-once (t>=96)
    for (int t = 0; t < Tz; ++t) {
        const int si = (t + 15) & 15, so = t & 15;
        gates_phase<36, 4>(p.xf_hi, p.xf_lo, t, p.wf_hi, p.wf_lo,
                           p.hrot_hi + (size_t)si * BH, p.hrot_lo + (size_t)si * BH,
                           p.b_l, c2, nullptr,
                           p.hrot_hi + (size_t)so * BH, p.hrot_lo + (size_t)so * BH,
                           p.buf_enc, t - 96, A_hi, A_lo, Gt, g_ji, g_bi, tid);
        gsync(p.sync, gen++, bid);
    }
    // decoder: 32 iterations (gates | attn | mlp)
    for (int sd = 0; sd < PLz; ++sd) {
        if (sd > 0) y_reduce(p.part_p, p.b2, p.y, sd - 1, bid, tid);
        const int si = (sd + 15) & 15, so = sd & 15;
        float* hf = p.h_f32rot + (size_t)(sd & 3) * BH;
        u16* cx_hi = p.ctxrot_hi + (size_t)(sd & 3) * BH;
        u16* cx_lo = p.ctxrot_lo + (size_t)(sd & 3) * BH;
        gates_phase<32, 0>(nullptr, nullptr, 0, p.wcf_hi, p.wcf_lo,
                           p.hrot_hi + (size_t)si * BH, p.hrot_lo + (size_t)si * BH,
                           p.b_c, c2, hf,
                           p.hrot_hi + (size_t)so * BH, p.hrot_lo + (size_t)so * BH,
                           nullptr, -1, A_hi, A_lo, Gt, g_ji, g_bi, tid);
        gsync(p.sync, gen++, bid);
        attn_phase(hf, p.buf_enc, p.buf_dec, cx_hi, cx_lo, sd, scr, bid, tid);
        gsync(p.sync, gen++, bid);
        mlp_phase(cx_hi, cx_lo,
                  p.hrot_hi + (size_t)so * BH, p.hrot_lo + (size_t)so * BH,
                  p.w1f_hi, p.w1f_lo, p.b1, p.W2, p.part_p, scr, bid, tid);
        gsync(p.sync, gen++, bid);
    }
    y_reduce(p.part_p, p.b2, p.y, PLz - 1, bid, tid);
}

extern "C" void kernel_launch(void* const* d_in, const int* in_sizes, int n_in,
                              void* d_out, int out_size, void* d_ws, size_t ws_size,
                              hipStream_t stream) {
    (void)in_sizes; (void)n_in; (void)out_size; (void)ws_size;
    const float* x     = (const float*)d_in[0];
    const float* W_ih  = (const float*)d_in[1];
    const float* W_hh  = (const float*)d_in[2];
    const float* b_l   = (const float*)d_in[3];
    const float* Wc_ih = (const float*)d_in[4];
    const float* Wc_hh = (const float*)d_in[5];
    const float* b_c   = (const float*)d_in[6];
    const float* W1    = (const float*)d_in[7];
    const float* b1    = (const float*)d_in[8];
    const float* W2    = (const float*)d_in[9];
    const float* b2    = (const float*)d_in[10];
    float* y = (float*)d_out;

    float* w = (float*)d_ws;
    float* h_f32rot = w;                             // 4*BH f32
    float* part_p   = w + 4 * (size_t)BH;            // 8192
    unsigned* sync  = (unsigned*)(w + 4 * (size_t)BH + 8192);   // 8192 u32
    u16* us = (u16*)(w + 4 * (size_t)BH + 8192 + 8192);
    u16* buf_enc = us;   us += 32 * (size_t)BH;      // bf16 ring (B*TS*H)
    u16* buf_dec = us;   us += 32 * (size_t)BH;      // bf16 ring (PL*B*H)
    u16* hrot_hi = us;   us += 16 * (size_t)BH;
    u16* hrot_lo = us;   us += 16 * (size_t)BH;
    u16* ctxrot_hi = us; us += 4 * (size_t)BH;
    u16* ctxrot_lo = us; us += 4 * (size_t)BH;
    u16* xf_hi = us;   us += 4194304;
    u16* xf_lo = us;   us += 4194304;
    u16* wf_hi = us;   us += 1179648;
    u16* wf_lo = us;   us += 1179648;
    u16* wcf_hi = us;  us += 1048576;
    u16* wcf_lo = us;  us += 1048576;
    u16* w1f_hi = us;  us += 524288;
    u16* w1f_lo = us;  us += 524288;

    k_init     <<<1024, 256, 0, stream>>>(hrot_hi + 15 * (size_t)BH,
                                          hrot_lo + 15 * (size_t)BH, sync);
    k_prep_wenc<<<576,  256, 0, stream>>>(W_ih, W_hh, wf_hi, wf_lo);
    k_prep_wc  <<<512,  256, 0, stream>>>(Wc_ih, Wc_hh, wcf_hi, wcf_lo);
    k_prep_w1  <<<256,  256, 0, stream>>>(W1, w1f_hi, w1f_lo);
    k_prep_x   <<<2048, 256, 0, stream>>>(x, xf_hi, xf_lo);

    KParams prm;
    prm.xf_hi = xf_hi;   prm.xf_lo = xf_lo;
    prm.wf_hi = wf_hi;   prm.wf_lo = wf_lo;
    prm.wcf_hi = wcf_hi; prm.wcf_lo = wcf_lo;
    prm.w1f_hi = w1f_hi; prm.w1f_lo = w1f_lo;
    prm.b_l = b_l; prm.b_c = b_c; prm.b1 = b1; prm.W2 = W2; prm.b2 = b2;
    prm.h_f32rot = h_f32rot; prm.part_p = part_p; prm.y = y;
    prm.buf_enc = buf_enc; prm.buf_dec = buf_dec;
    prm.hrot_hi = hrot_hi; prm.hrot_lo = hrot_lo;
    prm.ctxrot_hi = ctxrot_hi; prm.ctxrot_lo = ctxrot_lo;
    prm.sync = sync;

    k_persist<<<dim3(NBLK), dim3(NTHR), 0, stream>>>(prm);
}

// Round 14
// 2169.310 us; speedup vs baseline: 1.7016x; 1.0145x over previous
//
#include <hip/hip_runtime.h>
#include <hip/hip_bf16.h>
#include <math.h>

// Problem sizes
#define Bz   512
#define Tz   128
#define INz  64
#define Hz   512
#define TSz  32
#define PLz  32
#define BH   (Bz * Hz)          // 262144
#define NBLK 256
#define NTHR 512
#define PF   6

typedef unsigned short u16;
typedef unsigned long long u64;
typedef __attribute__((ext_vector_type(8)))  short short8;
typedef __attribute__((ext_vector_type(16))) float floatx16;

static __device__ __forceinline__ void split_bf(float w, u16& hi, u16& lo) {
    __hip_bfloat16 h = __float2bfloat16(w);
    hi = *reinterpret_cast<u16*>(&h);
    float r = w - __bfloat162float(h);
    __hip_bfloat16 l = __float2bfloat16(r);
    lo = *reinterpret_cast<u16*>(&l);
}

union FU  { unsigned u; float f; };
union F2U { u64 q; float f[2]; };

static __device__ __forceinline__ float b2f(u16 v) {
    FU c; c.u = ((unsigned)v) << 16; return c.f;
}
static __device__ __forceinline__ u16 f2b(float f) {
    __hip_bfloat16 h = __float2bfloat16(f);
    return *reinterpret_cast<u16*>(&h);
}

// ---- sc1 (coherence-point / MALL) STORE helpers + sync atomics ----
static __device__ __forceinline__ float aldf(const float* p) {
    FU c; c.u = __hip_atomic_load((const unsigned*)p, __ATOMIC_RELAXED, __HIP_MEMORY_SCOPE_AGENT);
    return c.f;
}
static __device__ __forceinline__ void ast64f(float* p, float a, float b) {
    F2U u; u.f[0] = a; u.f[1] = b;
    __hip_atomic_store((u64*)p, u.q, __ATOMIC_RELAXED, __HIP_MEMORY_SCOPE_AGENT);
}
static __device__ __forceinline__ void astf(float* p, float v) {
    FU c; c.f = v;
    __hip_atomic_store((unsigned*)p, c.u, __ATOMIC_RELAXED, __HIP_MEMORY_SCOPE_AGENT);
}
static __device__ __forceinline__ unsigned aldu(const unsigned* p) {
    return __hip_atomic_load(p, __ATOMIC_RELAXED, __HIP_MEMORY_SCOPE_AGENT);
}
static __device__ __forceinline__ void astu(unsigned* p, unsigned v) {
    __hip_atomic_store(p, v, __ATOMIC_RELAXED, __HIP_MEMORY_SCOPE_AGENT);
}
static __device__ __forceinline__ void astu16x2(u16* p, unsigned v) {
    __hip_atomic_store((unsigned*)p, v, __ATOMIC_RELAXED, __HIP_MEMORY_SCOPE_AGENT);
}

// ---------------- init: zero hrot slot 15 + sync area ----------------
__global__ __launch_bounds__(256) void k_init(u16* __restrict__ h15_hi,
                                              u16* __restrict__ h15_lo,
                                              unsigned* __restrict__ sync) {
    const int i = blockIdx.x * 256 + threadIdx.x;
    if (i < BH) { h15_hi[i] = 0; h15_lo[i] = 0; }
    if (i < 8192) sync[i] = 0;
}

// ---------------- prep kernels (verified, unchanged) ----------------
__global__ __launch_bounds__(256) void k_prep_wenc(const float* __restrict__ W_ih,
                                                   const float* __restrict__ W_hh,
                                                   u16* __restrict__ wf_hi,
                                                   u16* __restrict__ wf_lo) {
    const int idx = blockIdx.x * 256 + threadIdx.x;
    const int lane = idx & 63;
    const int g = (idx >> 6) % 36;
    const int cb = idx / (36 * 64);
    const int C = cb * 32 + (lane & 31);
    const int gate = ((C >> 4) & 3) * 512 + (C >> 6) * 16 + (C & 15);
    const int kh = lane >> 5;
    const size_t base = (size_t)idx * 8;
    #pragma unroll
    for (int e = 0; e < 8; ++e) {
        const int k = g * 16 + kh * 8 + e;
        const float w = (k < 64) ? W_ih[(size_t)gate * 64 + k]
                                 : W_hh[(size_t)gate * 512 + (k - 64)];
        u16 hi, lo; split_bf(w, hi, lo);
        wf_hi[base + e] = hi; wf_lo[base + e] = lo;
    }
}

__global__ __launch_bounds__(256) void k_prep_wc(const float* __restrict__ Wc_ih,
                                                 const float* __restrict__ Wc_hh,
                                                 u16* __restrict__ wf_hi,
                                                 u16* __restrict__ wf_lo) {
    const int idx = blockIdx.x * 256 + threadIdx.x;
    const int lane = idx & 63;
    const int cb = idx / (32 * 64);
    const int g = (idx >> 6) % 32;
    const int C = cb * 32 + (lane & 31);
    const int gate = ((C >> 4) & 3) * 512 + (C >> 6) * 16 + (C & 15);
    const int kh = lane >> 5;
    const size_t base = (size_t)idx * 8;
    #pragma unroll
    for (int e = 0; e < 8; ++e) {
        const int k = g * 16 + kh * 8 + e;
        const float w = Wc_ih[(size_t)gate * 512 + k] + Wc_hh[(size_t)gate * 512 + k];
        u16 hi, lo; split_bf(w, hi, lo);
        wf_hi[base + e] = hi; wf_lo[base + e] = lo;
    }
}

__global__ __launch_bounds__(256) void k_prep_w1(const float* __restrict__ W1,
                                                 u16* __restrict__ wf_hi,
                                                 u16* __restrict__ wf_lo) {
    const int idx = blockIdx.x * 256 + threadIdx.x;
    const int lane = idx & 63;
    const int cb = idx / (64 * 64);
    const int g = (idx >> 6) % 64;
    const int n = cb * 32 + (lane & 31);
    const int kh = lane >> 5;
    const size_t base = (size_t)idx * 8;
    #pragma unroll
    for (int e = 0; e < 8; ++e) {
        const int k = g * 16 + kh * 8 + e;
        const float w = W1[(size_t)n * 1024 + k];
        u16 hi, lo; split_bf(w, hi, lo);
        wf_hi[base + e] = hi; wf_lo[base + e] = lo;
    }
}

__global__ __launch_bounds__(256) void k_prep_x(const float* __restrict__ x,
                                                u16* __restrict__ xf_hi,
                                                u16* __restrict__ xf_lo) {
    const int idx = blockIdx.x * 256 + threadIdx.x;
    const int lane = idx & 63;
    const int g = (idx >> 6) & 3;
    const int rb = (idx >> 8) & 15;
    const int t = idx >> 12;
    const int b = rb * 32 + (lane & 31);
    const int kh = lane >> 5;
    const size_t base = (size_t)idx * 8;
    #pragma unroll
    for (int e = 0; e < 8; ++e) {
        const int i = g * 16 + kh * 8 + e;
        const float w = x[((size_t)b * Tz + t) * INz + i];
        u16 hi, lo; split_bf(w, hi, lo);
        xf_hi[base + e] = hi; xf_lo[base + e] = lo;
    }
}

// ---------------- grid barrier; acquire-fence (buffer_inv) every 16th generation ----------------
// Rotated-buffer reuse distances: enc h rot16 = 16 gens, dec h_f32/ctx rot8 = 24 gens,
// ring = write-once. Any 16 consecutive gens contain exactly one inv -> stale lines
// are dropped before reuse. 14 invs total (vs 28) halves the L2 weight-refill cost.
static __device__ __forceinline__ void gsync(unsigned* sync, unsigned target, int bid) {
    __syncthreads();
    const int tid = threadIdx.x;
    unsigned* arr  = sync + 64;
    unsigned* grel = sync + 64 + 4096;
    if (bid == 0) {
        if (tid < 64) {
            if (tid == 0) astu(&arr[0], target);
            bool done = false;
            while (!done) {
                unsigned mn = 0xffffffffu;
                #pragma unroll
                for (int k = 0; k < 4; ++k) {
                    const unsigned v = aldu(&arr[(tid * 4 + k) * 16]);
                    mn = v < mn ? v : mn;
                }
                done = (bool)__all((int)(mn >= target));
                if (!done) __builtin_amdgcn_s_sleep(1);
            }
            if (tid < 16) astu(&grel[tid * 16], target);
        }
    } else {
        if (tid == 0) {
            astu(&arr[bid * 16], target);
            while (aldu(&grel[(bid >> 4) * 16]) < target)
                __builtin_amdgcn_s_sleep(1);
        }
    }
    if ((target & 15u) == 0u && tid == 0)
        __builtin_amdgcn_fence(__ATOMIC_ACQUIRE, "agent");   // periodic buffer_inv
    __syncthreads();
}

// ---------------- gates + cell: 2D-remapped; XCD = (ji&1)|((bi&3)<<1) -> 8ji x 4bi ----------------
// Tile: 32 batches (bi) x 128 gate-cols (ji). Burst-stage h (64 KB) into LDS;
// K-loop reads A via ds_read_b128, B via L2-warm global with PF-deep register pipeline.
template<int NG, int GX>
__device__ __forceinline__ void gates_phase(
    const u16* __restrict__ xf_hi, const u16* __restrict__ xf_lo, int t,
    const u16* __restrict__ wf_hi, const u16* __restrict__ wf_lo,
    const u16* __restrict__ hin_hi, const u16* __restrict__ hin_lo,
    const float* __restrict__ bias,
    float (&c2)[2], float* __restrict__ h_f32,
    u16* __restrict__ hout_hi, u16* __restrict__ hout_lo,
    u16* __restrict__ buf_enc, int slot,
    u16* A_hi, u16* A_lo, float* Gt, int ji, int bi, int tid)
{
    const int lane = tid & 63, wid = tid >> 6;
    const int wc = wid & 3, kh = wid >> 2;

    // ---- burst-stage h slice (32 granules, 64 KB hi+lo) into LDS ----
    {
        float4 vh[4], vl[4];
        #pragma unroll
        for (int it = 0; it < 4; ++it) {
            const int sl = it * 512 + tid;                 // [0,2048)
            const size_t off = ((size_t)bi * 32 + (sl >> 6)) * 512 + (size_t)(sl & 63) * 8;
            vh[it] = *(const float4*)(hin_hi + off);
            vl[it] = *(const float4*)(hin_lo + off);
        }
        #pragma unroll
        for (int it = 0; it < 4; ++it) {
            const int sl = it * 512 + tid;
            *(float4*)(A_hi + (size_t)sl * 8) = vh[it];
            *(float4*)(A_lo + (size_t)sl * 8) = vl[it];
        }
    }
    __syncthreads();

    // ---- K-loop: col-block cb = ji*4+wc, K-half kh; A from LDS/x-global, B global ----
    constexpr int NGH = NG / 2;
    const int g0 = kh * NGH;
    const int cb = ji * 4 + wc;
    const u16* pbh = wf_hi + ((size_t)cb * NG) * 512 + lane * 8;
    const u16* pbl = wf_lo + ((size_t)cb * NG) * 512 + lane * 8;

    floatx16 acc0, acc1, acc2;
    #pragma unroll
    for (int i = 0; i < 16; ++i) { acc0[i] = 0.f; acc1[i] = 0.f; acc2[i] = 0.f; }

    short8 ah[PF], al[PF], bh[PF], bl[PF];

    #pragma unroll
    for (int i = 0; i < NGH + PF; ++i) {
        if (i >= PF) {   // consume granule g0 + i - PF
            const int s = (i - PF) % PF;
            acc0 = __builtin_amdgcn_mfma_f32_32x32x16_bf16(ah[s], bh[s], acc0, 0, 0, 0);
            acc1 = __builtin_amdgcn_mfma_f32_32x32x16_bf16(ah[s], bl[s], acc1, 0, 0, 0);
            acc2 = __builtin_amdgcn_mfma_f32_32x32x16_bf16(al[s], bh[s], acc2, 0, 0, 0);
        }
        if (i < NGH) {   // refill slot with granule g0+i
            const int s = i % PF;
            const int g = g0 + i;
            if (GX > 0 && g < GX) {   // x: direct cached global
                const size_t off = (((size_t)t * 16 + bi) * GX + g) * 512 + (size_t)lane * 8;
                ah[s] = *(const short8*)(xf_hi + off);
                al[s] = *(const short8*)(xf_lo + off);
            } else {                   // h: from LDS (conflict-free ds_read_b128)
                const int gh = g - GX;
                ah[s] = *(const short8*)(A_hi + ((size_t)gh * 64 + lane) * 8);
                al[s] = *(const short8*)(A_lo + ((size_t)gh * 64 + lane) * 8);
            }
            bh[s] = *(const short8*)(pbh + (size_t)g * 512);
            bl[s] = *(const short8*)(pbl + (size_t)g * 512);
        }
    }
    #pragma unroll
    for (int i = 0; i < 16; ++i) acc0[i] += acc1[i] + acc2[i];

    // ---- Gt overlays A region: sync (all A-reads done), dump, sync ----
    __syncthreads();
    {
        const int col = wc * 32 + (lane & 31);
        const int rb4 = 4 * (lane >> 5);
        float* G = Gt + (size_t)kh * 4224;   // [2][32][132]
        #pragma unroll
        for (int r = 0; r < 16; ++r)
            G[(rb4 + (r & 3) + 8 * (r >> 2)) * 132 + col] = acc0[r];
    }
    __syncthreads();

    // ---- cell update: thread -> (b = bi*32 + tid>>4, 2 consecutive j); c in VGPRs ----
    {
        const int bl2 = tid >> 4, jq = tid & 15;
        const int b = bi * 32 + bl2;
        const int j0 = ji * 32 + jq * 2;
        float hn2[2];
        unsigned phi = 0, plo = 0;
        #pragma unroll
        for (int e = 0; e < 2; ++e) {
            const int jl = jq * 2 + e;
            const int Cl = ((jl >> 4) << 6) | (jl & 15);
            const float* gp = Gt + (size_t)bl2 * 132 + Cl;
            const float* gq = gp + 4224;
            const float gi = gp[0]  + gq[0]  + bias[j0 + e];
            const float gf = gp[16] + gq[16] + bias[512 + j0 + e];
            const float gg = gp[32] + gq[32] + bias[1024 + j0 + e];
            const float go = gp[48] + gq[48] + bias[1536 + j0 + e];
            const float si = 1.f / (1.f + __expf(-gi));
            const float sf = 1.f / (1.f + __expf(-gf));
            const float so = 1.f / (1.f + __expf(-go));
            const float cn = sf * c2[e] + si * tanhf(gg);
            const float hn = so * tanhf(cn);
            c2[e] = cn; hn2[e] = hn;
            u16 hi, lo; split_bf(hn, hi, lo);
            phi |= (unsigned)hi << (16 * e);
            plo |= (unsigned)lo << (16 * e);
        }
        const int gran = j0 >> 4;
        const int fl = ((j0 >> 3) & 1) * 32 + (b & 31);
        const size_t fo = (((size_t)bi * 32 + gran) * 64 + fl) * 8 + (j0 & 7);
        astu16x2(hout_hi + fo, phi);    // sc1: fresh at MALL for all XCDs
        astu16x2(hout_lo + fo, plo);
        if (slot >= 0)
            astu16x2(buf_enc + ((size_t)b * TSz + slot) * Hz + j0, phi);  // bf16 ring
        if (h_f32 != nullptr)
            ast64f(h_f32 + (size_t)b * Hz + j0, hn2[0], hn2[1]);
    }
}

// ---------------- attention: 2 batches/block; bf16 ring, cached reads ----------------
__device__ __forceinline__ void attn_phase(const float* __restrict__ h_f32,
                                           const u16* __restrict__ buf_enc,
                                           u16* __restrict__ buf_dec,
                                           u16* __restrict__ ctx_hi, u16* __restrict__ ctx_lo,
                                           int sd, float* lds, int bid, int tid) {
    const int grp = tid >> 8;
    const int t8 = tid & 255;
    const int b = bid * 2 + grp;
    float* sh = lds + grp * 544;
    float* sa = sh + 512;
    {
        const int i0 = t8 * 2;
        const float2 hv = *(const float2*)(h_f32 + (size_t)b * Hz + i0);
        sh[i0] = hv.x; sh[i0 + 1] = hv.y;
    }
    __syncthreads();
    {   // 32 scores x 8 lanes; bf16 ring, ushort4 coalesced
        const int w = t8 >> 3, l8 = t8 & 7;
        const u16* v = (w < TSz - sd)
            ? buf_enc + ((size_t)b * TSz + (sd + w)) * Hz
            : buf_dec + (size_t)(w - TSz + sd) * BH + (size_t)b * Hz;
        float p = 0.f;
        #pragma unroll 4
        for (int k = 0; k < 16; ++k) {
            const int j = l8 * 4 + k * 32;
            const ushort4 q = *(const ushort4*)(v + j);
            p = fmaf(sh[j],     b2f(q.x), p);
            p = fmaf(sh[j + 1], b2f(q.y), p);
            p = fmaf(sh[j + 2], b2f(q.z), p);
            p = fmaf(sh[j + 3], b2f(q.w), p);
        }
        p += __shfl_xor(p, 1); p += __shfl_xor(p, 2); p += __shfl_xor(p, 4);
        if (l8 == 0) sa[w] = p;
    }
    __syncthreads();
    if (t8 < TSz) {
        const float v = sa[t8];
        float m = v;
        #pragma unroll
        for (int d = 1; d < 32; d <<= 1) m = fmaxf(m, __shfl_xor(m, d));
        const float e = __expf(v - m);
        float ss = e;
        #pragma unroll
        for (int d = 1; d < 32; d <<= 1) ss += __shfl_xor(ss, d);
        sa[t8] = e / ss;
    }
    __syncthreads();
    {   // ctx: 2 consecutive j per thread; bf16 ring reads; sc1 frag store
        const int j0 = t8 * 2;
        float a0 = 0.f, a1 = 0.f;
        for (int w2 = 0; w2 < TSz; ++w2) {
            const u16* vp = (w2 < TSz - sd)
                ? buf_enc + ((size_t)b * TSz + (sd + w2)) * Hz + j0
                : buf_dec + (size_t)(w2 - TSz + sd) * BH + (size_t)b * Hz + j0;
            const ushort2 vv = *(const ushort2*)vp;
            a0 = fmaf(sa[w2], b2f(vv.x), a0);
            a1 = fmaf(sa[w2], b2f(vv.y), a1);
        }
        u16 h0, l0, h1, l1;
        split_bf(a0, h0, l0); split_bf(a1, h1, l1);
        const int rb = b >> 5, gran = j0 >> 4;
        const int fl = ((j0 >> 3) & 1) * 32 + (b & 31);
        const size_t fo = (((size_t)rb * 32 + gran) * 64 + fl) * 8 + (j0 & 7);
        astu16x2(ctx_hi + fo, (unsigned)h0 | ((unsigned)h1 << 16));
        astu16x2(ctx_lo + fo, (unsigned)l0 | ((unsigned)l1 << 16));
    }
    {   // append h_sd to fresh buffer buf_dec[sd] (sc1, bf16, write-once)
        const int i0 = t8 * 2;
        const unsigned pk = (unsigned)f2b(sh[i0]) | ((unsigned)f2b(sh[i0 + 1]) << 16);
        astu16x2(buf_dec + (size_t)sd * BH + (size_t)b * Hz + i0, pk);
    }
}

// ---------------- MLP + partial out: 8-wave K-split; A reads cached (rotated) ----------------
__device__ __forceinline__ void mlp_phase(
    const u16* __restrict__ ctx_hi, const u16* __restrict__ ctx_lo,
    const u16* __restrict__ h_hi,   const u16* __restrict__ h_lo,
    const u16* __restrict__ w1_hi,  const u16* __restrict__ w1_lo,
    const float* __restrict__ b1, const float* __restrict__ W2,
    float* __restrict__ part_p, float* lds, int bid, int tid)
{
    const int lane = tid & 63, w = tid >> 6;
    const int ni = bid & 15, bi2 = bid >> 4;

    floatx16 acc0, acc1, acc2;
    #pragma unroll
    for (int i = 0; i < 16; ++i) { acc0[i] = 0.f; acc1[i] = 0.f; acc2[i] = 0.f; }

    short8 ah[4], al[4], bh[4], bl[4];

    #pragma unroll
    for (int i = 0; i < 8 + 4; ++i) {
        if (i >= 4) {
            const int s = (i - 4) & 3;
            acc0 = __builtin_amdgcn_mfma_f32_32x32x16_bf16(ah[s], bh[s], acc0, 0, 0, 0);
            acc1 = __builtin_amdgcn_mfma_f32_32x32x16_bf16(ah[s], bl[s], acc1, 0, 0, 0);
            acc2 = __builtin_amdgcn_mfma_f32_32x32x16_bf16(al[s], bh[s], acc2, 0, 0, 0);
        }
        if (i < 8) {
            const int s = i & 3;
            const int g = w * 8 + i;
            if (g < 32) {
                const size_t off = (((size_t)bi2 * 32 + g) * 64 + lane) * 8;
                ah[s] = *(const short8*)(ctx_hi + off);
                al[s] = *(const short8*)(ctx_lo + off);
            } else {
                const size_t off = (((size_t)bi2 * 32 + (g - 32)) * 64 + lane) * 8;
                ah[s] = *(const short8*)(h_hi + off);
                al[s] = *(const short8*)(h_lo + off);
            }
            const size_t boff = (((size_t)ni * 64 + g) * 64 + lane) * 8;
            bh[s] = *(const short8*)(w1_hi + boff);
            bl[s] = *(const short8*)(w1_lo + boff);
        }
    }
    #pragma unroll
    for (int i = 0; i < 16; ++i) acc0[i] += acc1[i] + acc2[i];

    {
        const int col = lane & 31;
        const int rb4 = 4 * (lane >> 5);
        #pragma unroll
        for (int r = 0; r < 16; ++r)
            lds[w * 1024 + (rb4 + (r & 3) + 8 * (r >> 2)) * 32 + col] = acc0[r];
    }
    __syncthreads();

    const int row = tid >> 4, l16 = tid & 15;
    float a = 0.f;
    #pragma unroll
    for (int jj = 0; jj < 2; ++jj) {
        const int col = l16 * 2 + jj;
        const int ncol = ni * 32 + col;
        float pre = b1[ncol];
        #pragma unroll
        for (int ww = 0; ww < 8; ++ww) pre += lds[ww * 1024 + row * 32 + col];
        a = fmaf(tanhf(pre), W2[ncol], a);
    }
    a += __shfl_xor(a, 1); a += __shfl_xor(a, 2);
    a += __shfl_xor(a, 4); a += __shfl_xor(a, 8);
    if (l16 == 0) astf(&part_p[ni * 512 + bi2 * 32 + row], a);
}

__device__ __forceinline__ void y_reduce(const float* __restrict__ part_p,
                                         const float* __restrict__ b2,
                                         float* __restrict__ y, int s, int bid, int tid) {
    if (tid < 2) {
        const int b = bid * 2 + tid;
        float a = b2[0];
        #pragma unroll
        for (int ni = 0; ni < 16; ++ni) a += aldf(&part_p[ni * 512 + b]);
        astf(&y[(size_t)b * PLz + s], a);
    }
}

// ---------------- the persistent kernel ----------------
struct KParams {
    const u16 *xf_hi, *xf_lo, *wf_hi, *wf_lo, *wcf_hi, *wcf_lo, *w1f_hi, *w1f_lo;
    const float *b_l, *b_c, *b1, *W2, *b2;
    float *h_f32rot, *part_p, *y;
    u16 *buf_enc, *buf_dec;
    u16 *hrot_hi, *hrot_lo, *ctxrot_hi, *ctxrot_lo;
    unsigned *sync;
};

__global__ __launch_bounds__(NTHR, 1) void k_persist(KParams p) {
    __shared__ char smem[65536];
    u16* A_hi = (u16*)smem;                 // 32 KB (staged h hi)
    u16* A_lo = (u16*)(smem + 32768);       // 32 KB (staged h lo)
    float* Gt = (float*)smem;               // [2][32][132] = 33 KB, overlays A after sync
    float* scr = (float*)smem;              // attn/mlp scratch

    const int bid = blockIdx.x;
    const int tid = threadIdx.x;
    // 2D XCD remap (8ji x 4bi per XCD): xcd = (ji&1) | ((bi&3)<<1)
    const int xcd = bid & 7, idx = bid >> 3;
    const int g_ji = (xcd & 1) | ((idx & 7) << 1);
    const int g_bi = ((xcd >> 1) & 3) | ((idx >> 3) << 2);
    unsigned gen = 1;
    float c2[2] = {0.f, 0.f};   // persistent cell state

    // encoder: 128 steps; h rotation depth 16, ring slots write-once (t>=96)
    for (int t = 0; t < Tz; ++t) {
        const int si = (t + 15) & 15, so = t & 15;
        gates_phase<36, 4>(p.xf_hi, p.xf_lo, t, p.wf_hi, p.wf_lo,
                           p.hrot_hi + (size_t)si * BH, p.hrot_lo + (size_t)si * BH,
                           p.b_l, c2, nullptr,
                           p.hrot_hi + (size_t)so * BH, p.hrot_lo + (size_t)so * BH,
                           p.buf_enc, t - 96, A_hi, A_lo, Gt, g_ji, g_bi, tid);
        gsync(p.sync, gen++, bid);
    }
    // decoder: 32 iterations (gates | attn | mlp)
    for (int sd = 0; sd < PLz; ++sd) {
        if (sd > 0) y_reduce(p.part_p, p.b2, p.y, sd - 1, bid, tid);
        const int si = (sd + 15) & 15, so = sd & 15;
        float* hf = p.h_f32rot + (size_t)(sd & 7) * BH;
        u16* cx_hi = p.ctxrot_hi + (size_t)(sd & 7) * BH;
        u16* cx_lo = p.ctxrot_lo + (size_t)(sd & 7) * BH;
        gates_phase<32, 0>(nullptr, nullptr, 0, p.wcf_hi, p.wcf_lo,
                           p.hrot_hi + (size_t)si * BH, p.hrot_lo + (size_t)si * BH,
                           p.b_c, c2, hf,
                           p.hrot_hi + (size_t)so * BH, p.hrot_lo + (size_t)so * BH,
                           nullptr, -1, A_hi, A_lo, Gt, g_ji, g_bi, tid);
        gsync(p.sync, gen++, bid);
        attn_phase(hf, p.buf_enc, p.buf_dec, cx_hi, cx_lo, sd, scr, bid, tid);
        gsync(p.sync, gen++, bid);
        mlp_phase(cx_hi, cx_lo,
                  p.hrot_hi + (size_t)so * BH, p.hrot_lo + (size_t)so * BH,
                  p.w1f_hi, p.w1f_lo, p.b1, p.W2, p.part_p, scr, bid, tid);
        gsync(p.sync, gen++, bid);
    }
    y_reduce(p.part_p, p.b2, p.y, PLz - 1, bid, tid);
}

extern "C" void kernel_launch(void* const* d_in, const int* in_sizes, int n_in,
                              void* d_out, int out_size, void* d_ws, size_t ws_size,
                              hipStream_t stream) {
    (void)in_sizes; (void)n_in; (void)out_size; (void)ws_size;
    const float* x     = (const float*)d_in[0];
    const float* W_ih  = (const float*)d_in[1];
    const float* W_hh  = (const float*)d_in[2];
    const float* b_l   = (const float*)d_in[3];
    const float* Wc_ih = (const float*)d_in[4];
    const float* Wc_hh = (const float*)d_in[5];
    const float* b_c   = (const float*)d_in[6];
    const float* W1    = (const float*)d_in[7];
    const float* b1    = (const float*)d_in[8];
    const float* W2    = (const float*)d_in[9];
    const float* b2    = (const float*)d_in[10];
    float* y = (float*)d_out;

    float* w = (float*)d_ws;
    float* h_f32rot = w;                             // 8*BH f32
    float* part_p   = w + 8 * (size_t)BH;            // 8192
    unsigned* sync  = (unsigned*)(w + 8 * (size_t)BH + 8192);   // 8192 u32
    u16* us = (u16*)(w + 8 * (size_t)BH + 8192 + 8192);
    u16* buf_enc = us;   us += 32 * (size_t)BH;      // bf16 ring (B*TS*H)
    u16* buf_dec = us;   us += 32 * (size_t)BH;      // bf16 ring (PL*B*H)
    u16* hrot_hi = us;   us += 16 * (size_t)BH;
    u16* hrot_lo = us;   us += 16 * (size_t)BH;
    u16* ctxrot_hi = us; us += 8 * (size_t)BH;
    u16* ctxrot_lo = us; us += 8 * (size_t)BH;
    u16* xf_hi = us;   us += 4194304;
    u16* xf_lo = us;   us += 4194304;
    u16* wf_hi = us;   us += 1179648;
    u16* wf_lo = us;   us += 1179648;
    u16* wcf_hi = us;  us += 1048576;
    u16* wcf_lo = us;  us += 1048576;
    u16* w1f_hi = us;  us += 524288;
    u16* w1f_lo = us;  us += 524288;

    k_init     <<<1024, 256, 0, stream>>>(hrot_hi + 15 * (size_t)BH,
                                          hrot_lo + 15 * (size_t)BH, sync);
    k_prep_wenc<<<576,  256, 0, stream>>>(W_ih, W_hh, wf_hi, wf_lo);
    k_prep_wc  <<<512,  256, 0, stream>>>(Wc_ih, Wc_hh, wcf_hi, wcf_lo);
    k_prep_w1  <<<256,  256, 0, stream>>>(W1, w1f_hi, w1f_lo);
    k_prep_x   <<<2048, 256, 0, stream>>>(x, xf_hi, xf_lo);

    KParams prm;
    prm.xf_hi = xf_hi;   prm.xf_lo = xf_lo;
    prm.wf_hi = wf_hi;   prm.wf_lo = wf_lo;
    prm.wcf_hi = wcf_hi; prm.wcf_lo = wcf_lo;
    prm.w1f_hi = w1f_hi; prm.w1f_lo = w1f_lo;
    prm.b_l = b_l; prm.b_c = b_c; prm.b1 = b1; prm.W2 = W2; prm.b2 = b2;
    prm.h_f32rot = h_f32rot; prm.part_p = part_p; prm.y = y;
    prm.buf_enc = buf_enc; prm.buf_dec = buf_dec;
    prm.hrot_hi = hrot_hi; prm.hrot_lo = hrot_lo;
    prm.ctxrot_hi = ctxrot_hi; prm.ctxrot_lo = ctxrot_lo;
    prm.sync = sync;

    k_persist<<<dim3(NBLK), dim3(NTHR), 0, stream>>>(prm);
}

// Round 15
// 2123.297 us; speedup vs baseline: 1.7385x; 1.0217x over previous
//
#include <hip/hip_runtime.h>
#include <hip/hip_bf16.h>
#include <math.h>

// Problem sizes
#define Bz   512
#define Tz   128
#define INz  64
#define Hz   512
#define TSz  32
#define PLz  32
#define BH   (Bz * Hz)          // 262144
#define NBLK 256
#define NTHR 512
#define PF   6

typedef unsigned short u16;
typedef unsigned long long u64;
typedef __attribute__((ext_vector_type(8)))  short short8;
typedef __attribute__((ext_vector_type(16))) float floatx16;

static __device__ __forceinline__ void split_bf(float w, u16& hi, u16& lo) {
    __hip_bfloat16 h = __float2bfloat16(w);
    hi = *reinterpret_cast<u16*>(&h);
    float r = w - __bfloat162float(h);
    __hip_bfloat16 l = __float2bfloat16(r);
    lo = *reinterpret_cast<u16*>(&l);
}

union FU  { unsigned u; float f; };
union F2U { u64 q; float f[2]; };

static __device__ __forceinline__ float b2f(u16 v) {
    FU c; c.u = ((unsigned)v) << 16; return c.f;
}
static __device__ __forceinline__ u16 f2b(float f) {
    __hip_bfloat16 h = __float2bfloat16(f);
    return *reinterpret_cast<u16*>(&h);
}

// ---- sc1 (coherence-point / MALL) STORE helpers + sync atomics ----
static __device__ __forceinline__ float aldf(const float* p) {
    FU c; c.u = __hip_atomic_load((const unsigned*)p, __ATOMIC_RELAXED, __HIP_MEMORY_SCOPE_AGENT);
    return c.f;
}
static __device__ __forceinline__ void ast64f(float* p, float a, float b) {
    F2U u; u.f[0] = a; u.f[1] = b;
    __hip_atomic_store((u64*)p, u.q, __ATOMIC_RELAXED, __HIP_MEMORY_SCOPE_AGENT);
}
static __device__ __forceinline__ void astf(float* p, float v) {
    FU c; c.f = v;
    __hip_atomic_store((unsigned*)p, c.u, __ATOMIC_RELAXED, __HIP_MEMORY_SCOPE_AGENT);
}
static __device__ __forceinline__ unsigned aldu(const unsigned* p) {
    return __hip_atomic_load(p, __ATOMIC_RELAXED, __HIP_MEMORY_SCOPE_AGENT);
}
static __device__ __forceinline__ void astu(unsigned* p, unsigned v) {
    __hip_atomic_store(p, v, __ATOMIC_RELAXED, __HIP_MEMORY_SCOPE_AGENT);
}
static __device__ __forceinline__ void astu16x2(u16* p, unsigned v) {
    __hip_atomic_store((unsigned*)p, v, __ATOMIC_RELAXED, __HIP_MEMORY_SCOPE_AGENT);
}

// ---------------- init: zero hrot slot 15 + sync area ----------------
__global__ __launch_bounds__(256) void k_init(u16* __restrict__ h15_hi,
                                              u16* __restrict__ h15_lo,
                                              unsigned* __restrict__ sync) {
    const int i = blockIdx.x * 256 + threadIdx.x;
    if (i < BH) { h15_hi[i] = 0; h15_lo[i] = 0; }
    if (i < 8192) sync[i] = 0;
}

// ---------------- prep kernels (verified, unchanged) ----------------
__global__ __launch_bounds__(256) void k_prep_wenc(const float* __restrict__ W_ih,
                                                   const float* __restrict__ W_hh,
                                                   u16* __restrict__ wf_hi,
                                                   u16* __restrict__ wf_lo) {
    const int idx = blockIdx.x * 256 + threadIdx.x;
    const int lane = idx & 63;
    const int g = (idx >> 6) % 36;
    const int cb = idx / (36 * 64);
    const int C = cb * 32 + (lane & 31);
    const int gate = ((C >> 4) & 3) * 512 + (C >> 6) * 16 + (C & 15);
    const int kh = lane >> 5;
    const size_t base = (size_t)idx * 8;
    #pragma unroll
    for (int e = 0; e < 8; ++e) {
        const int k = g * 16 + kh * 8 + e;
        const float w = (k < 64) ? W_ih[(size_t)gate * 64 + k]
                                 : W_hh[(size_t)gate * 512 + (k - 64)];
        u16 hi, lo; split_bf(w, hi, lo);
        wf_hi[base + e] = hi; wf_lo[base + e] = lo;
    }
}

__global__ __launch_bounds__(256) void k_prep_wc(const float* __restrict__ Wc_ih,
                                                 const float* __restrict__ Wc_hh,
                                                 u16* __restrict__ wf_hi,
                                                 u16* __restrict__ wf_lo) {
    const int idx = blockIdx.x * 256 + threadIdx.x;
    const int lane = idx & 63;
    const int cb = idx / (32 * 64);
    const int g = (idx >> 6) % 32;
    const int C = cb * 32 + (lane & 31);
    const int gate = ((C >> 4) & 3) * 512 + (C >> 6) * 16 + (C & 15);
    const int kh = lane >> 5;
    const size_t base = (size_t)idx * 8;
    #pragma unroll
    for (int e = 0; e < 8; ++e) {
        const int k = g * 16 + kh * 8 + e;
        const float w = Wc_ih[(size_t)gate * 512 + k] + Wc_hh[(size_t)gate * 512 + k];
        u16 hi, lo; split_bf(w, hi, lo);
        wf_hi[base + e] = hi; wf_lo[base + e] = lo;
    }
}

__global__ __launch_bounds__(256) void k_prep_w1(const float* __restrict__ W1,
                                                 u16* __restrict__ wf_hi,
                                                 u16* __restrict__ wf_lo) {
    const int idx = blockIdx.x * 256 + threadIdx.x;
    const int lane = idx & 63;
    const int cb = idx / (64 * 64);
    const int g = (idx >> 6) % 64;
    const int n = cb * 32 + (lane & 31);
    const int kh = lane >> 5;
    const size_t base = (size_t)idx * 8;
    #pragma unroll
    for (int e = 0; e < 8; ++e) {
        const int k = g * 16 + kh * 8 + e;
        const float w = W1[(size_t)n * 1024 + k];
        u16 hi, lo; split_bf(w, hi, lo);
        wf_hi[base + e] = hi; wf_lo[base + e] = lo;
    }
}

__global__ __launch_bounds__(256) void k_prep_x(const float* __restrict__ x,
                                                u16* __restrict__ xf_hi,
                                                u16* __restrict__ xf_lo) {
    const int idx = blockIdx.x * 256 + threadIdx.x;
    const int lane = idx & 63;
    const int g = (idx >> 6) & 3;
    const int rb = (idx >> 8) & 15;
    const int t = idx >> 12;
    const int b = rb * 32 + (lane & 31);
    const int kh = lane >> 5;
    const size_t base = (size_t)idx * 8;
    #pragma unroll
    for (int e = 0; e < 8; ++e) {
        const int i = g * 16 + kh * 8 + e;
        const float w = x[((size_t)b * Tz + t) * INz + i];
        u16 hi, lo; split_bf(w, hi, lo);
        xf_hi[base + e] = hi; xf_lo[base + e] = lo;
    }
}

// ---------------- grid barrier: two-level RELAXED fetch_add (no per-op cache ops) ----------------
// Arrival: relaxed atomic add on group counter (16 groups); last-in-group adds to root;
// last root-arriver stores generation. All blocks poll the single generation word.
// RELAXED RMW emits NO wbl2/inv (round-7's cost was ACQ_REL ordering). Ordering safety
// unchanged: __syncthreads drains vmcnt (sc1 data stores visible at MALL before arrival);
// rotated-buffer staleness handled by the periodic acquire fence (every 16 gens).
static __device__ __forceinline__ void gsync(unsigned* sync, unsigned target, int bid) {
    __syncthreads();
    if (threadIdx.x == 0) {
        unsigned* grp  = sync + 64 + ((bid >> 4) << 4);   // 16 groups, 64B apart
        unsigned* root = sync + 64 + (16 << 4);
        const unsigned a = __hip_atomic_fetch_add(grp, 1u, __ATOMIC_RELAXED, __HIP_MEMORY_SCOPE_AGENT);
        if ((a & 15u) == 15u) {   // 16th arriver of this group for this generation
            const unsigned r = __hip_atomic_fetch_add(root, 1u, __ATOMIC_RELAXED, __HIP_MEMORY_SCOPE_AGENT);
            if ((r & 15u) == 15u)   // 16th group
                astu(sync, target);
        }
        while (aldu(sync) < target)
            __builtin_amdgcn_s_sleep(2);
        if ((target & 15u) == 0u)
            __builtin_amdgcn_fence(__ATOMIC_ACQUIRE, "agent");   // periodic buffer_inv
    }
    __syncthreads();
}

// ---------------- gates + cell: 2D-remapped; XCD = (ji&1)|((bi&3)<<1) -> 8ji x 4bi ----------------
template<int NG, int GX>
__device__ __forceinline__ void gates_phase(
    const u16* __restrict__ xf_hi, const u16* __restrict__ xf_lo, int t,
    const u16* __restrict__ wf_hi, const u16* __restrict__ wf_lo,
    const u16* __restrict__ hin_hi, const u16* __restrict__ hin_lo,
    const float* __restrict__ bias,
    float (&c2)[2], float* __restrict__ h_f32,
    u16* __restrict__ hout_hi, u16* __restrict__ hout_lo,
    u16* __restrict__ buf_enc, int slot,
    u16* A_hi, u16* A_lo, float* Gt, int ji, int bi, int tid)
{
    const int lane = tid & 63, wid = tid >> 6;
    const int wc = wid & 3, kh = wid >> 2;

    // ---- burst-stage h slice (32 granules, 64 KB hi+lo) into LDS ----
    {
        float4 vh[4], vl[4];
        #pragma unroll
        for (int it = 0; it < 4; ++it) {
            const int sl = it * 512 + tid;                 // [0,2048)
            const size_t off = ((size_t)bi * 32 + (sl >> 6)) * 512 + (size_t)(sl & 63) * 8;
            vh[it] = *(const float4*)(hin_hi + off);
            vl[it] = *(const float4*)(hin_lo + off);
        }
        #pragma unroll
        for (int it = 0; it < 4; ++it) {
            const int sl = it * 512 + tid;
            *(float4*)(A_hi + (size_t)sl * 8) = vh[it];
            *(float4*)(A_lo + (size_t)sl * 8) = vl[it];
        }
    }
    __syncthreads();

    // ---- K-loop: col-block cb = ji*4+wc, K-half kh; A from LDS/x-global, B global ----
    constexpr int NGH = NG / 2;
    const int g0 = kh * NGH;
    const int cb = ji * 4 + wc;
    const u16* pbh = wf_hi + ((size_t)cb * NG) * 512 + lane * 8;
    const u16* pbl = wf_lo + ((size_t)cb * NG) * 512 + lane * 8;

    floatx16 acc0, acc1, acc2;
    #pragma unroll
    for (int i = 0; i < 16; ++i) { acc0[i] = 0.f; acc1[i] = 0.f; acc2[i] = 0.f; }

    short8 ah[PF], al[PF], bh[PF], bl[PF];

    #pragma unroll
    for (int i = 0; i < NGH + PF; ++i) {
        if (i >= PF) {   // consume granule g0 + i - PF
            const int s = (i - PF) % PF;
            acc0 = __builtin_amdgcn_mfma_f32_32x32x16_bf16(ah[s], bh[s], acc0, 0, 0, 0);
            acc1 = __builtin_amdgcn_mfma_f32_32x32x16_bf16(ah[s], bl[s], acc1, 0, 0, 0);
            acc2 = __builtin_amdgcn_mfma_f32_32x32x16_bf16(al[s], bh[s], acc2, 0, 0, 0);
        }
        if (i < NGH) {   // refill slot with granule g0+i
            const int s = i % PF;
            const int g = g0 + i;
            if (GX > 0 && g < GX) {   // x: direct cached global
                const size_t off = (((size_t)t * 16 + bi) * GX + g) * 512 + (size_t)lane * 8;
                ah[s] = *(const short8*)(xf_hi + off);
                al[s] = *(const short8*)(xf_lo + off);
            } else {                   // h: from LDS (conflict-free ds_read_b128)
                const int gh = g - GX;
                ah[s] = *(const short8*)(A_hi + ((size_t)gh * 64 + lane) * 8);
                al[s] = *(const short8*)(A_lo + ((size_t)gh * 64 + lane) * 8);
            }
            bh[s] = *(const short8*)(pbh + (size_t)g * 512);
            bl[s] = *(const short8*)(pbl + (size_t)g * 512);
        }
    }
    #pragma unroll
    for (int i = 0; i < 16; ++i) acc0[i] += acc1[i] + acc2[i];

    // ---- Gt overlays A region: sync (all A-reads done), dump, sync ----
    __syncthreads();
    {
        const int col = wc * 32 + (lane & 31);
        const int rb4 = 4 * (lane >> 5);
        float* G = Gt + (size_t)kh * 4224;   // [2][32][132]
        #pragma unroll
        for (int r = 0; r < 16; ++r)
            G[(rb4 + (r & 3) + 8 * (r >> 2)) * 132 + col] = acc0[r];
    }
    __syncthreads();

    // ---- cell update: thread -> (b = bi*32 + tid>>4, 2 consecutive j); c in VGPRs ----
    {
        const int bl2 = tid >> 4, jq = tid & 15;
        const int b = bi * 32 + bl2;
        const int j0 = ji * 32 + jq * 2;
        float hn2[2];
        unsigned phi = 0, plo = 0;
        #pragma unroll
        for (int e = 0; e < 2; ++e) {
            const int jl = jq * 2 + e;
            const int Cl = ((jl >> 4) << 6) | (jl & 15);
            const float* gp = Gt + (size_t)bl2 * 132 + Cl;
            const float* gq = gp + 4224;
            const float gi = gp[0]  + gq[0]  + bias[j0 + e];
            const float gf = gp[16] + gq[16] + bias[512 + j0 + e];
            const float gg = gp[32] + gq[32] + bias[1024 + j0 + e];
            const float go = gp[48] + gq[48] + bias[1536 + j0 + e];
            const float si = 1.f / (1.f + __expf(-gi));
            const float sf = 1.f / (1.f + __expf(-gf));
            const float so = 1.f / (1.f + __expf(-go));
            const float cn = sf * c2[e] + si * tanhf(gg);
            const float hn = so * tanhf(cn);
            c2[e] = cn; hn2[e] = hn;
            u16 hi, lo; split_bf(hn, hi, lo);
            phi |= (unsigned)hi << (16 * e);
            plo |= (unsigned)lo << (16 * e);
        }
        const int gran = j0 >> 4;
        const int fl = ((j0 >> 3) & 1) * 32 + (b & 31);
        const size_t fo = (((size_t)bi * 32 + gran) * 64 + fl) * 8 + (j0 & 7);
        astu16x2(hout_hi + fo, phi);    // sc1: fresh at MALL for all XCDs
        astu16x2(hout_lo + fo, plo);
        if (slot >= 0)
            astu16x2(buf_enc + ((size_t)b * TSz + slot) * Hz + j0, phi);  // bf16 ring
        if (h_f32 != nullptr)
            ast64f(h_f32 + (size_t)b * Hz + j0, hn2[0], hn2[1]);
    }
}

// ---------------- attention: 2 batches/block; bf16 ring, cached reads ----------------
__device__ __forceinline__ void attn_phase(const float* __restrict__ h_f32,
                                           const u16* __restrict__ buf_enc,
                                           u16* __restrict__ buf_dec,
                                           u16* __restrict__ ctx_hi, u16* __restrict__ ctx_lo,
                                           int sd, float* lds, int bid, int tid) {
    const int grp = tid >> 8;
    const int t8 = tid & 255;
    const int b = bid * 2 + grp;
    float* sh = lds + grp * 544;
    float* sa = sh + 512;
    {
        const int i0 = t8 * 2;
        const float2 hv = *(const float2*)(h_f32 + (size_t)b * Hz + i0);
        sh[i0] = hv.x; sh[i0 + 1] = hv.y;
    }
    __syncthreads();
    {   // 32 scores x 8 lanes; bf16 ring, ushort4 coalesced
        const int w = t8 >> 3, l8 = t8 & 7;
        const u16* v = (w < TSz - sd)
            ? buf_enc + ((size_t)b * TSz + (sd + w)) * Hz
            : buf_dec + (size_t)(w - TSz + sd) * BH + (size_t)b * Hz;
        float p = 0.f;
        #pragma unroll 4
        for (int k = 0; k < 16; ++k) {
            const int j = l8 * 4 + k * 32;
            const ushort4 q = *(const ushort4*)(v + j);
            p = fmaf(sh[j],     b2f(q.x), p);
            p = fmaf(sh[j + 1], b2f(q.y), p);
            p = fmaf(sh[j + 2], b2f(q.z), p);
            p = fmaf(sh[j + 3], b2f(q.w), p);
        }
        p += __shfl_xor(p, 1); p += __shfl_xor(p, 2); p += __shfl_xor(p, 4);
        if (l8 == 0) sa[w] = p;
    }
    __syncthreads();
    if (t8 < TSz) {
        const float v = sa[t8];
        float m = v;
        #pragma unroll
        for (int d = 1; d < 32; d <<= 1) m = fmaxf(m, __shfl_xor(m, d));
        const float e = __expf(v - m);
        float ss = e;
        #pragma unroll
        for (int d = 1; d < 32; d <<= 1) ss += __shfl_xor(ss, d);
        sa[t8] = e / ss;
    }
    __syncthreads();
    {   // ctx: 2 consecutive j per thread; bf16 ring reads; sc1 frag store
        const int j0 = t8 * 2;
        float a0 = 0.f, a1 = 0.f;
        for (int w2 = 0; w2 < TSz; ++w2) {
            const u16* vp = (w2 < TSz - sd)
                ? buf_enc + ((size_t)b * TSz + (sd + w2)) * Hz + j0
                : buf_dec + (size_t)(w2 - TSz + sd) * BH + (size_t)b * Hz + j0;
            const ushort2 vv = *(const ushort2*)vp;
            a0 = fmaf(sa[w2], b2f(vv.x), a0);
            a1 = fmaf(sa[w2], b2f(vv.y), a1);
        }
        u16 h0, l0, h1, l1;
        split_bf(a0, h0, l0); split_bf(a1, h1, l1);
        const int rb = b >> 5, gran = j0 >> 4;
        const int fl = ((j0 >> 3) & 1) * 32 + (b & 31);
        const size_t fo = (((size_t)rb * 32 + gran) * 64 + fl) * 8 + (j0 & 7);
        astu16x2(ctx_hi + fo, (unsigned)h0 | ((unsigned)h1 << 16));
        astu16x2(ctx_lo + fo, (unsigned)l0 | ((unsigned)l1 << 16));
    }
    {   // append h_sd to fresh buffer buf_dec[sd] (sc1, bf16, write-once)
        const int i0 = t8 * 2;
        const unsigned pk = (unsigned)f2b(sh[i0]) | ((unsigned)f2b(sh[i0 + 1]) << 16);
        astu16x2(buf_dec + (size_t)sd * BH + (size_t)b * Hz + i0, pk);
    }
}

// ---------------- MLP + partial out: 8-wave K-split; A reads cached (rotated) ----------------
__device__ __forceinline__ void mlp_phase(
    const u16* __restrict__ ctx_hi, const u16* __restrict__ ctx_lo,
    const u16* __restrict__ h_hi,   const u16* __restrict__ h_lo,
    const u16* __restrict__ w1_hi,  const u16* __restrict__ w1_lo,
    const float* __restrict__ b1, const float* __restrict__ W2,
    float* __restrict__ part_p, float* lds, int bid, int tid)
{
    const int lane = tid & 63, w = tid >> 6;
    const int ni = bid & 15, bi2 = bid >> 4;

    floatx16 acc0, acc1, acc2;
    #pragma unroll
    for (int i = 0; i < 16; ++i) { acc0[i] = 0.f; acc1[i] = 0.f; acc2[i] = 0.f; }

    short8 ah[4], al[4], bh[4], bl[4];

    #pragma unroll
    for (int i = 0; i < 8 + 4; ++i) {
        if (i >= 4) {
            const int s = (i - 4) & 3;
            acc0 = __builtin_amdgcn_mfma_f32_32x32x16_bf16(ah[s], bh[s], acc0, 0, 0, 0);
            acc1 = __builtin_amdgcn_mfma_f32_32x32x16_bf16(ah[s], bl[s], acc1, 0, 0, 0);
            acc2 = __builtin_amdgcn_mfma_f32_32x32x16_bf16(al[s], bh[s], acc2, 0, 0, 0);
        }
        if (i < 8) {
            const int s = i & 3;
            const int g = w * 8 + i;
            if (g < 32) {
                const size_t off = (((size_t)bi2 * 32 + g) * 64 + lane) * 8;
                ah[s] = *(const short8*)(ctx_hi + off);
                al[s] = *(const short8*)(ctx_lo + off);
            } else {
                const size_t off = (((size_t)bi2 * 32 + (g - 32)) * 64 + lane) * 8;
                ah[s] = *(const short8*)(h_hi + off);
                al[s] = *(const short8*)(h_lo + off);
            }
            const size_t boff = (((size_t)ni * 64 + g) * 64 + lane) * 8;
            bh[s] = *(const short8*)(w1_hi + boff);
            bl[s] = *(const short8*)(w1_lo + boff);
        }
    }
    #pragma unroll
    for (int i = 0; i < 16; ++i) acc0[i] += acc1[i] + acc2[i];

    {
        const int col = lane & 31;
        const int rb4 = 4 * (lane >> 5);
        #pragma unroll
        for (int r = 0; r < 16; ++r)
            lds[w * 1024 + (rb4 + (r & 3) + 8 * (r >> 2)) * 32 + col] = acc0[r];
    }
    __syncthreads();

    const int row = tid >> 4, l16 = tid & 15;
    float a = 0.f;
    #pragma unroll
    for (int jj = 0; jj < 2; ++jj) {
        const int col = l16 * 2 + jj;
        const int ncol = ni * 32 + col;
        float pre = b1[ncol];
        #pragma unroll
        for (int ww = 0; ww < 8; ++ww) pre += lds[ww * 1024 + row * 32 + col];
        a = fmaf(tanhf(pre), W2[ncol], a);
    }
    a += __shfl_xor(a, 1); a += __shfl_xor(a, 2);
    a += __shfl_xor(a, 4); a += __shfl_xor(a, 8);
    if (l16 == 0) astf(&part_p[ni * 512 + bi2 * 32 + row], a);
}

__device__ __forceinline__ void y_reduce(const float* __restrict__ part_p,
                                         const float* __restrict__ b2,
                                         float* __restrict__ y, int s, int bid, int tid) {
    if (tid < 2) {
        const int b = bid * 2 + tid;
        float a = b2[0];
        #pragma unroll
        for (int ni = 0; ni < 16; ++ni) a += aldf(&part_p[ni * 512 + b]);
        astf(&y[(size_t)b * PLz + s], a);
    }
}

// ---------------- the persistent kernel ----------------
struct KParams {
    const u16 *xf_hi, *xf_lo, *wf_hi, *wf_lo, *wcf_hi, *wcf_lo, *w1f_hi, *w1f_lo;
    const float *b_l, *b_c, *b1, *W2, *b2;
    float *h_f32rot, *part_p, *y;
    u16 *buf_enc, *buf_dec;
    u16 *hrot_hi, *hrot_lo, *ctxrot_hi, *ctxrot_lo;
    unsigned *sync;
};

__global__ __launch_bounds__(NTHR, 1) void k_persist(KParams p) {
    __shared__ char smem[65536];
    u16* A_hi = (u16*)smem;                 // 32 KB (staged h hi)
    u16* A_lo = (u16*)(smem + 32768);       // 32 KB (staged h lo)
    float* Gt = (float*)smem;               // [2][32][132] = 33 KB, overlays A after sync
    float* scr = (float*)smem;              // attn/mlp scratch

    const int bid = blockIdx.x;
    const int tid = threadIdx.x;
    // 2D XCD remap (8ji x 4bi per XCD): xcd = (ji&1) | ((bi&3)<<1)
    const int xcd = bid & 7, idx = bid >> 3;
    const int g_ji = (xcd & 1) | ((idx & 7) << 1);
    const int g_bi = ((xcd >> 1) & 3) | ((idx >> 3) << 2);
    unsigned gen = 1;
    float c2[2] = {0.f, 0.f};   // persistent cell state

    // encoder: 128 steps; h rotation depth 16, ring slots write-once (t>=96)
    for (int t = 0; t < Tz; ++t) {
        const int si = (t + 15) & 15, so = t & 15;
        gates_phase<36, 4>(p.xf_hi, p.xf_lo, t, p.wf_hi, p.wf_lo,
                           p.hrot_hi + (size_t)si * BH, p.hrot_lo + (size_t)si * BH,
                           p.b_l, c2, nullptr,
                           p.hrot_hi + (size_t)so * BH, p.hrot_lo + (size_t)so * BH,
                           p.buf_enc, t - 96, A_hi, A_lo, Gt, g_ji, g_bi, tid);
        gsync(p.sync, gen++, bid);
    }
    // decoder: 32 iterations (gates | attn | mlp)
    for (int sd = 0; sd < PLz; ++sd) {
        if (sd > 0) y_reduce(p.part_p, p.b2, p.y, sd - 1, bid, tid);
        const int si = (sd + 15) & 15, so = sd & 15;
        float* hf = p.h_f32rot + (size_t)(sd & 7) * BH;
        u16* cx_hi = p.ctxrot_hi + (size_t)(sd & 7) * BH;
        u16* cx_lo = p.ctxrot_lo + (size_t)(sd & 7) * BH;
        gates_phase<32, 0>(nullptr, nullptr, 0, p.wcf_hi, p.wcf_lo,
                           p.hrot_hi + (size_t)si * BH, p.hrot_lo + (size_t)si * BH,
                           p.b_c, c2, hf,
                           p.hrot_hi + (size_t)so * BH, p.hrot_lo + (size_t)so * BH,
                           nullptr, -1, A_hi, A_lo, Gt, g_ji, g_bi, tid);
        gsync(p.sync, gen++, bid);
        attn_phase(hf, p.buf_enc, p.buf_dec, cx_hi, cx_lo, sd, scr, bid, tid);
        gsync(p.sync, gen++, bid);
        mlp_phase(cx_hi, cx_lo,
                  p.hrot_hi + (size_t)so * BH, p.hrot_lo + (size_t)so * BH,
                  p.w1f_hi, p.w1f_lo, p.b1, p.W2, p.part_p, scr, bid, tid);
        gsync(p.sync, gen++, bid);
    }
    y_reduce(p.part_p, p.b2, p.y, PLz - 1, bid, tid);
}

extern "C" void kernel_launch(void* const* d_in, const int* in_sizes, int n_in,
                              void* d_out, int out_size, void* d_ws, size_t ws_size,
                              hipStream_t stream) {
    (void)in_sizes; (void)n_in; (void)out_size; (void)ws_size;
    const float* x     = (const float*)d_in[0];
    const float* W_ih  = (const float*)d_in[1];
    const float* W_hh  = (const float*)d_in[2];
    const float* b_l   = (const float*)d_in[3];
    const float* Wc_ih = (const float*)d_in[4];
    const float* Wc_hh = (const float*)d_in[5];
    const float* b_c   = (const float*)d_in[6];
    const float* W1    = (const float*)d_in[7];
    const float* b1    = (const float*)d_in[8];
    const float* W2    = (const float*)d_in[9];
    const float* b2    = (const float*)d_in[10];
    float* y = (float*)d_out;

    float* w = (float*)d_ws;
    float* h_f32rot = w;                             // 8*BH f32
    float* part_p   = w + 8 * (size_t)BH;            // 8192
    unsigned* sync  = (unsigned*)(w + 8 * (size_t)BH + 8192);   // 8192 u32
    u16* us = (u16*)(w + 8 * (size_t)BH + 8192 + 8192);
    u16* buf_enc = us;   us += 32 * (size_t)BH;      // bf16 ring (B*TS*H)
    u16* buf_dec = us;   us += 32 * (size_t)BH;      // bf16 ring (PL*B*H)
    u16* hrot_hi = us;   us += 16 * (size_t)BH;
    u16* hrot_lo = us;   us += 16 * (size_t)BH;
    u16* ctxrot_hi = us; us += 8 * (size_t)BH;
    u16* ctxrot_lo = us; us += 8 * (size_t)BH;
    u16* xf_hi = us;   us += 4194304;
    u16* xf_lo = us;   us += 4194304;
    u16* wf_hi = us;   us += 1179648;
    u16* wf_lo = us;   us += 1179648;
    u16* wcf_hi = us;  us += 1048576;
    u16* wcf_lo = us;  us += 1048576;
    u16* w1f_hi = us;  us += 524288;
    u16* w1f_lo = us;  us += 524288;

    k_init     <<<1024, 256, 0, stream>>>(hrot_hi + 15 * (size_t)BH,
                                          hrot_lo + 15 * (size_t)BH, sync);
    k_prep_wenc<<<576,  256, 0, stream>>>(W_ih, W_hh, wf_hi, wf_lo);
    k_prep_wc  <<<512,  256, 0, stream>>>(Wc_ih, Wc_hh, wcf_hi, wcf_lo);
    k_prep_w1  <<<256,  256, 0, stream>>>(W1, w1f_hi, w1f_lo);
    k_prep_x   <<<2048, 256, 0, stream>>>(x, xf_hi, xf_lo);

    KParams prm;
    prm.xf_hi = xf_hi;   prm.xf_lo = xf_lo;
    prm.wf_hi = wf_hi;   prm.wf_lo = wf_lo;
    prm.wcf_hi = wcf_hi; prm.wcf_lo = wcf_lo;
    prm.w1f_hi = w1f_hi; prm.w1f_lo = w1f_lo;
    prm.b_l = b_l; prm.b_c = b_c; prm.b1 = b1; prm.W2 = W2; prm.b2 = b2;
    prm.h_f32rot = h_f32rot; prm.part_p = part_p; prm.y = y;
    prm.buf_enc = buf_enc; prm.buf_dec = buf_dec;
    prm.hrot_hi = hrot_hi; prm.hrot_lo = hrot_lo;
    prm.ctxrot_hi = ctxrot_hi; prm.ctxrot_lo = ctxrot_lo;
    prm.sync = sync;

    k_persist<<<dim3(NBLK), dim3(NTHR), 0, stream>>>(prm);
}

// Round 16
// 1906.263 us; speedup vs baseline: 1.9365x; 1.1139x over previous
//
#include <hip/hip_runtime.h>
#include <hip/hip_bf16.h>
#include <math.h>

// Problem sizes
#define Bz   512
#define Tz   128
#define INz  64
#define Hz   512
#define TSz  32
#define PLz  32
#define BH   (Bz * Hz)          // 262144
#define NBLK 256
#define NTHR 512
#define PF   6

typedef unsigned short u16;
typedef unsigned long long u64;
typedef __attribute__((ext_vector_type(8)))  short short8;
typedef __attribute__((ext_vector_type(16))) float floatx16;

static __device__ __forceinline__ void split_bf(float w, u16& hi, u16& lo) {
    __hip_bfloat16 h = __float2bfloat16(w);
    hi = *reinterpret_cast<u16*>(&h);
    float r = w - __bfloat162float(h);
    __hip_bfloat16 l = __float2bfloat16(r);
    lo = *reinterpret_cast<u16*>(&l);
}

union FU  { unsigned u; float f; };
union F2U { u64 q; float f[2]; };

static __device__ __forceinline__ float b2f(u16 v) {
    FU c; c.u = ((unsigned)v) << 16; return c.f;
}
static __device__ __forceinline__ u16 f2b(float f) {
    __hip_bfloat16 h = __float2bfloat16(f);
    return *reinterpret_cast<u16*>(&h);
}

// ---- sc1 (coherence-point / MALL) STORE helpers + sync atomics ----
static __device__ __forceinline__ float aldf(const float* p) {
    FU c; c.u = __hip_atomic_load((const unsigned*)p, __ATOMIC_RELAXED, __HIP_MEMORY_SCOPE_AGENT);
    return c.f;
}
static __device__ __forceinline__ void ast64f(float* p, float a, float b) {
    F2U u; u.f[0] = a; u.f[1] = b;
    __hip_atomic_store((u64*)p, u.q, __ATOMIC_RELAXED, __HIP_MEMORY_SCOPE_AGENT);
}
static __device__ __forceinline__ void astf(float* p, float v) {
    FU c; c.f = v;
    __hip_atomic_store((unsigned*)p, c.u, __ATOMIC_RELAXED, __HIP_MEMORY_SCOPE_AGENT);
}
static __device__ __forceinline__ unsigned aldu(const unsigned* p) {
    return __hip_atomic_load(p, __ATOMIC_RELAXED, __HIP_MEMORY_SCOPE_AGENT);
}
static __device__ __forceinline__ void astu(unsigned* p, unsigned v) {
    __hip_atomic_store(p, v, __ATOMIC_RELAXED, __HIP_MEMORY_SCOPE_AGENT);
}
static __device__ __forceinline__ void astu16x2(u16* p, unsigned v) {
    __hip_atomic_store((unsigned*)p, v, __ATOMIC_RELAXED, __HIP_MEMORY_SCOPE_AGENT);
}

// ---------------- init: zero hrot slot 15 + sync area ----------------
__global__ __launch_bounds__(256) void k_init(u16* __restrict__ h15_hi,
                                              u16* __restrict__ h15_lo,
                                              unsigned* __restrict__ sync) {
    const int i = blockIdx.x * 256 + threadIdx.x;
    if (i < BH) { h15_hi[i] = 0; h15_lo[i] = 0; }
    if (i < 8192) sync[i] = 0;
}

// ---------------- prep kernels (verified, unchanged) ----------------
__global__ __launch_bounds__(256) void k_prep_wenc(const float* __restrict__ W_ih,
                                                   const float* __restrict__ W_hh,
                                                   u16* __restrict__ wf_hi,
                                                   u16* __restrict__ wf_lo) {
    const int idx = blockIdx.x * 256 + threadIdx.x;
    const int lane = idx & 63;
    const int g = (idx >> 6) % 36;
    const int cb = idx / (36 * 64);
    const int C = cb * 32 + (lane & 31);
    const int gate = ((C >> 4) & 3) * 512 + (C >> 6) * 16 + (C & 15);
    const int kh = lane >> 5;
    const size_t base = (size_t)idx * 8;
    #pragma unroll
    for (int e = 0; e < 8; ++e) {
        const int k = g * 16 + kh * 8 + e;
        const float w = (k < 64) ? W_ih[(size_t)gate * 64 + k]
                                 : W_hh[(size_t)gate * 512 + (k - 64)];
        u16 hi, lo; split_bf(w, hi, lo);
        wf_hi[base + e] = hi; wf_lo[base + e] = lo;
    }
}

__global__ __launch_bounds__(256) void k_prep_wc(const float* __restrict__ Wc_ih,
                                                 const float* __restrict__ Wc_hh,
                                                 u16* __restrict__ wf_hi,
                                                 u16* __restrict__ wf_lo) {
    const int idx = blockIdx.x * 256 + threadIdx.x;
    const int lane = idx & 63;
    const int cb = idx / (32 * 64);
    const int g = (idx >> 6) % 32;
    const int C = cb * 32 + (lane & 31);
    const int gate = ((C >> 4) & 3) * 512 + (C >> 6) * 16 + (C & 15);
    const int kh = lane >> 5;
    const size_t base = (size_t)idx * 8;
    #pragma unroll
    for (int e = 0; e < 8; ++e) {
        const int k = g * 16 + kh * 8 + e;
        const float w = Wc_ih[(size_t)gate * 512 + k] + Wc_hh[(size_t)gate * 512 + k];
        u16 hi, lo; split_bf(w, hi, lo);
        wf_hi[base + e] = hi; wf_lo[base + e] = lo;
    }
}

__global__ __launch_bounds__(256) void k_prep_w1(const float* __restrict__ W1,
                                                 u16* __restrict__ wf_hi,
                                                 u16* __restrict__ wf_lo) {
    const int idx = blockIdx.x * 256 + threadIdx.x;
    const int lane = idx & 63;
    const int cb = idx / (64 * 64);
    const int g = (idx >> 6) % 64;
    const int n = cb * 32 + (lane & 31);
    const int kh = lane >> 5;
    const size_t base = (size_t)idx * 8;
    #pragma unroll
    for (int e = 0; e < 8; ++e) {
        const int k = g * 16 + kh * 8 + e;
        const float w = W1[(size_t)n * 1024 + k];
        u16 hi, lo; split_bf(w, hi, lo);
        wf_hi[base + e] = hi; wf_lo[base + e] = lo;
    }
}

__global__ __launch_bounds__(256) void k_prep_x(const float* __restrict__ x,
                                                u16* __restrict__ xf_hi,
                                                u16* __restrict__ xf_lo) {
    const int idx = blockIdx.x * 256 + threadIdx.x;
    const int lane = idx & 63;
    const int g = (idx >> 6) & 3;
    const int rb = (idx >> 8) & 15;
    const int t = idx >> 12;
    const int b = rb * 32 + (lane & 31);
    const int kh = lane >> 5;
    const size_t base = (size_t)idx * 8;
    #pragma unroll
    for (int e = 0; e < 8; ++e) {
        const int i = g * 16 + kh * 8 + e;
        const float w = x[((size_t)b * Tz + t) * INz + i];
        u16 hi, lo; split_bf(w, hi, lo);
        xf_hi[base + e] = hi; xf_lo[base + e] = lo;
    }
}

// ---------------- grid barrier: two-level RELAXED fetch_add (round-15, verified) ----------------
static __device__ __forceinline__ void gsync(unsigned* sync, unsigned target, int bid) {
    __syncthreads();
    if (threadIdx.x == 0) {
        unsigned* grp  = sync + 64 + ((bid >> 4) << 4);   // 16 groups, 64B apart
        unsigned* root = sync + 64 + (16 << 4);
        const unsigned a = __hip_atomic_fetch_add(grp, 1u, __ATOMIC_RELAXED, __HIP_MEMORY_SCOPE_AGENT);
        if ((a & 15u) == 15u) {
            const unsigned r = __hip_atomic_fetch_add(root, 1u, __ATOMIC_RELAXED, __HIP_MEMORY_SCOPE_AGENT);
            if ((r & 15u) == 15u)
                astu(sync, target);
        }
        while (aldu(sync) < target)
            __builtin_amdgcn_s_sleep(2);
        if ((target & 15u) == 0u)
            __builtin_amdgcn_fence(__ATOMIC_ACQUIRE, "agent");   // periodic buffer_inv
    }
    __syncthreads();
}

// ---------------- gates + cell: A-side bf16-only (hi), split weights kept ----------------
// acc = Ah*Bh + Ah*Bl. A-lo (h_lo/x_lo) never read -> halves the per-step h-broadcast.
// Decoder (h_f32 != nullptr) still stores h_lo for the MLP's 3-pass path.
template<int NG, int GX>
__device__ __forceinline__ void gates_phase(
    const u16* __restrict__ xf_hi, int t,
    const u16* __restrict__ wf_hi, const u16* __restrict__ wf_lo,
    const u16* __restrict__ hin_hi,
    const float* __restrict__ bias,
    float (&c2)[2], float* __restrict__ h_f32,
    u16* __restrict__ hout_hi, u16* __restrict__ hout_lo,
    u16* __restrict__ buf_enc, int slot,
    u16* A_hi, float* Gt, int ji, int bi, int tid)
{
    const int lane = tid & 63, wid = tid >> 6;
    const int wc = wid & 3, kh = wid >> 2;

    // ---- burst-stage h_hi slice (32 granules, 32 KB) into LDS ----
    {
        float4 vh[4];
        #pragma unroll
        for (int it = 0; it < 4; ++it) {
            const int sl = it * 512 + tid;                 // [0,2048)
            const size_t off = ((size_t)bi * 32 + (sl >> 6)) * 512 + (size_t)(sl & 63) * 8;
            vh[it] = *(const float4*)(hin_hi + off);
        }
        #pragma unroll
        for (int it = 0; it < 4; ++it) {
            const int sl = it * 512 + tid;
            *(float4*)(A_hi + (size_t)sl * 8) = vh[it];
        }
    }
    __syncthreads();

    // ---- K-loop: col-block cb = ji*4+wc, K-half kh; A from LDS/x-global, B global ----
    constexpr int NGH = NG / 2;
    const int g0 = kh * NGH;
    const int cb = ji * 4 + wc;
    const u16* pbh = wf_hi + ((size_t)cb * NG) * 512 + lane * 8;
    const u16* pbl = wf_lo + ((size_t)cb * NG) * 512 + lane * 8;

    floatx16 acc0, acc1;
    #pragma unroll
    for (int i = 0; i < 16; ++i) { acc0[i] = 0.f; acc1[i] = 0.f; }

    short8 ah[PF], bh[PF], bl[PF];

    #pragma unroll
    for (int i = 0; i < NGH + PF; ++i) {
        if (i >= PF) {   // consume granule g0 + i - PF
            const int s = (i - PF) % PF;
            acc0 = __builtin_amdgcn_mfma_f32_32x32x16_bf16(ah[s], bh[s], acc0, 0, 0, 0);
            acc1 = __builtin_amdgcn_mfma_f32_32x32x16_bf16(ah[s], bl[s], acc1, 0, 0, 0);
        }
        if (i < NGH) {   // refill slot with granule g0+i
            const int s = i % PF;
            const int g = g0 + i;
            if (GX > 0 && g < GX) {   // x: direct cached global (hi only)
                const size_t off = (((size_t)t * 16 + bi) * GX + g) * 512 + (size_t)lane * 8;
                ah[s] = *(const short8*)(xf_hi + off);
            } else {                   // h: from LDS (conflict-free ds_read_b128)
                const int gh = g - GX;
                ah[s] = *(const short8*)(A_hi + ((size_t)gh * 64 + lane) * 8);
            }
            bh[s] = *(const short8*)(pbh + (size_t)g * 512);
            bl[s] = *(const short8*)(pbl + (size_t)g * 512);
        }
    }
    #pragma unroll
    for (int i = 0; i < 16; ++i) acc0[i] += acc1[i];

    // ---- Gt overlays A region: sync (all A-reads done), dump, sync ----
    __syncthreads();
    {
        const int col = wc * 32 + (lane & 31);
        const int rb4 = 4 * (lane >> 5);
        float* G = Gt + (size_t)kh * 4224;   // [2][32][132]
        #pragma unroll
        for (int r = 0; r < 16; ++r)
            G[(rb4 + (r & 3) + 8 * (r >> 2)) * 132 + col] = acc0[r];
    }
    __syncthreads();

    // ---- cell update: thread -> (b = bi*32 + tid>>4, 2 consecutive j); c in VGPRs ----
    {
        const int bl2 = tid >> 4, jq = tid & 15;
        const int b = bi * 32 + bl2;
        const int j0 = ji * 32 + jq * 2;
        float hn2[2];
        unsigned phi = 0, plo = 0;
        #pragma unroll
        for (int e = 0; e < 2; ++e) {
            const int jl = jq * 2 + e;
            const int Cl = ((jl >> 4) << 6) | (jl & 15);
            const float* gp = Gt + (size_t)bl2 * 132 + Cl;
            const float* gq = gp + 4224;
            const float gi = gp[0]  + gq[0]  + bias[j0 + e];
            const float gf = gp[16] + gq[16] + bias[512 + j0 + e];
            const float gg = gp[32] + gq[32] + bias[1024 + j0 + e];
            const float go = gp[48] + gq[48] + bias[1536 + j0 + e];
            const float si = 1.f / (1.f + __expf(-gi));
            const float sf = 1.f / (1.f + __expf(-gf));
            const float so = 1.f / (1.f + __expf(-go));
            const float cn = sf * c2[e] + si * tanhf(gg);
            const float hn = so * tanhf(cn);
            c2[e] = cn; hn2[e] = hn;
            u16 hi, lo; split_bf(hn, hi, lo);
            phi |= (unsigned)hi << (16 * e);
            plo |= (unsigned)lo << (16 * e);
        }
        const int gran = j0 >> 4;
        const int fl = ((j0 >> 3) & 1) * 32 + (b & 31);
        const size_t fo = (((size_t)bi * 32 + gran) * 64 + fl) * 8 + (j0 & 7);
        astu16x2(hout_hi + fo, phi);    // sc1: fresh at MALL for all XCDs
        if (h_f32 != nullptr)
            astu16x2(hout_lo + fo, plo);   // only decoder needs h_lo (MLP 3-pass)
        if (slot >= 0)
            astu16x2(buf_enc + ((size_t)b * TSz + slot) * Hz + j0, phi);  // bf16 ring
        if (h_f32 != nullptr)
            ast64f(h_f32 + (size_t)b * Hz + j0, hn2[0], hn2[1]);
    }
}

// ---------------- attention: 2 batches/block; bf16 ring, cached reads ----------------
__device__ __forceinline__ void attn_phase(const float* __restrict__ h_f32,
                                           const u16* __restrict__ buf_enc,
                                           u16* __restrict__ buf_dec,
                                           u16* __restrict__ ctx_hi, u16* __restrict__ ctx_lo,
                                           int sd, float* lds, int bid, int tid) {
    const int grp = tid >> 8;
    const int t8 = tid & 255;
    const int b = bid * 2 + grp;
    float* sh = lds + grp * 544;
    float* sa = sh + 512;
    {
        const int i0 = t8 * 2;
        const float2 hv = *(const float2*)(h_f32 + (size_t)b * Hz + i0);
        sh[i0] = hv.x; sh[i0 + 1] = hv.y;
    }
    __syncthreads();
    {   // 32 scores x 8 lanes; bf16 ring, ushort4 coalesced
        const int w = t8 >> 3, l8 = t8 & 7;
        const u16* v = (w < TSz - sd)
            ? buf_enc + ((size_t)b * TSz + (sd + w)) * Hz
            : buf_dec + (size_t)(w - TSz + sd) * BH + (size_t)b * Hz;
        float p = 0.f;
        #pragma unroll 4
        for (int k = 0; k < 16; ++k) {
            const int j = l8 * 4 + k * 32;
            const ushort4 q = *(const ushort4*)(v + j);
            p = fmaf(sh[j],     b2f(q.x), p);
            p = fmaf(sh[j + 1], b2f(q.y), p);
            p = fmaf(sh[j + 2], b2f(q.z), p);
            p = fmaf(sh[j + 3], b2f(q.w), p);
        }
        p += __shfl_xor(p, 1); p += __shfl_xor(p, 2); p += __shfl_xor(p, 4);
        if (l8 == 0) sa[w] = p;
    }
    __syncthreads();
    if (t8 < TSz) {
        const float v = sa[t8];
        float m = v;
        #pragma unroll
        for (int d = 1; d < 32; d <<= 1) m = fmaxf(m, __shfl_xor(m, d));
        const float e = __expf(v - m);
        float ss = e;
        #pragma unroll
        for (int d = 1; d < 32; d <<= 1) ss += __shfl_xor(ss, d);
        sa[t8] = e / ss;
    }
    __syncthreads();
    {   // ctx: 2 consecutive j per thread; bf16 ring reads; sc1 frag store
        const int j0 = t8 * 2;
        float a0 = 0.f, a1 = 0.f;
        for (int w2 = 0; w2 < TSz; ++w2) {
            const u16* vp = (w2 < TSz - sd)
                ? buf_enc + ((size_t)b * TSz + (sd + w2)) * Hz + j0
                : buf_dec + (size_t)(w2 - TSz + sd) * BH + (size_t)b * Hz + j0;
            const ushort2 vv = *(const ushort2*)vp;
            a0 = fmaf(sa[w2], b2f(vv.x), a0);
            a1 = fmaf(sa[w2], b2f(vv.y), a1);
        }
        u16 h0, l0, h1, l1;
        split_bf(a0, h0, l0); split_bf(a1, h1, l1);
        const int rb = b >> 5, gran = j0 >> 4;
        const int fl = ((j0 >> 3) & 1) * 32 + (b & 31);
        const size_t fo = (((size_t)rb * 32 + gran) * 64 + fl) * 8 + (j0 & 7);
        astu16x2(ctx_hi + fo, (unsigned)h0 | ((unsigned)h1 << 16));
        astu16x2(ctx_lo + fo, (unsigned)l0 | ((unsigned)l1 << 16));
    }
    {   // append h_sd to fresh buffer buf_dec[sd] (sc1, bf16, write-once)
        const int i0 = t8 * 2;
        const unsigned pk = (unsigned)f2b(sh[i0]) | ((unsigned)f2b(sh[i0 + 1]) << 16);
        astu16x2(buf_dec + (size_t)sd * BH + (size_t)b * Hz + i0, pk);
    }
}

// ---------------- MLP + partial out: 8-wave K-split; 3-pass (unchanged numerics) ----------------
__device__ __forceinline__ void mlp_phase(
    const u16* __restrict__ ctx_hi, const u16* __restrict__ ctx_lo,
    const u16* __restrict__ h_hi,   const u16* __restrict__ h_lo,
    const u16* __restrict__ w1_hi,  const u16* __restrict__ w1_lo,
    const float* __restrict__ b1, const float* __restrict__ W2,
    float* __restrict__ part_p, float* lds, int bid, int tid)
{
    const int lane = tid & 63, w = tid >> 6;
    const int ni = bid & 15, bi2 = bid >> 4;

    floatx16 acc0, acc1, acc2;
    #pragma unroll
    for (int i = 0; i < 16; ++i) { acc0[i] = 0.f; acc1[i] = 0.f; acc2[i] = 0.f; }

    short8 ah[4], al[4], bh[4], bl[4];

    #pragma unroll
    for (int i = 0; i < 8 + 4; ++i) {
        if (i >= 4) {
            const int s = (i - 4) & 3;
            acc0 = __builtin_amdgcn_mfma_f32_32x32x16_bf16(ah[s], bh[s], acc0, 0, 0, 0);
            acc1 = __builtin_amdgcn_mfma_f32_32x32x16_bf16(ah[s], bl[s], acc1, 0, 0, 0);
            acc2 = __builtin_amdgcn_mfma_f32_32x32x16_bf16(al[s], bh[s], acc2, 0, 0, 0);
        }
        if (i < 8) {
            const int s = i & 3;
            const int g = w * 8 + i;
            if (g < 32) {
                const size_t off = (((size_t)bi2 * 32 + g) * 64 + lane) * 8;
                ah[s] = *(const short8*)(ctx_hi + off);
                al[s] = *(const short8*)(ctx_lo + off);
            } else {
                const size_t off = (((size_t)bi2 * 32 + (g - 32)) * 64 + lane) * 8;
                ah[s] = *(const short8*)(h_hi + off);
                al[s] = *(const short8*)(h_lo + off);
            }
            const size_t boff = (((size_t)ni * 64 + g) * 64 + lane) * 8;
            bh[s] = *(const short8*)(w1_hi + boff);
            bl[s] = *(const short8*)(w1_lo + boff);
        }
    }
    #pragma unroll
    for (int i = 0; i < 16; ++i) acc0[i] += acc1[i] + acc2[i];

    {
        const int col = lane & 31;
        const int rb4 = 4 * (lane >> 5);
        #pragma unroll
        for (int r = 0; r < 16; ++r)
            lds[w * 1024 + (rb4 + (r & 3) + 8 * (r >> 2)) * 32 + col] = acc0[r];
    }
    __syncthreads();

    const int row = tid >> 4, l16 = tid & 15;
    float a = 0.f;
    #pragma unroll
    for (int jj = 0; jj < 2; ++jj) {
        const int col = l16 * 2 + jj;
        const int ncol = ni * 32 + col;
        float pre = b1[ncol];
        #pragma unroll
        for (int ww = 0; ww < 8; ++ww) pre += lds[ww * 1024 + row * 32 + col];
        a = fmaf(tanhf(pre), W2[ncol], a);
    }
    a += __shfl_xor(a, 1); a += __shfl_xor(a, 2);
    a += __shfl_xor(a, 4); a += __shfl_xor(a, 8);
    if (l16 == 0) astf(&part_p[ni * 512 + bi2 * 32 + row], a);
}

__device__ __forceinline__ void y_reduce(const float* __restrict__ part_p,
                                         const float* __restrict__ b2,
                                         float* __restrict__ y, int s, int bid, int tid) {
    if (tid < 2) {
        const int b = bid * 2 + tid;
        float a = b2[0];
        #pragma unroll
        for (int ni = 0; ni < 16; ++ni) a += aldf(&part_p[ni * 512 + b]);
        astf(&y[(size_t)b * PLz + s], a);
    }
}

// ---------------- the persistent kernel ----------------
struct KParams {
    const u16 *xf_hi, *xf_lo, *wf_hi, *wf_lo, *wcf_hi, *wcf_lo, *w1f_hi, *w1f_lo;
    const float *b_l, *b_c, *b1, *W2, *b2;
    float *h_f32rot, *part_p, *y;
    u16 *buf_enc, *buf_dec;
    u16 *hrot_hi, *hrot_lo, *ctxrot_hi, *ctxrot_lo;
    unsigned *sync;
};

__global__ __launch_bounds__(NTHR, 1) void k_persist(KParams p) {
    __shared__ char smem[65536];
    u16* A_hi = (u16*)smem;                 // 32 KB (staged h hi)
    float* Gt = (float*)smem;               // [2][32][132] = 33 KB, overlays A after sync
    float* scr = (float*)smem;              // attn/mlp scratch

    const int bid = blockIdx.x;
    const int tid = threadIdx.x;
    // 2D XCD remap (8ji x 4bi per XCD): xcd = (ji&1) | ((bi&3)<<1)
    const int xcd = bid & 7, idx = bid >> 3;
    const int g_ji = (xcd & 1) | ((idx & 7) << 1);
    const int g_bi = ((xcd >> 1) & 3) | ((idx >> 3) << 2);
    unsigned gen = 1;
    float c2[2] = {0.f, 0.f};   // persistent cell state

    // encoder: 128 steps; h rotation depth 16, ring slots write-once (t>=96)
    for (int t = 0; t < Tz; ++t) {
        const int si = (t + 15) & 15, so = t & 15;
        gates_phase<36, 4>(p.xf_hi, t, p.wf_hi, p.wf_lo,
                           p.hrot_hi + (size_t)si * BH,
                           p.b_l, c2, nullptr,
                           p.hrot_hi + (size_t)so * BH, nullptr,
                           p.buf_enc, t - 96, A_hi, Gt, g_ji, g_bi, tid);
        gsync(p.sync, gen++, bid);
    }
    // decoder: 32 iterations (gates | attn | mlp)
    for (int sd = 0; sd < PLz; ++sd) {
        if (sd > 0) y_reduce(p.part_p, p.b2, p.y, sd - 1, bid, tid);
        const int si = (sd + 15) & 15, so = sd & 15;
        float* hf = p.h_f32rot + (size_t)(sd & 7) * BH;
        u16* cx_hi = p.ctxrot_hi + (size_t)(sd & 7) * BH;
        u16* cx_lo = p.ctxrot_lo + (size_t)(sd & 7) * BH;
        gates_phase<32, 0>(nullptr, 0, p.wcf_hi, p.wcf_lo,
                           p.hrot_hi + (size_t)si * BH,
                           p.b_c, c2, hf,
                           p.hrot_hi + (size_t)so * BH, p.hrot_lo + (size_t)so * BH,
                           nullptr, -1, A_hi, Gt, g_ji, g_bi, tid);
        gsync(p.sync, gen++, bid);
        attn_phase(hf, p.buf_enc, p.buf_dec, cx_hi, cx_lo, sd, scr, bid, tid);
        gsync(p.sync, gen++, bid);
        mlp_phase(cx_hi, cx_lo,
                  p.hrot_hi + (size_t)so * BH, p.hrot_lo + (size_t)so * BH,
                  p.w1f_hi, p.w1f_lo, p.b1, p.W2, p.part_p, scr, bid, tid);
        gsync(p.sync, gen++, bid);
    }
    y_reduce(p.part_p, p.b2, p.y, PLz - 1, bid, tid);
}

extern "C" void kernel_launch(void* const* d_in, const int* in_sizes, int n_in,
                              void* d_out, int out_size, void* d_ws, size_t ws_size,
                              hipStream_t stream) {
    (void)in_sizes; (void)n_in; (void)out_size; (void)ws_size;
    const float* x     = (const float*)d_in[0];
    const float* W_ih  = (const float*)d_in[1];
    const float* W_hh  = (const float*)d_in[2];
    const float* b_l   = (const float*)d_in[3];
    const float* Wc_ih = (const float*)d_in[4];
    const float* Wc_hh = (const float*)d_in[5];
    const float* b_c   = (const float*)d_in[6];
    const float* W1    = (const float*)d_in[7];
    const float* b1    = (const float*)d_in[8];
    const float* W2    = (const float*)d_in[9];
    const float* b2    = (const float*)d_in[10];
    float* y = (float*)d_out;

    float* w = (float*)d_ws;
    float* h_f32rot = w;                             // 8*BH f32
    float* part_p   = w + 8 * (size_t)BH;            // 8192
    unsigned* sync  = (unsigned*)(w + 8 * (size_t)BH + 8192);   // 8192 u32
    u16* us = (u16*)(w + 8 * (size_t)BH + 8192 + 8192);
    u16* buf_enc = us;   us += 32 * (size_t)BH;      // bf16 ring (B*TS*H)
    u16* buf_dec = us;   us += 32 * (size_t)BH;      // bf16 ring (PL*B*H)
    u16* hrot_hi = us;   us += 16 * (size_t)BH;
    u16* hrot_lo = us;   us += 16 * (size_t)BH;
    u16* ctxrot_hi = us; us += 8 * (size_t)BH;
    u16* ctxrot_lo = us; us += 8 * (size_t)BH;
    u16* xf_hi = us;   us += 4194304;
    u16* xf_lo = us;   us += 4194304;
    u16* wf_hi = us;   us += 1179648;
    u16* wf_lo = us;   us += 1179648;
    u16* wcf_hi = us;  us += 1048576;
    u16* wcf_lo = us;  us += 1048576;
    u16* w1f_hi = us;  us += 524288;
    u16* w1f_lo = us;  us += 524288;

    k_init     <<<1024, 256, 0, stream>>>(hrot_hi + 15 * (size_t)BH,
                                          hrot_lo + 15 * (size_t)BH, sync);
    k_prep_wenc<<<576,  256, 0, stream>>>(W_ih, W_hh, wf_hi, wf_lo);
    k_prep_wc  <<<512,  256, 0, stream>>>(Wc_ih, Wc_hh, wcf_hi, wcf_lo);
    k_prep_w1  <<<256,  256, 0, stream>>>(W1, w1f_hi, w1f_lo);
    k_prep_x   <<<2048, 256, 0, stream>>>(x, xf_hi, xf_lo);

    KParams prm;
    prm.xf_hi = xf_hi;   prm.xf_lo = xf_lo;
    prm.wf_hi = wf_hi;   prm.wf_lo = wf_lo;
    prm.wcf_hi = wcf_hi; prm.wcf_lo = wcf_lo;
    prm.w1f_hi = w1f_hi; prm.w1f_lo = w1f_lo;
    prm.b_l = b_l; prm.b_c = b_c; prm.b1 = b1; prm.W2 = W2; prm.b2 = b2;
    prm.h_f32rot = h_f32rot; prm.part_p = part_p; prm.y = y;
    prm.buf_enc = buf_enc; prm.buf_dec = buf_dec;
    prm.hrot_hi = hrot_hi; prm.hrot_lo = hrot_lo;
    prm.ctxrot_hi = ctxrot_hi; prm.ctxrot_lo = ctxrot_lo;
    prm.sync = sync;

    k_persist<<<dim3(NBLK), dim3(NTHR), 0, stream>>>(prm);
}